// Round 10
// baseline (2108.144 us; speedup 1.0000x reference)
//
#include <hip/hip_runtime.h>
#include <math.h>

#define V_SZ 50257
#define NPAD 50432   // 197 * 256
#define NCB 197

typedef short s16x8 __attribute__((ext_vector_type(8)));
typedef ushort u16x4 __attribute__((ext_vector_type(4)));
typedef float f32x4 __attribute__((ext_vector_type(4)));

__device__ __forceinline__ ushort f2bf(float x) {
    union { float f; unsigned u; } v; v.f = x;
    unsigned r = v.u + 0x7FFF + ((v.u >> 16) & 1);   // RNE
    return (ushort)(r >> 16);
}
__device__ __forceinline__ float bf2f(ushort u) {
    union { unsigned u; float f; } v; v.u = ((unsigned)u) << 16; return v.f;
}

// ================= embed + ln1(layer0): wave per row =================
__global__ __launch_bounds__(256) void gpt_embed_ln(const int* __restrict__ tokens,
                                                    const float* __restrict__ tok_emb,
                                                    const float* __restrict__ pos_emb,
                                                    const float* __restrict__ s, const float* __restrict__ b,
                                                    float* __restrict__ x, ushort* __restrict__ hb) {
    int wave = threadIdx.x >> 6, lane = threadIdx.x & 63;
    int row = blockIdx.x * 4 + wave;
    int t = row & 511;
    int tok = tokens[row];
    float4 te = ((const float4*)(tok_emb + tok * 256))[lane];
    float4 pe = ((const float4*)(pos_emb + t * 256))[lane];
    float4 v = make_float4(te.x + pe.x, te.y + pe.y, te.z + pe.z, te.w + pe.w);
    ((float4*)(x + row * 256))[lane] = v;
    float sum = v.x + v.y + v.z + v.w;
    #pragma unroll
    for (int off = 1; off < 64; off <<= 1) sum += __shfl_xor(sum, off);
    float mean = sum * (1.0f / 256.0f);
    float dx = v.x - mean, dy = v.y - mean, dz = v.z - mean, dw = v.w - mean;
    float vs = dx * dx + dy * dy + dz * dz + dw * dw;
    #pragma unroll
    for (int off = 1; off < 64; off <<= 1) vs += __shfl_xor(vs, off);
    float rstd = rsqrtf(vs * (1.0f / 256.0f) + 1e-5f);
    float4 sv = ((const float4*)s)[lane];
    float4 bv = ((const float4*)b)[lane];
    u16x4 o;
    o[0] = f2bf(dx * rstd * sv.x + bv.x);
    o[1] = f2bf(dy * rstd * sv.y + bv.y);
    o[2] = f2bf(dz * rstd * sv.z + bv.z);
    o[3] = f2bf(dw * rstd * sv.w + bv.w);
    *(u16x4*)&hb[row * 256 + lane * 4] = o;
}

// ================= generic transpose+convert: in fp32 [Kd][Nd] -> out bf16 [n][k] =================
__global__ __launch_bounds__(256) void cvt_transpose(const float* __restrict__ in, ushort* __restrict__ out,
                                                     int Kd, int Nd, int n_real,
                                                     int in_stride, int out_stride) {
    __shared__ __align__(16) ushort t[64][80];
    const float* inp = in + (size_t)blockIdx.z * in_stride;
    ushort* outp = out + (size_t)blockIdx.z * out_stride;
    int n0 = blockIdx.x * 64, k0 = blockIdx.y * 64;
    int tid = threadIdx.x;
    #pragma unroll
    for (int p = 0; p < 4; p++) {
        int lk = p * 16 + (tid >> 4);
        int ln = (tid & 15) * 4;
        int k = k0 + lk, n = n0 + ln;
        const float* rowp = inp + (size_t)k * Nd;
        float v0 = 0.f, v1 = 0.f, v2 = 0.f, v3 = 0.f;
        if (n + 0 < n_real) v0 = rowp[n + 0];
        if (n + 1 < n_real) v1 = rowp[n + 1];
        if (n + 2 < n_real) v2 = rowp[n + 2];
        if (n + 3 < n_real) v3 = rowp[n + 3];
        t[ln + 0][lk] = f2bf(v0);
        t[ln + 1][lk] = f2bf(v1);
        t[ln + 2][lk] = f2bf(v2);
        t[ln + 3][lk] = f2bf(v3);
    }
    __syncthreads();
    int ln = tid >> 2, kq = (tid & 3) * 16;
    ushort* op = outp + (size_t)(n0 + ln) * Kd + k0 + kq;
    *(s16x8*)&op[0] = *(const s16x8*)&t[ln][kq];
    *(s16x8*)&op[8] = *(const s16x8*)&t[ln][kq + 8];
}

// ================= Wq/Wk/Wv [L][H][E][D] -> WqkvT [L][256][256] (rows 192..255 zero) =================
__global__ __launch_bounds__(256) void cvt_qkv(const float* __restrict__ Wq, const float* __restrict__ Wk,
                                               const float* __restrict__ Wv, ushort* __restrict__ WqkvT) {
    int l = blockIdx.x, kind = blockIdx.y;
    const float* W = (kind == 0 ? Wq : (kind == 1 ? Wk : Wv)) + l * 16384;
    ushort* out = WqkvT + (size_t)l * 65536 + kind * 64 * 256;
    int tid = threadIdx.x;
    #pragma unroll 4
    for (int it = 0; it < 64; it++) {
        int idx = it * 256 + tid;
        int row = idx >> 8, e = idx & 255;
        int h = row >> 3, d = row & 7;
        out[row * 256 + e] = f2bf(W[h * 2048 + e * 8 + d]);
    }
    if (kind == 0) {
        ushort* zp = WqkvT + (size_t)l * 65536 + 192 * 256;
        #pragma unroll 4
        for (int it = 0; it < 64; it++) zp[it * 256 + tid] = 0;
    }
}

// ================= pre: QKV (16 rows/block) + V out + R partials (layer 0 only) =================
__global__ __launch_bounds__(512, 4) void gpt_pre(const ushort* __restrict__ hb,
                                                  const ushort* __restrict__ WqkvT,
                                                  ushort* __restrict__ Vb,
                                                  float* __restrict__ Rpart) {
    __shared__ __align__(16) ushort As[16 * 64];
    __shared__ __align__(16) ushort Bs[256 * 64];
    __shared__ float kqv[16][193];
    const int tid = threadIdx.x, lane = tid & 63, wn = tid >> 6;
    const int rows0 = blockIdx.x * 16;
    const int fr = lane & 15, fkb = (lane >> 4) * 16;
    const int arow = tid >> 3, ach = tid & 7;

    f32x4 acc[2];
    acc[0] = (f32x4)0.0f; acc[1] = (f32x4)0.0f;

    s16x8 ra, rb[4];
    if (tid < 128) ra = *(const s16x8*)&hb[(size_t)(rows0 + arow) * 256 + ach * 8];
    #pragma unroll
    for (int i = 0; i < 4; i++) {
        int u = tid + i * 512, r = u >> 3, ch = u & 7;
        rb[i] = *(const s16x8*)&WqkvT[(size_t)r * 256 + ch * 8];
    }
    #pragma unroll 1
    for (int kt = 0; kt < 4; kt++) {
        if (kt) __syncthreads();
        if (tid < 128)
            *(s16x8*)&As[arow * 64 + (((ach * 16) ^ ((arow & 7) << 4)) >> 1)] = ra;
        #pragma unroll
        for (int i = 0; i < 4; i++) {
            int u = tid + i * 512, r = u >> 3, ch = u & 7;
            *(s16x8*)&Bs[r * 64 + (((ch * 16) ^ ((r & 7) << 4)) >> 1)] = rb[i];
        }
        __syncthreads();
        if (kt < 3) {
            int k0 = (kt + 1) * 64;
            if (tid < 128) ra = *(const s16x8*)&hb[(size_t)(rows0 + arow) * 256 + k0 + ach * 8];
            #pragma unroll
            for (int i = 0; i < 4; i++) {
                int u = tid + i * 512, r = u >> 3, ch = u & 7;
                rb[i] = *(const s16x8*)&WqkvT[(size_t)r * 256 + k0 + ch * 8];
            }
        }
        #pragma unroll
        for (int kk = 0; kk < 2; kk++) {
            int kbyte = kk * 64 + fkb;
            s16x8 af = *(const s16x8*)&As[fr * 64 + ((kbyte ^ ((fr & 7) << 4)) >> 1)];
            #pragma unroll
            for (int n = 0; n < 2; n++) {
                int brow = wn * 32 + n * 16 + fr;
                s16x8 bfv = *(const s16x8*)&Bs[brow * 64 + ((kbyte ^ ((brow & 7) << 4)) >> 1)];
                acc[n] = __builtin_amdgcn_mfma_f32_16x16x32_bf16(af, bfv, acc[n], 0, 0, 0);
            }
        }
    }
    #pragma unroll
    for (int n = 0; n < 2; n++) {
        int col = wn * 32 + n * 16 + fr;
        if (col < 192) {
            #pragma unroll
            for (int r = 0; r < 4; r++)
                kqv[(lane >> 4) * 4 + r][col] = acc[n][r];
        }
    }
    __syncthreads();
    #pragma unroll
    for (int i = 0; i < 2; i++) {
        int u = tid + i * 512, t = u >> 6, hd = u & 63;
        Vb[(size_t)(rows0 + t) * 64 + hd] = f2bf(kqv[t][128 + hd]);
    }
    {
        int h = tid >> 6, i2 = (tid >> 3) & 7, j = tid & 7;
        float s = 0.0f;
        #pragma unroll
        for (int t = 0; t < 16; t++)
            s += kqv[t][64 + h * 8 + i2] * kqv[t][h * 8 + j];
        int bb = rows0 >> 9, part = (rows0 >> 4) & 31;
        Rpart[(size_t)(bb * 32 + part) * 512 + tid] = s;
    }
}

// ================= fused layer: softmax(R)->ab->proj(+x,+LN)->MLP1->MLP2(+x,+LN)->[QKV next] =================
__global__ __launch_bounds__(512, 4) void gpt_layer(
        const float* __restrict__ Rpart_in, const ushort* __restrict__ Vb_in,
        const ushort* __restrict__ WoT, const float* __restrict__ bo,
        const ushort* __restrict__ W1T, const float* __restrict__ b1,
        const ushort* __restrict__ W2T, const float* __restrict__ b2,
        const float* __restrict__ ls2, const float* __restrict__ lb2,
        const float* __restrict__ nls, const float* __restrict__ nlb,
        float* __restrict__ x,
        const ushort* __restrict__ WqkvT_next,
        ushort* __restrict__ Vb_out, float* __restrict__ Rpart_out,
        ushort* __restrict__ hbout, int mode) {
    __shared__ __align__(16) ushort Bs[256 * 64];     // 32 KB
    __shared__ __align__(16) ushort ffs[16 * 1024];   // 32 KB (aliased as kqv in QKV phase)
    __shared__ __align__(16) ushort h2s[16 * 256];    // 8 KB
    __shared__ __align__(16) ushort abl[16 * 64];     // 2 KB
    __shared__ __align__(16) ushort Vl[16 * 64];      // 2 KB
    __shared__ float Rs[512];                          // 2 KB
    __shared__ float red1[16][8], red2[16][8], mrow[16], rrow[16];

    const int tid = threadIdx.x, lane = tid & 63, wn = tid >> 6;
    const int rows0 = blockIdx.x * 16, b = rows0 >> 9;
    const int fr = lane & 15, fkb = (lane >> 4) * 16, rbase = (lane >> 4) * 4;
    int colv[2]; colv[0] = wn * 32 + fr; colv[1] = wn * 32 + 16 + fr;

    // ---- softmax(R) from 32 partials ----
    {
        const float* rp = Rpart_in + (size_t)b * 32 * 512 + tid;
        float s = 0.0f;
        #pragma unroll
        for (int p = 0; p < 32; p++) s += rp[p * 512];
        s *= (1.0f / 16.0f);
        int ii = (tid >> 3) & 7, j = tid & 7;
        float val = (j >= ii) ? s : -INFINITY;
        float m = val;
        #pragma unroll
        for (int off = 1; off < 8; off <<= 1) m = fmaxf(m, __shfl_xor(m, off, 8));
        float ex = __expf(val - m);
        float su = ex;
        #pragma unroll
        for (int off = 1; off < 8; off <<= 1) su += __shfl_xor(su, off, 8);
        Rs[tid] = ex / su;
    }
    #pragma unroll
    for (int i = 0; i < 2; i++) {
        int u = tid + i * 512, t = u >> 6, hd = u & 63;
        Vl[t * 64 + hd] = Vb_in[(size_t)(rows0 + t) * 64 + hd];
    }
    __syncthreads();
    // ---- ab = V @ R -> abl (bf16, swizzled A) ----
    #pragma unroll
    for (int i = 0; i < 2; i++) {
        int u = tid + i * 512, t = u >> 6, hd = u & 63, h = hd >> 3, j = hd & 7;
        float a = 0.0f;
        #pragma unroll
        for (int q = 0; q < 8; q++)
            a += bf2f(Vl[t * 64 + h * 8 + q]) * Rs[h * 64 + q * 8 + j];
        abl[t * 64 + (((hd * 2) ^ ((t & 7) << 4)) >> 1)] = f2bf(a);
    }
    // ---- proj: 16x256 = abl(16x64) @ WoT(256x64) ----
    s16x8 rbv[4];
    #pragma unroll
    for (int i = 0; i < 4; i++) {
        int u = tid + i * 512, r = u >> 3, ch = u & 7;
        rbv[i] = *(const s16x8*)&WoT[(size_t)r * 64 + ch * 8];
    }
    __syncthreads();
    #pragma unroll
    for (int i = 0; i < 4; i++) {
        int u = tid + i * 512, r = u >> 3, ch = u & 7;
        *(s16x8*)&Bs[r * 64 + (((ch * 16) ^ ((r & 7) << 4)) >> 1)] = rbv[i];
    }
    __syncthreads();
    f32x4 acc[2];
    acc[0] = (f32x4)0.0f; acc[1] = (f32x4)0.0f;
    #pragma unroll
    for (int kk = 0; kk < 2; kk++) {
        int kbyte = kk * 64 + fkb;
        s16x8 af = *(const s16x8*)&abl[fr * 64 + ((kbyte ^ ((fr & 7) << 4)) >> 1)];
        #pragma unroll
        for (int n = 0; n < 2; n++) {
            int brow = wn * 32 + n * 16 + fr;
            s16x8 bfv = *(const s16x8*)&Bs[brow * 64 + ((kbyte ^ ((brow & 7) << 4)) >> 1)];
            acc[n] = __builtin_amdgcn_mfma_f32_16x16x32_bf16(af, bfv, acc[n], 0, 0, 0);
        }
    }
    float xn[2][4];
    #pragma unroll
    for (int n = 0; n < 2; n++) {
        int col = colv[n];
        float bbv = bo[col];
        #pragma unroll
        for (int r = 0; r < 4; r++)
            xn[n][r] = acc[n][r] + bbv + x[(size_t)(rows0 + rbase + r) * 256 + col];
    }
    // ---- LN(ln2) -> h2s ----
    #pragma unroll
    for (int r = 0; r < 4; r++) {
        float s1 = xn[0][r] + xn[1][r];
        float s2 = xn[0][r] * xn[0][r] + xn[1][r] * xn[1][r];
        #pragma unroll
        for (int off = 1; off < 16; off <<= 1) {
            s1 += __shfl_xor(s1, off);
            s2 += __shfl_xor(s2, off);
        }
        if (fr == 0) { red1[rbase + r][wn] = s1; red2[rbase + r][wn] = s2; }
    }
    __syncthreads();
    if (tid < 16) {
        float s1 = 0.f, s2 = 0.f;
        #pragma unroll
        for (int w = 0; w < 8; w++) { s1 += red1[tid][w]; s2 += red2[tid][w]; }
        float mean = s1 * (1.0f / 256.0f);
        float var = s2 * (1.0f / 256.0f) - mean * mean;
        mrow[tid] = mean;
        rrow[tid] = rsqrtf(var + 1e-5f);
    }
    __syncthreads();
    #pragma unroll
    for (int n = 0; n < 2; n++) {
        int col = colv[n];
        float lsv = ls2[col], lbv = lb2[col];
        #pragma unroll
        for (int r = 0; r < 4; r++) {
            int rl = rbase + r;
            float hv = (xn[n][r] - mrow[rl]) * rrow[rl] * lsv + lbv;
            h2s[rl * 256 + (((col * 2) ^ ((rl & 7) << 4)) >> 1)] = f2bf(hv);
        }
    }
    // ---- MLP1: ff = relu(h2 @ W1T + b1), 4 chunks of 256 cols, ff stays in LDS ----
    #pragma unroll 1
    for (int c = 0; c < 4; c++) {
        const ushort* Bg = W1T + (size_t)c * 256 * 256;
        acc[0] = (f32x4)0.0f; acc[1] = (f32x4)0.0f;
        #pragma unroll
        for (int i = 0; i < 4; i++) {
            int u = tid + i * 512, r = u >> 3, ch = u & 7;
            rbv[i] = *(const s16x8*)&Bg[(size_t)r * 256 + ch * 8];
        }
        #pragma unroll 1
        for (int kt = 0; kt < 4; kt++) {
            __syncthreads();
            #pragma unroll
            for (int i = 0; i < 4; i++) {
                int u = tid + i * 512, r = u >> 3, ch = u & 7;
                *(s16x8*)&Bs[r * 64 + (((ch * 16) ^ ((r & 7) << 4)) >> 1)] = rbv[i];
            }
            __syncthreads();
            if (kt < 3) {
                int k0 = (kt + 1) * 64;
                #pragma unroll
                for (int i = 0; i < 4; i++) {
                    int u = tid + i * 512, r = u >> 3, ch = u & 7;
                    rbv[i] = *(const s16x8*)&Bg[(size_t)r * 256 + k0 + ch * 8];
                }
            }
            #pragma unroll
            for (int kk = 0; kk < 2; kk++) {
                int kbyte = kt * 128 + kk * 64 + fkb;
                s16x8 af = *(const s16x8*)&h2s[fr * 256 + ((kbyte ^ ((fr & 7) << 4)) >> 1)];
                int kb2 = kk * 64 + fkb;
                #pragma unroll
                for (int n = 0; n < 2; n++) {
                    int brow = wn * 32 + n * 16 + fr;
                    s16x8 bfv = *(const s16x8*)&Bs[brow * 64 + ((kb2 ^ ((brow & 7) << 4)) >> 1)];
                    acc[n] = __builtin_amdgcn_mfma_f32_16x16x32_bf16(af, bfv, acc[n], 0, 0, 0);
                }
            }
        }
        #pragma unroll
        for (int n = 0; n < 2; n++) {
            int col = c * 256 + colv[n];
            float bb1 = b1[col];
            #pragma unroll
            for (int r = 0; r < 4; r++) {
                int rl = rbase + r;
                ffs[rl * 1024 + (((col * 2) ^ ((rl & 7) << 4)) >> 1)] =
                    f2bf(fmaxf(acc[n][r] + bb1, 0.0f));
            }
        }
    }
    // ---- MLP2: x += ffs @ W2T + b2 (K=1024) ----
    f32x4 a2[2];
    a2[0] = (f32x4)0.0f; a2[1] = (f32x4)0.0f;
    #pragma unroll
    for (int i = 0; i < 4; i++) {
        int u = tid + i * 512, r = u >> 3, ch = u & 7;
        rbv[i] = *(const s16x8*)&W2T[(size_t)r * 1024 + ch * 8];
    }
    #pragma unroll 1
    for (int kt = 0; kt < 16; kt++) {
        __syncthreads();
        #pragma unroll
        for (int i = 0; i < 4; i++) {
            int u = tid + i * 512, r = u >> 3, ch = u & 7;
            *(s16x8*)&Bs[r * 64 + (((ch * 16) ^ ((r & 7) << 4)) >> 1)] = rbv[i];
        }
        __syncthreads();
        if (kt < 15) {
            int k0 = (kt + 1) * 64;
            #pragma unroll
            for (int i = 0; i < 4; i++) {
                int u = tid + i * 512, r = u >> 3, ch = u & 7;
                rbv[i] = *(const s16x8*)&W2T[(size_t)r * 1024 + k0 + ch * 8];
            }
        }
        #pragma unroll
        for (int kk = 0; kk < 2; kk++) {
            int kbyte = kt * 128 + kk * 64 + fkb;
            s16x8 af = *(const s16x8*)&ffs[fr * 1024 + ((kbyte ^ ((fr & 7) << 4)) >> 1)];
            int kb2 = kk * 64 + fkb;
            #pragma unroll
            for (int n = 0; n < 2; n++) {
                int brow = wn * 32 + n * 16 + fr;
                s16x8 bfv = *(const s16x8*)&Bs[brow * 64 + ((kb2 ^ ((brow & 7) << 4)) >> 1)];
                a2[n] = __builtin_amdgcn_mfma_f32_16x16x32_bf16(af, bfv, a2[n], 0, 0, 0);
            }
        }
    }
    #pragma unroll
    for (int n = 0; n < 2; n++) {
        int col = colv[n];
        float bb2 = b2[col];
        #pragma unroll
        for (int r = 0; r < 4; r++) {
            float v = xn[n][r] + a2[n][r] + bb2;
            xn[n][r] = v;
            x[(size_t)(rows0 + rbase + r) * 256 + col] = v;
        }
    }
    // ---- LN(next ln1 / lnf) -> h2s (and global hb if last layer) ----
    __syncthreads();
    #pragma unroll
    for (int r = 0; r < 4; r++) {
        float s1 = xn[0][r] + xn[1][r];
        float s2 = xn[0][r] * xn[0][r] + xn[1][r] * xn[1][r];
        #pragma unroll
        for (int off = 1; off < 16; off <<= 1) {
            s1 += __shfl_xor(s1, off);
            s2 += __shfl_xor(s2, off);
        }
        if (fr == 0) { red1[rbase + r][wn] = s1; red2[rbase + r][wn] = s2; }
    }
    __syncthreads();
    if (tid < 16) {
        float s1 = 0.f, s2 = 0.f;
        #pragma unroll
        for (int w = 0; w < 8; w++) { s1 += red1[tid][w]; s2 += red2[tid][w]; }
        float mean = s1 * (1.0f / 256.0f);
        float var = s2 * (1.0f / 256.0f) - mean * mean;
        mrow[tid] = mean;
        rrow[tid] = rsqrtf(var + 1e-5f);
    }
    __syncthreads();
    #pragma unroll
    for (int n = 0; n < 2; n++) {
        int col = colv[n];
        float lsv = nls[col], lbv = nlb[col];
        #pragma unroll
        for (int r = 0; r < 4; r++) {
            int rl = rbase + r;
            float hv = (xn[n][r] - mrow[rl]) * rrow[rl] * lsv + lbv;
            ushort hu = f2bf(hv);
            h2s[rl * 256 + (((col * 2) ^ ((rl & 7) << 4)) >> 1)] = hu;
            if (mode == 0)
                hbout[(size_t)(rows0 + rl) * 256 + col] = hu;
        }
    }
    if (mode == 0) return;

    // ---- QKV for next layer: kqv = h2 @ WqkvT_next (K=256), A from h2s ----
    float* kqv = (float*)ffs;   // 16 x 193 floats, aliases ffs (dead now)
    acc[0] = (f32x4)0.0f; acc[1] = (f32x4)0.0f;
    #pragma unroll
    for (int i = 0; i < 4; i++) {
        int u = tid + i * 512, r = u >> 3, ch = u & 7;
        rbv[i] = *(const s16x8*)&WqkvT_next[(size_t)r * 256 + ch * 8];
    }
    #pragma unroll 1
    for (int kt = 0; kt < 4; kt++) {
        __syncthreads();
        #pragma unroll
        for (int i = 0; i < 4; i++) {
            int u = tid + i * 512, r = u >> 3, ch = u & 7;
            *(s16x8*)&Bs[r * 64 + (((ch * 16) ^ ((r & 7) << 4)) >> 1)] = rbv[i];
        }
        __syncthreads();
        if (kt < 3) {
            int k0 = (kt + 1) * 64;
            #pragma unroll
            for (int i = 0; i < 4; i++) {
                int u = tid + i * 512, r = u >> 3, ch = u & 7;
                rbv[i] = *(const s16x8*)&WqkvT_next[(size_t)r * 256 + k0 + ch * 8];
            }
        }
        #pragma unroll
        for (int kk = 0; kk < 2; kk++) {
            int kbyte = kt * 128 + kk * 64 + fkb;
            s16x8 af = *(const s16x8*)&h2s[fr * 256 + ((kbyte ^ ((fr & 7) << 4)) >> 1)];
            int kb2 = kk * 64 + fkb;
            #pragma unroll
            for (int n = 0; n < 2; n++) {
                int brow = wn * 32 + n * 16 + fr;
                s16x8 bfv = *(const s16x8*)&Bs[brow * 64 + ((kb2 ^ ((brow & 7) << 4)) >> 1)];
                acc[n] = __builtin_amdgcn_mfma_f32_16x16x32_bf16(af, bfv, acc[n], 0, 0, 0);
            }
        }
    }
    __syncthreads();   // ffs reads (MLP2) long done; safe to write kqv
    #pragma unroll
    for (int n = 0; n < 2; n++) {
        int col = wn * 32 + n * 16 + fr;
        if (col < 192) {
            #pragma unroll
            for (int r = 0; r < 4; r++)
                kqv[(rbase + r) * 193 + col] = acc[n][r];
        }
    }
    __syncthreads();
    #pragma unroll
    for (int i = 0; i < 2; i++) {
        int u = tid + i * 512, t = u >> 6, hd = u & 63;
        Vb_out[(size_t)(rows0 + t) * 64 + hd] = f2bf(kqv[t * 193 + 128 + hd]);
    }
    {
        int h = tid >> 6, i2 = (tid >> 3) & 7, j = tid & 7;
        float s = 0.0f;
        #pragma unroll
        for (int t = 0; t < 16; t++)
            s += kqv[t * 193 + 64 + h * 8 + i2] * kqv[t * 193 + h * 8 + j];
        int part = (rows0 >> 4) & 31;
        Rpart_out[(size_t)(b * 32 + part) * 512 + tid] = s;
    }
}

// ================= logits GEMM: 128x256 tile, 512 thr, LDS-staged, coalesced epilogue =================
__global__ __launch_bounds__(512, 4) void gpt_logits_mfma(const ushort* __restrict__ hb, const ushort* __restrict__ WfT,
                                                          const float* __restrict__ bfb, float* __restrict__ out,
                                                          float2* __restrict__ lsebuf) {
    __shared__ __align__(16) ushort smem[8192 + 16384];   // 48 KB: As(16K) + Bs(32K)
    ushort* As = smem;
    ushort* Bs = smem + 8192;
    f32x4 acc[4][4];
    // XCD-bijective swizzle: 6304 blocks = 8 * 788
    int flat = blockIdx.y * 32 + blockIdx.x;
    int nf = (flat & 7) * 788 + (flat >> 3);
    int rb = nf & 31, cb = nf >> 5;
    int row0 = rb * 128, c0 = cb * 256;
    const int tid = threadIdx.x, lane = tid & 63, wid = tid >> 6;
    const int wm = wid >> 2, wn = wid & 3;           // 2 x 4 waves, 64x64 each
    const int fr = lane & 15, fkb = (lane >> 4) * 16;
    const int rbase = (lane >> 4) * 4;

    #pragma unroll
    for (int m = 0; m < 4; m++)
        #pragma unroll
        for (int n = 0; n < 4; n++) acc[m][n] = (f32x4)0.0f;

    s16x8 ra[2], rbv[4];
    #pragma unroll
    for (int i = 0; i < 2; i++) {
        int u = tid + i * 512, r = u >> 3, ch = u & 7;
        ra[i] = *(const s16x8*)&hb[(size_t)(row0 + r) * 256 + ch * 8];
    }
    #pragma unroll
    for (int i = 0; i < 4; i++) {
        int u = tid + i * 512, r = u >> 3, ch = u & 7;
        rbv[i] = *(const s16x8*)&WfT[(size_t)(c0 + r) * 256 + ch * 8];
    }
    #pragma unroll 1
    for (int kt = 0; kt < 4; kt++) {
        if (kt) __syncthreads();
        #pragma unroll
        for (int i = 0; i < 2; i++) {
            int u = tid + i * 512, r = u >> 3, ch = u & 7;
            *(s16x8*)&As[r * 64 + (((ch * 16) ^ ((r & 7) << 4)) >> 1)] = ra[i];
        }
        #pragma unroll
        for (int i = 0; i < 4; i++) {
            int u = tid + i * 512, r = u >> 3, ch = u & 7;
            *(s16x8*)&Bs[r * 64 + (((ch * 16) ^ ((r & 7) << 4)) >> 1)] = rbv[i];
        }
        __syncthreads();
        if (kt < 3) {
            int k0 = (kt + 1) * 64;
            #pragma unroll
            for (int i = 0; i < 2; i++) {
                int u = tid + i * 512, r = u >> 3, ch = u & 7;
                ra[i] = *(const s16x8*)&hb[(size_t)(row0 + r) * 256 + k0 + ch * 8];
            }
            #pragma unroll
            for (int i = 0; i < 4; i++) {
                int u = tid + i * 512, r = u >> 3, ch = u & 7;
                rbv[i] = *(const s16x8*)&WfT[(size_t)(c0 + r) * 256 + k0 + ch * 8];
            }
        }
        #pragma unroll
        for (int kk = 0; kk < 2; kk++) {
            int kbyte = kk * 64 + fkb;
            s16x8 af[4], bfr[4];
            #pragma unroll
            for (int m = 0; m < 4; m++) {
                int arow = wm * 64 + m * 16 + fr;
                af[m] = *(const s16x8*)&As[arow * 64 + ((kbyte ^ ((arow & 7) << 4)) >> 1)];
            }
            #pragma unroll
            for (int n = 0; n < 4; n++) {
                int brow = wn * 64 + n * 16 + fr;
                bfr[n] = *(const s16x8*)&Bs[brow * 64 + ((kbyte ^ ((brow & 7) << 4)) >> 1)];
            }
            #pragma unroll
            for (int m = 0; m < 4; m++)
                #pragma unroll
                for (int n = 0; n < 4; n++)
                    acc[m][n] = __builtin_amdgcn_mfma_f32_16x16x32_bf16(af[m], bfr[n], acc[m][n], 0, 0, 0);
        }
    }
    // ---- epilogue: bias, LDS transpose, coalesced float4 stores, lse partials ----
    float bb[4]; int gcv[4];
    #pragma unroll
    for (int n = 0; n < 4; n++) {
        int gc = c0 + wn * 64 + n * 16 + fr;
        gcv[n] = gc;
        bb[n] = (gc < V_SZ) ? bfb[gc] : 0.0f;
    }
    __syncthreads();                                     // all LDS MFMA reads done
    float* tb = (float*)smem;                            // 32 rows x 256 cols f32 = 32 KB
    float2 (*red)[4] = (float2(*)[4])(smem + 16384);     // byte 32768, 4 KB (disjoint from tb)
    const bool fastcol = (c0 + 256 <= V_SZ);
    #pragma unroll 1
    for (int m = 0; m < 4; m++) {
        #pragma unroll
        for (int r = 0; r < 4; r++) {
            int lrow = wm * 16 + rbase + r;              // 0..31
            float v[4];
            float vmax = -1e30f;
            #pragma unroll
            for (int n = 0; n < 4; n++) {
                v[n] = (gcv[n] < V_SZ) ? acc[m][n][r] + bb[n] : -1e30f;
                vmax = fmaxf(vmax, v[n]);
                tb[lrow * 256 + wn * 64 + n * 16 + fr] = v[n];
            }
            #pragma unroll
            for (int off = 1; off < 16; off <<= 1)
                vmax = fmaxf(vmax, __shfl_xor(vmax, off));
            float vsum = __expf(v[0] - vmax) + __expf(v[1] - vmax)
                       + __expf(v[2] - vmax) + __expf(v[3] - vmax);
            #pragma unroll
            for (int off = 1; off < 16; off <<= 1)
                vsum += __shfl_xor(vsum, off);
            int rloc = wm * 64 + m * 16 + rbase + r;
            if ((lane & 15) == 0)
                red[rloc][wn] = make_float2(vmax, vsum);
        }
        __syncthreads();
        // coalesced store: 32 rows x 256 cols, each thread 4 float4
        #pragma unroll
        for (int i = 0; i < 4; i++) {
            int f = tid + i * 512;                       // 0..2047
            int lr = f >> 6, lc4 = (f & 63) * 4;
            int grow = row0 + ((lr < 16) ? (m * 16 + lr) : (64 + m * 16 + lr - 16));
            int gcol = c0 + lc4;
            float4 val = *(float4*)&tb[lr * 256 + lc4];
            float* dst = &out[(size_t)grow * V_SZ + gcol];
            if (fastcol) {
                __builtin_memcpy(dst, &val, 16);         // 4B-aligned dwordx4 (gfx950 unaligned-ok)
            } else {
                if (gcol + 0 < V_SZ) dst[0] = val.x;
                if (gcol + 1 < V_SZ) dst[1] = val.y;
                if (gcol + 2 < V_SZ) dst[2] = val.z;
                if (gcol + 3 < V_SZ) dst[3] = val.w;
            }
        }
        __syncthreads();
    }
    if (tid < 128) {
        float M = -1e30f, S = 0.0f;
        #pragma unroll
        for (int w = 0; w < 4; w++) {
            float2 p = red[tid][w];
            float M2 = fmaxf(M, p.x);
            S = S * __expf(M - M2) + p.y * __expf(p.x - M2);
            M = M2;
        }
        lsebuf[(size_t)(row0 + tid) * NCB + cb] = make_float2(M, S);
    }
}

// ================= lse finish =================
__global__ __launch_bounds__(256) void gpt_lse(const float2* __restrict__ lsebuf, const float* __restrict__ out,
                                               const int* __restrict__ tgt, float* __restrict__ partial) {
    int wave = threadIdx.x >> 6, lane = threadIdx.x & 63;
    int row = blockIdx.x * 4 + wave;
    float m = -INFINITY, s = 0.0f;
    for (int i = lane; i < NCB; i += 64) {
        float2 p = lsebuf[(size_t)row * NCB + i];
        float M = fmaxf(m, p.x);
        s = s * __expf(m - M) + p.y * __expf(p.x - M);
        m = M;
    }
    #pragma unroll
    for (int off = 1; off < 64; off <<= 1) {
        float m2 = __shfl_xor(m, off);
        float s2 = __shfl_xor(s, off);
        float M = fmaxf(m, m2);
        s = s * __expf(m - M) + s2 * __expf(m2 - M);
        m = M;
    }
    if (lane == 0)
        partial[row] = m + logf(s) - out[(size_t)row * V_SZ + tgt[row]];
}

__global__ void gpt_loss_reduce(const float* __restrict__ partial, float* __restrict__ out) {
    __shared__ float red[256];
    int tid = threadIdx.x;
    float s = 0.0f;
    for (int i = tid; i < 4096; i += 256) s += partial[i];
    red[tid] = s;
    __syncthreads();
    for (int off = 128; off > 0; off >>= 1) {
        if (tid < off) red[tid] += red[tid + off];
        __syncthreads();
    }
    if (tid == 0) out[0] = red[0] * (1.0f / 4096.0f);
}

// ======================= fp32 fallback kernels (small-ws path) =======================
__global__ void gpt_embed(const int* __restrict__ tokens, const float* __restrict__ tok_emb,
                          const float* __restrict__ pos_emb, float* __restrict__ x) {
    int idx = blockIdx.x * 256 + threadIdx.x;
    int bt = idx >> 8, e = idx & 255;
    int t = bt & 511;
    int tok = tokens[bt];
    x[idx] = tok_emb[tok * 256 + e] + pos_emb[t * 256 + e];
}

__global__ void gpt_ln(const float* __restrict__ x, const float* __restrict__ s,
                       const float* __restrict__ b, float* __restrict__ h) {
    __shared__ float red[256];
    int row = blockIdx.x, e = threadIdx.x;
    float v = x[row * 256 + e];
    red[e] = v;
    __syncthreads();
    for (int off = 128; off > 0; off >>= 1) {
        if (e < off) red[e] += red[e + off];
        __syncthreads();
    }
    float mean = red[0] * (1.0f / 256.0f);
    __syncthreads();
    float d = v - mean;
    red[e] = d * d;
    __syncthreads();
    for (int off = 128; off > 0; off >>= 1) {
        if (e < off) red[e] += red[e + off];
        __syncthreads();
    }
    float rstd = rsqrtf(red[0] * (1.0f / 256.0f) + 1e-5f);
    h[row * 256 + e] = d * rstd * s[e] + b[e];
}

__global__ void gpt_qkv(const float* __restrict__ h, const float* __restrict__ Wq,
                        const float* __restrict__ Wk, const float* __restrict__ Wv,
                        float* __restrict__ Q, float* __restrict__ K, float* __restrict__ Vv) {
    __shared__ float hs[8][256];
    int tid = threadIdx.x;
    int row0 = blockIdx.x * 8;
    #pragma unroll
    for (int r = 0; r < 8; r++) hs[r][tid] = h[(row0 + r) * 256 + tid];
    __syncthreads();
    if (tid < 192) {
        int kind = tid >> 6, o = tid & 63, hh = o >> 3, d = o & 7;
        const float* W = kind == 0 ? Wq : (kind == 1 ? Wk : Wv);
        const float* wp = W + hh * 2048 + d;
        float acc[8];
        #pragma unroll
        for (int r = 0; r < 8; r++) acc[r] = 0.0f;
        for (int e = 0; e < 256; e++) {
            float w = wp[e * 8];
            #pragma unroll
            for (int r = 0; r < 8; r++) acc[r] += hs[r][e] * w;
        }
        float* outp = kind == 0 ? Q : (kind == 1 ? K : Vv);
        int b = row0 >> 9;
        #pragma unroll
        for (int r = 0; r < 8; r++) {
            int t = (row0 + r) & 511;
            outp[((b * 8 + hh) * 512 + t) * 8 + d] = acc[r];
        }
    }
}

__global__ void gpt_attn_r(const float* __restrict__ K, const float* __restrict__ Q,
                           float* __restrict__ R) {
    __shared__ __align__(16) float Ks[64][8];
    __shared__ __align__(16) float Qs[64][8];
    int bh = blockIdx.x, tid = threadIdx.x;
    int i = tid >> 3, j = tid & 7;
    const float* Kb = K + bh * 512 * 8;
    const float* Qb = Q + bh * 512 * 8;
    float acc = 0.0f;
    for (int t0 = 0; t0 < 512; t0 += 64) {
        *(float4*)&Ks[tid][0] = *(const float4*)&Kb[(t0 + tid) * 8];
        *(float4*)&Ks[tid][4] = *(const float4*)&Kb[(t0 + tid) * 8 + 4];
        *(float4*)&Qs[tid][0] = *(const float4*)&Qb[(t0 + tid) * 8];
        *(float4*)&Qs[tid][4] = *(const float4*)&Qb[(t0 + tid) * 8 + 4];
        __syncthreads();
        #pragma unroll 16
        for (int t = 0; t < 64; t++) acc += Ks[t][i] * Qs[t][j];
        __syncthreads();
    }
    acc *= (1.0f / 16.0f);
    float val = (j >= i) ? acc : -INFINITY;
    float m = val;
    #pragma unroll
    for (int off = 1; off < 8; off <<= 1) m = fmaxf(m, __shfl_xor(m, off, 8));
    float ex = expf(val - m);
    float sum = ex;
    #pragma unroll
    for (int off = 1; off < 8; off <<= 1) sum += __shfl_xor(sum, off, 8);
    R[bh * 64 + tid] = ex / sum;
}

__global__ void gpt_attn_out(const float* __restrict__ Vv, const float* __restrict__ R,
                             const float* __restrict__ Wo, const float* __restrict__ bo,
                             float* __restrict__ x) {
    __shared__ __align__(16) float as[8][64];
    int tid = threadIdx.x;
    int row0 = blockIdx.x * 8;
    int b = row0 >> 9;
    #pragma unroll
    for (int k = 0; k < 2; k++) {
        int idx = k * 256 + tid;
        int r = idx >> 6, hd = idx & 63;
        int hh = hd >> 3, jj = hd & 7;
        int t = (row0 + r) & 511;
        const float* vp = Vv + ((b * 8 + hh) * 512 + t) * 8;
        const float* rp = R + (b * 8 + hh) * 64 + jj;
        float a = 0.0f;
        #pragma unroll
        for (int i = 0; i < 8; i++) a += vp[i] * rp[i * 8];
        as[r][hd] = a;
    }
    __syncthreads();
    float acc[8];
    float bb = bo[tid];
    #pragma unroll
    for (int r = 0; r < 8; r++) acc[r] = bb;
    for (int hd0 = 0; hd0 < 64; hd0 += 4) {
        float w0 = Wo[(hd0 + 0) * 256 + tid];
        float w1 = Wo[(hd0 + 1) * 256 + tid];
        float w2 = Wo[(hd0 + 2) * 256 + tid];
        float w3 = Wo[(hd0 + 3) * 256 + tid];
        #pragma unroll
        for (int r = 0; r < 8; r++) {
            float4 av = *(const float4*)&as[r][hd0];
            acc[r] += av.x * w0 + av.y * w1 + av.z * w2 + av.w * w3;
        }
    }
    #pragma unroll
    for (int r = 0; r < 8; r++) x[(row0 + r) * 256 + tid] += acc[r];
}

__global__ __launch_bounds__(256) void gpt_mlp(const float* __restrict__ h, const float* __restrict__ W1,
                         const float* __restrict__ b1, const float* __restrict__ W2,
                         const float* __restrict__ b2, float* __restrict__ x) {
    __shared__ __align__(16) float hs[8][256];
    __shared__ __align__(16) float ffs[8][1024];
    int tid = threadIdx.x;
    int row0 = blockIdx.x * 8;
    #pragma unroll
    for (int r = 0; r < 8; r++) hs[r][tid] = h[(row0 + r) * 256 + tid];
    __syncthreads();
    {
        float acc[4][8];
        #pragma unroll
        for (int k = 0; k < 4; k++) {
            float bb = b1[k * 256 + tid];
            #pragma unroll
            for (int r = 0; r < 8; r++) acc[k][r] = bb;
        }
        for (int e0 = 0; e0 < 256; e0 += 4) {
            float w[4][4];
            #pragma unroll
            for (int ee = 0; ee < 4; ee++)
                #pragma unroll
                for (int k = 0; k < 4; k++)
                    w[ee][k] = W1[(e0 + ee) * 1024 + k * 256 + tid];
            #pragma unroll
            for (int r = 0; r < 8; r++) {
                float4 hv = *(const float4*)&hs[r][e0];
                #pragma unroll
                for (int k = 0; k < 4; k++)
                    acc[k][r] += hv.x * w[0][k] + hv.y * w[1][k] + hv.z * w[2][k] + hv.w * w[3][k];
            }
        }
        #pragma unroll
        for (int k = 0; k < 4; k++)
            #pragma unroll
            for (int r = 0; r < 8; r++)
                ffs[r][k * 256 + tid] = fmaxf(acc[k][r], 0.0f);
    }
    __syncthreads();
    {
        float acc[8];
        float bb = b2[tid];
        #pragma unroll
        for (int r = 0; r < 8; r++) acc[r] = bb;
        for (int f0 = 0; f0 < 1024; f0 += 4) {
            float w0 = W2[(f0 + 0) * 256 + tid];
            float w1 = W2[(f0 + 1) * 256 + tid];
            float w2 = W2[(f0 + 2) * 256 + tid];
            float w3 = W2[(f0 + 3) * 256 + tid];
            #pragma unroll
            for (int r = 0; r < 8; r++) {
                float4 fv = *(const float4*)&ffs[r][f0];
                acc[r] += fv.x * w0 + fv.y * w1 + fv.z * w2 + fv.w * w3;
            }
        }
        #pragma unroll
        for (int r = 0; r < 8; r++) x[(row0 + r) * 256 + tid] += acc[r];
    }
}

__global__ __launch_bounds__(256) void gpt_logits(const float* __restrict__ hf, const float* __restrict__ Wf,
                            const float* __restrict__ bf, float* __restrict__ out) {
    __shared__ __align__(16) float hs[32][256];
    int tid = threadIdx.x;
    int row0 = blockIdx.y * 32;
    #pragma unroll
    for (int r = 0; r < 32; r++) hs[r][tid] = hf[(row0 + r) * 256 + tid];
    __syncthreads();
    int c0 = blockIdx.x * 512 + tid;
    int c1 = c0 + 256;
    int c0c = c0 < V_SZ ? c0 : V_SZ - 1;
    int c1c = c1 < V_SZ ? c1 : V_SZ - 1;
    float acc0[32], acc1[32];
    float b0 = bf[c0c], b1 = bf[c1c];
    #pragma unroll
    for (int r = 0; r < 32; r++) { acc0[r] = b0; acc1[r] = b1; }
    const float* p0 = Wf + c0c;
    const float* p1 = Wf + c1c;
    for (int e0 = 0; e0 < 256; e0 += 4) {
        float w00 = p0[(size_t)(e0 + 0) * V_SZ];
        float w01 = p0[(size_t)(e0 + 1) * V_SZ];
        float w02 = p0[(size_t)(e0 + 2) * V_SZ];
        float w03 = p0[(size_t)(e0 + 3) * V_SZ];
        float w10 = p1[(size_t)(e0 + 0) * V_SZ];
        float w11 = p1[(size_t)(e0 + 1) * V_SZ];
        float w12 = p1[(size_t)(e0 + 2) * V_SZ];
        float w13 = p1[(size_t)(e0 + 3) * V_SZ];
        #pragma unroll
        for (int r = 0; r < 32; r++) {
            float4 hv = *(const float4*)&hs[r][e0];
            acc0[r] += hv.x * w00 + hv.y * w01 + hv.z * w02 + hv.w * w03;
            acc1[r] += hv.x * w10 + hv.y * w11 + hv.z * w12 + hv.w * w13;
        }
    }
    if (c0 < V_SZ) {
        #pragma unroll
        for (int r = 0; r < 32; r++) out[(size_t)(row0 + r) * V_SZ + c0] = acc0[r];
    }
    if (c1 < V_SZ) {
        #pragma unroll
        for (int r = 0; r < 32; r++) out[(size_t)(row0 + r) * V_SZ + c1] = acc1[r];
    }
}

__global__ void gpt_loss(const float* __restrict__ logits, const int* __restrict__ tgt,
                         float* __restrict__ partial) {
    __shared__ float ms[256], ss[256];
    int row = blockIdx.x, tid = threadIdx.x;
    const float* lr = logits + (size_t)row * V_SZ;
    float m = -INFINITY, s = 0.0f;
    for (int c = tid; c < V_SZ; c += 256) {
        float v = lr[c];
        float nm = fmaxf(m, v);
        s = s * expf(m - nm) + expf(v - nm);
        m = nm;
    }
    ms[tid] = m; ss[tid] = s;
    __syncthreads();
    for (int off = 128; off > 0; off >>= 1) {
        if (tid < off) {
            float m2 = ms[tid + off], s2 = ss[tid + off];
            float M = fmaxf(ms[tid], m2);
            ss[tid] = ss[tid] * expf(ms[tid] - M) + s2 * expf(m2 - M);
            ms[tid] = M;
        }
        __syncthreads();
    }
    if (tid == 0) {
        float lse = ms[0] + logf(ss[0]);
        partial[row] = lse - lr[tgt[row]];
    }
}

// ======================= launch =======================
extern "C" void kernel_launch(void* const* d_in, const int* in_sizes, int n_in,
                              void* d_out, int out_size, void* d_ws, size_t ws_size,
                              hipStream_t stream) {
    const int*   tokens  = (const int*)d_in[0];
    const int*   ideal   = (const int*)d_in[1];
    const float* tok_emb = (const float*)d_in[2];
    const float* pos_emb = (const float*)d_in[3];
    const float* Wq      = (const float*)d_in[4];
    const float* Wk      = (const float*)d_in[5];
    const float* Wv      = (const float*)d_in[6];
    const float* Wo      = (const float*)d_in[7];
    const float* bo      = (const float*)d_in[8];
    const float* ln1_s   = (const float*)d_in[9];
    const float* ln1_b   = (const float*)d_in[10];
    const float* W1      = (const float*)d_in[11];
    const float* b1      = (const float*)d_in[12];
    const float* W2      = (const float*)d_in[13];
    const float* b2      = (const float*)d_in[14];
    const float* ln2_s   = (const float*)d_in[15];
    const float* ln2_b   = (const float*)d_in[16];
    const float* lnf_s   = (const float*)d_in[17];
    const float* lnf_b   = (const float*)d_in[18];
    const float* Wf      = (const float*)d_in[19];
    const float* bf      = (const float*)d_in[20];
    float* out = (float*)d_out;

    // ---- workspace layout (bf16 path) ----
    size_t off = 0;
    char* wsc = (char*)d_ws;
    ushort* WfT   = (ushort*)(wsc + off); off += (size_t)NPAD * 256 * 2;
    ushort* W1T   = (ushort*)(wsc + off); off += (size_t)16 * 1024 * 256 * 2;
    ushort* W2T   = (ushort*)(wsc + off); off += (size_t)16 * 256 * 1024 * 2;
    ushort* WqkvT = (ushort*)(wsc + off); off += (size_t)16 * 256 * 256 * 2;
    ushort* WoT   = (ushort*)(wsc + off); off += (size_t)16 * 256 * 64 * 2;
    ushort* hb    = (ushort*)(wsc + off); off += (size_t)4096 * 256 * 2;
    ushort* Vb0   = (ushort*)(wsc + off); off += (size_t)4096 * 64 * 2;
    ushort* Vb1   = (ushort*)(wsc + off); off += (size_t)4096 * 64 * 2;
    float*  x     = (float*)(wsc + off);  off += (size_t)4096 * 256 * 4;
    float*  Rp0   = (float*)(wsc + off);  off += (size_t)8 * 32 * 512 * 4;
    float*  Rp1   = (float*)(wsc + off);  off += (size_t)8 * 32 * 512 * 4;
    float*  partial = (float*)(wsc + off); off += (size_t)4096 * 4;
    float2* lsebuf = (float2*)(wsc + off); off += (size_t)4096 * NCB * 8;
    bool big = ws_size >= off;

    if (big) {
        cvt_transpose<<<dim3(16, 4, 16), 256, 0, stream>>>(W1, W1T, 256, 1024, 1024, 262144, 262144);
        cvt_transpose<<<dim3(4, 16, 16), 256, 0, stream>>>(W2, W2T, 1024, 256, 256, 262144, 262144);
        cvt_transpose<<<dim3(4, 1, 16), 256, 0, stream>>>(Wo, WoT, 64, 256, 256, 16384, 16384);
        cvt_transpose<<<dim3(788, 4, 1), 256, 0, stream>>>(Wf, WfT, 256, V_SZ, V_SZ, 0, 0);
        cvt_qkv<<<dim3(16, 3), 256, 0, stream>>>(Wq, Wk, Wv, WqkvT);

        gpt_embed_ln<<<1024, 256, 0, stream>>>(tokens, tok_emb, pos_emb, ln1_s, ln1_b, x, hb);
        gpt_pre<<<256, 512, 0, stream>>>(hb, WqkvT, Vb0, Rp0);

        for (int l = 0; l < 16; l++) {
            const float* nls = (l < 15) ? ln1_s + (l + 1) * 256 : lnf_s;
            const float* nlb = (l < 15) ? ln1_b + (l + 1) * 256 : lnf_b;
            const float* Rin = (l & 1) ? Rp1 : Rp0;
            const ushort* Vin = (l & 1) ? Vb1 : Vb0;
            float* Rout = (l & 1) ? Rp0 : Rp1;
            ushort* Vout = (l & 1) ? Vb0 : Vb1;
            int mode = (l < 15) ? 1 : 0;
            const ushort* Wnext = WqkvT + (size_t)((l < 15) ? (l + 1) : 0) * 65536;
            gpt_layer<<<256, 512, 0, stream>>>(Rin, Vin,
                                               WoT + (size_t)l * 16384, bo + l * 256,
                                               W1T + (size_t)l * 262144, b1 + l * 1024,
                                               W2T + (size_t)l * 262144, b2 + l * 256,
                                               ln2_s + l * 256, ln2_b + l * 256,
                                               nls, nlb, x,
                                               Wnext, Vout, Rout, hb, mode);
        }

        gpt_logits_mfma<<<dim3(32, NCB), 512, 0, stream>>>(hb, WfT, bf, out, lsebuf);
        gpt_lse<<<1024, 256, 0, stream>>>(lsebuf, out, ideal, partial);
        gpt_loss_reduce<<<1, 256, 0, stream>>>(partial, out + (size_t)4096 * V_SZ);
    } else {
        // fp32 fallback
        float* fx  = (float*)d_ws;
        float* fh  = fx + 4096 * 256;
        float* fQ  = fh + 4096 * 256;
        float* fK  = fQ + 4096 * 64;
        float* fV  = fK + 4096 * 64;
        float* fR  = fV + 4096 * 64;
        float* fpart = fR + 64 * 64;
        gpt_embed<<<4096, 256, 0, stream>>>(tokens, tok_emb, pos_emb, fx);
        for (int l = 0; l < 16; l++) {
            gpt_ln<<<4096, 256, 0, stream>>>(fx, ln1_s + l * 256, ln1_b + l * 256, fh);
            gpt_qkv<<<512, 256, 0, stream>>>(fh, Wq + l * 16384, Wk + l * 16384, Wv + l * 16384, fQ, fK, fV);
            gpt_attn_r<<<64, 64, 0, stream>>>(fK, fQ, fR);
            gpt_attn_out<<<512, 256, 0, stream>>>(fV, fR, Wo + l * 16384, bo + l * 256, fx);
            gpt_ln<<<4096, 256, 0, stream>>>(fx, ln2_s + l * 256, ln2_b + l * 256, fh);
            gpt_mlp<<<512, 256, 0, stream>>>(fh, W1 + l * 262144, b1 + l * 1024, W2 + l * 262144, b2 + l * 256, fx);
        }
        gpt_ln<<<4096, 256, 0, stream>>>(fx, lnf_s, lnf_b, fh);
        dim3 lg(99, 128);
        gpt_logits<<<lg, 256, 0, stream>>>(fh, Wf, bf, out);
        gpt_loss<<<4096, 256, 0, stream>>>(out, ideal, fpart);
        gpt_loss_reduce<<<1, 256, 0, stream>>>(fpart, out + (size_t)4096 * V_SZ);
    }
}

// Round 11
// 1170.943 us; speedup vs baseline: 1.8004x; 1.8004x over previous
//
#include <hip/hip_runtime.h>
#include <math.h>

#define V_SZ 50257
#define NPAD 50432   // 197 * 256
#define NCB 197

typedef short s16x8 __attribute__((ext_vector_type(8)));
typedef ushort u16x4 __attribute__((ext_vector_type(4)));
typedef float f32x4 __attribute__((ext_vector_type(4)));

__device__ __forceinline__ ushort f2bf(float x) {
    union { float f; unsigned u; } v; v.f = x;
    unsigned r = v.u + 0x7FFF + ((v.u >> 16) & 1);   // RNE
    return (ushort)(r >> 16);
}
__device__ __forceinline__ float bf2f(ushort u) {
    union { unsigned u; float f; } v; v.u = ((unsigned)u) << 16; return v.f;
}

// ================= embed + ln1(layer0): wave per row =================
__global__ __launch_bounds__(256) void gpt_embed_ln(const int* __restrict__ tokens,
                                                    const float* __restrict__ tok_emb,
                                                    const float* __restrict__ pos_emb,
                                                    const float* __restrict__ s, const float* __restrict__ b,
                                                    float* __restrict__ x, ushort* __restrict__ hb) {
    int wave = threadIdx.x >> 6, lane = threadIdx.x & 63;
    int row = blockIdx.x * 4 + wave;
    int t = row & 511;
    int tok = tokens[row];
    float4 te = ((const float4*)(tok_emb + tok * 256))[lane];
    float4 pe = ((const float4*)(pos_emb + t * 256))[lane];
    float4 v = make_float4(te.x + pe.x, te.y + pe.y, te.z + pe.z, te.w + pe.w);
    ((float4*)(x + row * 256))[lane] = v;
    float sum = v.x + v.y + v.z + v.w;
    #pragma unroll
    for (int off = 1; off < 64; off <<= 1) sum += __shfl_xor(sum, off);
    float mean = sum * (1.0f / 256.0f);
    float dx = v.x - mean, dy = v.y - mean, dz = v.z - mean, dw = v.w - mean;
    float vs = dx * dx + dy * dy + dz * dz + dw * dw;
    #pragma unroll
    for (int off = 1; off < 64; off <<= 1) vs += __shfl_xor(vs, off);
    float rstd = rsqrtf(vs * (1.0f / 256.0f) + 1e-5f);
    float4 sv = ((const float4*)s)[lane];
    float4 bv = ((const float4*)b)[lane];
    u16x4 o;
    o[0] = f2bf(dx * rstd * sv.x + bv.x);
    o[1] = f2bf(dy * rstd * sv.y + bv.y);
    o[2] = f2bf(dz * rstd * sv.z + bv.z);
    o[3] = f2bf(dw * rstd * sv.w + bv.w);
    *(u16x4*)&hb[row * 256 + lane * 4] = o;
}

// ================= generic transpose+convert: in fp32 [Kd][Nd] -> out bf16 [n][k] =================
__global__ __launch_bounds__(256) void cvt_transpose(const float* __restrict__ in, ushort* __restrict__ out,
                                                     int Kd, int Nd, int n_real,
                                                     int in_stride, int out_stride) {
    __shared__ __align__(16) ushort t[64][80];
    const float* inp = in + (size_t)blockIdx.z * in_stride;
    ushort* outp = out + (size_t)blockIdx.z * out_stride;
    int n0 = blockIdx.x * 64, k0 = blockIdx.y * 64;
    int tid = threadIdx.x;
    #pragma unroll
    for (int p = 0; p < 4; p++) {
        int lk = p * 16 + (tid >> 4);
        int ln = (tid & 15) * 4;
        int k = k0 + lk, n = n0 + ln;
        const float* rowp = inp + (size_t)k * Nd;
        float v0 = 0.f, v1 = 0.f, v2 = 0.f, v3 = 0.f;
        if (n + 0 < n_real) v0 = rowp[n + 0];
        if (n + 1 < n_real) v1 = rowp[n + 1];
        if (n + 2 < n_real) v2 = rowp[n + 2];
        if (n + 3 < n_real) v3 = rowp[n + 3];
        t[ln + 0][lk] = f2bf(v0);
        t[ln + 1][lk] = f2bf(v1);
        t[ln + 2][lk] = f2bf(v2);
        t[ln + 3][lk] = f2bf(v3);
    }
    __syncthreads();
    int ln = tid >> 2, kq = (tid & 3) * 16;
    ushort* op = outp + (size_t)(n0 + ln) * Kd + k0 + kq;
    *(s16x8*)&op[0] = *(const s16x8*)&t[ln][kq];
    *(s16x8*)&op[8] = *(const s16x8*)&t[ln][kq + 8];
}

// ================= Wq/Wk/Wv [L][H][E][D] -> WqkvT [L][256][256] (rows 192..255 zero) =================
__global__ __launch_bounds__(256) void cvt_qkv(const float* __restrict__ Wq, const float* __restrict__ Wk,
                                               const float* __restrict__ Wv, ushort* __restrict__ WqkvT) {
    int l = blockIdx.x, kind = blockIdx.y;
    const float* W = (kind == 0 ? Wq : (kind == 1 ? Wk : Wv)) + l * 16384;
    ushort* out = WqkvT + (size_t)l * 65536 + kind * 64 * 256;
    int tid = threadIdx.x;
    #pragma unroll 4
    for (int it = 0; it < 64; it++) {
        int idx = it * 256 + tid;
        int row = idx >> 8, e = idx & 255;
        int h = row >> 3, d = row & 7;
        out[row * 256 + e] = f2bf(W[h * 2048 + e * 8 + d]);
    }
    if (kind == 0) {
        ushort* zp = WqkvT + (size_t)l * 65536 + 192 * 256;
        #pragma unroll 4
        for (int it = 0; it < 64; it++) zp[it * 256 + tid] = 0;
    }
}

// ================= pre: QKV (16 rows/block) + V out + R partials (layer 0 only) =================
__global__ __launch_bounds__(512, 4) void gpt_pre(const ushort* __restrict__ hb,
                                                  const ushort* __restrict__ WqkvT,
                                                  ushort* __restrict__ Vb,
                                                  float* __restrict__ Rpart) {
    __shared__ __align__(16) ushort As[16 * 64];
    __shared__ __align__(16) ushort Bs[256 * 64];
    __shared__ float kqv[16][193];
    const int tid = threadIdx.x, lane = tid & 63, wn = tid >> 6;
    const int rows0 = blockIdx.x * 16;
    const int fr = lane & 15, fkb = (lane >> 4) * 16;
    const int arow = tid >> 3, ach = tid & 7;

    f32x4 acc[2];
    acc[0] = (f32x4)0.0f; acc[1] = (f32x4)0.0f;

    s16x8 ra, rb[4];
    if (tid < 128) ra = *(const s16x8*)&hb[(size_t)(rows0 + arow) * 256 + ach * 8];
    #pragma unroll
    for (int i = 0; i < 4; i++) {
        int u = tid + i * 512, r = u >> 3, ch = u & 7;
        rb[i] = *(const s16x8*)&WqkvT[(size_t)r * 256 + ch * 8];
    }
    #pragma unroll 1
    for (int kt = 0; kt < 4; kt++) {
        if (kt) __syncthreads();
        if (tid < 128)
            *(s16x8*)&As[arow * 64 + (((ach * 16) ^ ((arow & 7) << 4)) >> 1)] = ra;
        #pragma unroll
        for (int i = 0; i < 4; i++) {
            int u = tid + i * 512, r = u >> 3, ch = u & 7;
            *(s16x8*)&Bs[r * 64 + (((ch * 16) ^ ((r & 7) << 4)) >> 1)] = rb[i];
        }
        __syncthreads();
        if (kt < 3) {
            int k0 = (kt + 1) * 64;
            if (tid < 128) ra = *(const s16x8*)&hb[(size_t)(rows0 + arow) * 256 + k0 + ach * 8];
            #pragma unroll
            for (int i = 0; i < 4; i++) {
                int u = tid + i * 512, r = u >> 3, ch = u & 7;
                rb[i] = *(const s16x8*)&WqkvT[(size_t)r * 256 + k0 + ch * 8];
            }
        }
        #pragma unroll
        for (int kk = 0; kk < 2; kk++) {
            int kbyte = kk * 64 + fkb;
            s16x8 af = *(const s16x8*)&As[fr * 64 + ((kbyte ^ ((fr & 7) << 4)) >> 1)];
            #pragma unroll
            for (int n = 0; n < 2; n++) {
                int brow = wn * 32 + n * 16 + fr;
                s16x8 bfv = *(const s16x8*)&Bs[brow * 64 + ((kbyte ^ ((brow & 7) << 4)) >> 1)];
                acc[n] = __builtin_amdgcn_mfma_f32_16x16x32_bf16(af, bfv, acc[n], 0, 0, 0);
            }
        }
    }
    #pragma unroll
    for (int n = 0; n < 2; n++) {
        int col = wn * 32 + n * 16 + fr;
        if (col < 192) {
            #pragma unroll
            for (int r = 0; r < 4; r++)
                kqv[(lane >> 4) * 4 + r][col] = acc[n][r];
        }
    }
    __syncthreads();
    #pragma unroll
    for (int i = 0; i < 2; i++) {
        int u = tid + i * 512, t = u >> 6, hd = u & 63;
        Vb[(size_t)(rows0 + t) * 64 + hd] = f2bf(kqv[t][128 + hd]);
    }
    {
        int h = tid >> 6, i2 = (tid >> 3) & 7, j = tid & 7;
        float s = 0.0f;
        #pragma unroll
        for (int t = 0; t < 16; t++)
            s += kqv[t][64 + h * 8 + i2] * kqv[t][h * 8 + j];
        int bb = rows0 >> 9, part = (rows0 >> 4) & 31;
        Rpart[(size_t)(bb * 32 + part) * 512 + tid] = s;
    }
}

// ================= fused layer (B-operands direct from L2; A in LDS; few barriers) =================
__global__ __launch_bounds__(512, 4) void gpt_layer(
        const float* __restrict__ Rpart_in, const ushort* __restrict__ Vb_in,
        const ushort* __restrict__ WoT, const float* __restrict__ bo,
        const ushort* __restrict__ W1T, const float* __restrict__ b1,
        const ushort* __restrict__ W2T, const float* __restrict__ b2,
        const float* __restrict__ ls2, const float* __restrict__ lb2,
        const float* __restrict__ nls, const float* __restrict__ nlb,
        float* __restrict__ x,
        const ushort* __restrict__ WqkvT_next,
        ushort* __restrict__ Vb_out, float* __restrict__ Rpart_out,
        ushort* __restrict__ hbout, int mode) {
    __shared__ __align__(16) ushort ffs[16 * 1024];   // 32 KB (aliased as kqv in QKV phase)
    __shared__ __align__(16) ushort h2s[16 * 256];    // 8 KB
    __shared__ __align__(16) ushort abl[16 * 64];     // 2 KB
    __shared__ __align__(16) ushort Vl[16 * 64];      // 2 KB
    __shared__ float Rs[512];                          // 2 KB
    __shared__ float red1[16][8], red2[16][8], mrow[16], rrow[16];

    const int tid = threadIdx.x, lane = tid & 63, wn = tid >> 6;
    const int rows0 = blockIdx.x * 16, b = rows0 >> 9;
    const int fr = lane & 15, fkb = (lane >> 4) * 16, rbase = (lane >> 4) * 4;
    const int koffe = (lane >> 4) * 8;                // element k-slice offset within 32-k group
    int colv[2]; colv[0] = wn * 32 + fr; colv[1] = wn * 32 + 16 + fr;
    const int brow0 = wn * 32 + fr, brow1 = wn * 32 + 16 + fr;

    // ---- softmax(R) from 32 partials ----
    {
        const float* rp = Rpart_in + (size_t)b * 32 * 512 + tid;
        float s = 0.0f;
        #pragma unroll
        for (int p = 0; p < 32; p++) s += rp[p * 512];
        s *= (1.0f / 16.0f);
        int ii = (tid >> 3) & 7, j = tid & 7;
        float val = (j >= ii) ? s : -INFINITY;
        float m = val;
        #pragma unroll
        for (int off = 1; off < 8; off <<= 1) m = fmaxf(m, __shfl_xor(m, off, 8));
        float ex = __expf(val - m);
        float su = ex;
        #pragma unroll
        for (int off = 1; off < 8; off <<= 1) su += __shfl_xor(su, off, 8);
        Rs[tid] = ex / su;
    }
    #pragma unroll
    for (int i = 0; i < 2; i++) {
        int u = tid + i * 512, t = u >> 6, hd = u & 63;
        Vl[t * 64 + hd] = Vb_in[(size_t)(rows0 + t) * 64 + hd];
    }
    __syncthreads();
    // ---- ab = V @ R -> abl (bf16, swizzled A) ----
    #pragma unroll
    for (int i = 0; i < 2; i++) {
        int u = tid + i * 512, t = u >> 6, hd = u & 63, h = hd >> 3, j = hd & 7;
        float a = 0.0f;
        #pragma unroll
        for (int q = 0; q < 8; q++)
            a += bf2f(Vl[t * 64 + h * 8 + q]) * Rs[h * 64 + q * 8 + j];
        abl[t * 64 + (((hd * 2) ^ ((t & 7) << 4)) >> 1)] = f2bf(a);
    }
    __syncthreads();
    // ---- proj: 16x256 = abl(16x64) @ WoT(256x64), B direct from global ----
    f32x4 acc[2];
    acc[0] = (f32x4)0.0f; acc[1] = (f32x4)0.0f;
    #pragma unroll
    for (int kk = 0; kk < 2; kk++) {
        int kbyte = kk * 64 + fkb;
        s16x8 af = *(const s16x8*)&abl[fr * 64 + ((kbyte ^ ((fr & 7) << 4)) >> 1)];
        s16x8 b0 = *(const s16x8*)&WoT[(size_t)brow0 * 64 + kk * 32 + koffe];
        s16x8 b1v = *(const s16x8*)&WoT[(size_t)brow1 * 64 + kk * 32 + koffe];
        acc[0] = __builtin_amdgcn_mfma_f32_16x16x32_bf16(af, b0, acc[0], 0, 0, 0);
        acc[1] = __builtin_amdgcn_mfma_f32_16x16x32_bf16(af, b1v, acc[1], 0, 0, 0);
    }
    float xn[2][4];
    #pragma unroll
    for (int n = 0; n < 2; n++) {
        int col = colv[n];
        float bbv = bo[col];
        #pragma unroll
        for (int r = 0; r < 4; r++)
            xn[n][r] = acc[n][r] + bbv + x[(size_t)(rows0 + rbase + r) * 256 + col];
    }
    // ---- LN(ln2) -> h2s ----
    #pragma unroll
    for (int r = 0; r < 4; r++) {
        float s1 = xn[0][r] + xn[1][r];
        float s2 = xn[0][r] * xn[0][r] + xn[1][r] * xn[1][r];
        #pragma unroll
        for (int off = 1; off < 16; off <<= 1) {
            s1 += __shfl_xor(s1, off);
            s2 += __shfl_xor(s2, off);
        }
        if (fr == 0) { red1[rbase + r][wn] = s1; red2[rbase + r][wn] = s2; }
    }
    __syncthreads();
    if (tid < 16) {
        float s1 = 0.f, s2 = 0.f;
        #pragma unroll
        for (int w = 0; w < 8; w++) { s1 += red1[tid][w]; s2 += red2[tid][w]; }
        float mean = s1 * (1.0f / 256.0f);
        float var = s2 * (1.0f / 256.0f) - mean * mean;
        mrow[tid] = mean;
        rrow[tid] = rsqrtf(var + 1e-5f);
    }
    __syncthreads();
    #pragma unroll
    for (int n = 0; n < 2; n++) {
        int col = colv[n];
        float lsv = ls2[col], lbv = lb2[col];
        #pragma unroll
        for (int r = 0; r < 4; r++) {
            int rl = rbase + r;
            float hv = (xn[n][r] - mrow[rl]) * rrow[rl] * lsv + lbv;
            h2s[rl * 256 + (((col * 2) ^ ((rl & 7) << 4)) >> 1)] = f2bf(hv);
        }
    }
    __syncthreads();
    // ---- MLP1: ff = relu(h2 @ W1T + b1), 4 col-chunks, B direct, ff in LDS ----
    #pragma unroll 1
    for (int c = 0; c < 4; c++) {
        const ushort* Bg = W1T + (size_t)c * 256 * 256;
        acc[0] = (f32x4)0.0f; acc[1] = (f32x4)0.0f;
        #pragma unroll
        for (int kt = 0; kt < 4; kt++) {
            #pragma unroll
            for (int kk = 0; kk < 2; kk++) {
                int kbyte = kt * 128 + kk * 64 + fkb;
                s16x8 af = *(const s16x8*)&h2s[fr * 256 + ((kbyte ^ ((fr & 7) << 4)) >> 1)];
                int ke = kt * 64 + kk * 32 + koffe;
                s16x8 b0 = *(const s16x8*)&Bg[(size_t)brow0 * 256 + ke];
                s16x8 b1v = *(const s16x8*)&Bg[(size_t)brow1 * 256 + ke];
                acc[0] = __builtin_amdgcn_mfma_f32_16x16x32_bf16(af, b0, acc[0], 0, 0, 0);
                acc[1] = __builtin_amdgcn_mfma_f32_16x16x32_bf16(af, b1v, acc[1], 0, 0, 0);
            }
        }
        #pragma unroll
        for (int n = 0; n < 2; n++) {
            int col = c * 256 + colv[n];
            float bb1 = b1[col];
            #pragma unroll
            for (int r = 0; r < 4; r++) {
                int rl = rbase + r;
                ffs[rl * 1024 + (((col * 2) ^ ((rl & 7) << 4)) >> 1)] =
                    f2bf(fmaxf(acc[n][r] + bb1, 0.0f));
            }
        }
    }
    __syncthreads();
    // ---- MLP2: x += ffs @ W2T + b2 (K=1024), B direct ----
    f32x4 a2[2];
    a2[0] = (f32x4)0.0f; a2[1] = (f32x4)0.0f;
    #pragma unroll 4
    for (int kt = 0; kt < 16; kt++) {
        #pragma unroll
        for (int kk = 0; kk < 2; kk++) {
            int kbyte = kt * 128 + kk * 64 + fkb;
            s16x8 af = *(const s16x8*)&ffs[fr * 1024 + ((kbyte ^ ((fr & 7) << 4)) >> 1)];
            int ke = kt * 64 + kk * 32 + koffe;
            s16x8 b0 = *(const s16x8*)&W2T[(size_t)brow0 * 1024 + ke];
            s16x8 b1v = *(const s16x8*)&W2T[(size_t)brow1 * 1024 + ke];
            a2[0] = __builtin_amdgcn_mfma_f32_16x16x32_bf16(af, b0, a2[0], 0, 0, 0);
            a2[1] = __builtin_amdgcn_mfma_f32_16x16x32_bf16(af, b1v, a2[1], 0, 0, 0);
        }
    }
    #pragma unroll
    for (int n = 0; n < 2; n++) {
        int col = colv[n];
        float bb2 = b2[col];
        #pragma unroll
        for (int r = 0; r < 4; r++) {
            float v = xn[n][r] + a2[n][r] + bb2;
            xn[n][r] = v;
            x[(size_t)(rows0 + rbase + r) * 256 + col] = v;
        }
    }
    // ---- LN(next ln1 / lnf) -> h2s (and global hb if last layer) ----
    __syncthreads();
    #pragma unroll
    for (int r = 0; r < 4; r++) {
        float s1 = xn[0][r] + xn[1][r];
        float s2 = xn[0][r] * xn[0][r] + xn[1][r] * xn[1][r];
        #pragma unroll
        for (int off = 1; off < 16; off <<= 1) {
            s1 += __shfl_xor(s1, off);
            s2 += __shfl_xor(s2, off);
        }
        if (fr == 0) { red1[rbase + r][wn] = s1; red2[rbase + r][wn] = s2; }
    }
    __syncthreads();
    if (tid < 16) {
        float s1 = 0.f, s2 = 0.f;
        #pragma unroll
        for (int w = 0; w < 8; w++) { s1 += red1[tid][w]; s2 += red2[tid][w]; }
        float mean = s1 * (1.0f / 256.0f);
        float var = s2 * (1.0f / 256.0f) - mean * mean;
        mrow[tid] = mean;
        rrow[tid] = rsqrtf(var + 1e-5f);
    }
    __syncthreads();
    #pragma unroll
    for (int n = 0; n < 2; n++) {
        int col = colv[n];
        float lsv = nls[col], lbv = nlb[col];
        #pragma unroll
        for (int r = 0; r < 4; r++) {
            int rl = rbase + r;
            float hv = (xn[n][r] - mrow[rl]) * rrow[rl] * lsv + lbv;
            ushort hu = f2bf(hv);
            h2s[rl * 256 + (((col * 2) ^ ((rl & 7) << 4)) >> 1)] = hu;
            if (mode == 0)
                hbout[(size_t)(rows0 + rl) * 256 + col] = hu;
        }
    }
    if (mode == 0) return;
    __syncthreads();

    // ---- QKV for next layer: kqv = h2 @ WqkvT_next (K=256), A from h2s, B direct ----
    float* kqv = (float*)ffs;   // 16 x 193 floats, aliases ffs (dead now)
    acc[0] = (f32x4)0.0f; acc[1] = (f32x4)0.0f;
    #pragma unroll
    for (int kt = 0; kt < 4; kt++) {
        #pragma unroll
        for (int kk = 0; kk < 2; kk++) {
            int kbyte = kt * 128 + kk * 64 + fkb;
            s16x8 af = *(const s16x8*)&h2s[fr * 256 + ((kbyte ^ ((fr & 7) << 4)) >> 1)];
            int ke = kt * 64 + kk * 32 + koffe;
            s16x8 b0 = *(const s16x8*)&WqkvT_next[(size_t)brow0 * 256 + ke];
            s16x8 b1v = *(const s16x8*)&WqkvT_next[(size_t)brow1 * 256 + ke];
            acc[0] = __builtin_amdgcn_mfma_f32_16x16x32_bf16(af, b0, acc[0], 0, 0, 0);
            acc[1] = __builtin_amdgcn_mfma_f32_16x16x32_bf16(af, b1v, acc[1], 0, 0, 0);
        }
    }
    __syncthreads();   // ffs (MLP2 A-reads) done long ago; fence before kqv writes
    #pragma unroll
    for (int n = 0; n < 2; n++) {
        int col = wn * 32 + n * 16 + fr;
        if (col < 192) {
            #pragma unroll
            for (int r = 0; r < 4; r++)
                kqv[(rbase + r) * 193 + col] = acc[n][r];
        }
    }
    __syncthreads();
    #pragma unroll
    for (int i = 0; i < 2; i++) {
        int u = tid + i * 512, t = u >> 6, hd = u & 63;
        Vb_out[(size_t)(rows0 + t) * 64 + hd] = f2bf(kqv[t * 193 + 128 + hd]);
    }
    {
        int h = tid >> 6, i2 = (tid >> 3) & 7, j = tid & 7;
        float s = 0.0f;
        #pragma unroll
        for (int t = 0; t < 16; t++)
            s += kqv[t * 193 + 64 + h * 8 + i2] * kqv[t * 193 + h * 8 + j];
        int part = (rows0 >> 4) & 31;
        Rpart_out[(size_t)(b * 32 + part) * 512 + tid] = s;
    }
}

// ================= logits GEMM: 128x256 tile, 512 thr (2x4 waves), LDS-staged (round-9 proven) =================
__global__ __launch_bounds__(512, 4) void gpt_logits_mfma(const ushort* __restrict__ hb, const ushort* __restrict__ WfT,
                                                          const float* __restrict__ bfb, float* __restrict__ out,
                                                          float2* __restrict__ lsebuf) {
    __shared__ __align__(16) ushort As[128 * 64];   // 16 KB
    __shared__ __align__(16) ushort Bs[256 * 64];   // 32 KB
    f32x4 acc[4][4];
    // XCD-bijective swizzle: 6304 blocks = 8 * 788
    int flat = blockIdx.y * 32 + blockIdx.x;
    int nf = (flat & 7) * 788 + (flat >> 3);
    int rb = nf & 31, cb = nf >> 5;
    int row0 = rb * 128, c0 = cb * 256;
    const int tid = threadIdx.x, lane = tid & 63, wid = tid >> 6;
    const int wm = wid >> 2, wn = wid & 3;           // 2 x 4 waves, 64x64 each
    const int fr = lane & 15, fkb = (lane >> 4) * 16;

    #pragma unroll
    for (int m = 0; m < 4; m++)
        #pragma unroll
        for (int n = 0; n < 4; n++) acc[m][n] = (f32x4)0.0f;

    s16x8 ra[2], rbv[4];
    #pragma unroll
    for (int i = 0; i < 2; i++) {
        int u = tid + i * 512, r = u >> 3, ch = u & 7;
        ra[i] = *(const s16x8*)&hb[(size_t)(row0 + r) * 256 + ch * 8];
    }
    #pragma unroll
    for (int i = 0; i < 4; i++) {
        int u = tid + i * 512, r = u >> 3, ch = u & 7;
        rbv[i] = *(const s16x8*)&WfT[(size_t)(c0 + r) * 256 + ch * 8];
    }
    #pragma unroll 1
    for (int kt = 0; kt < 4; kt++) {
        if (kt) __syncthreads();
        #pragma unroll
        for (int i = 0; i < 2; i++) {
            int u = tid + i * 512, r = u >> 3, ch = u & 7;
            *(s16x8*)&As[r * 64 + (((ch * 16) ^ ((r & 7) << 4)) >> 1)] = ra[i];
        }
        #pragma unroll
        for (int i = 0; i < 4; i++) {
            int u = tid + i * 512, r = u >> 3, ch = u & 7;
            *(s16x8*)&Bs[r * 64 + (((ch * 16) ^ ((r & 7) << 4)) >> 1)] = rbv[i];
        }
        __syncthreads();
        if (kt < 3) {
            int k0 = (kt + 1) * 64;
            #pragma unroll
            for (int i = 0; i < 2; i++) {
                int u = tid + i * 512, r = u >> 3, ch = u & 7;
                ra[i] = *(const s16x8*)&hb[(size_t)(row0 + r) * 256 + k0 + ch * 8];
            }
            #pragma unroll
            for (int i = 0; i < 4; i++) {
                int u = tid + i * 512, r = u >> 3, ch = u & 7;
                rbv[i] = *(const s16x8*)&WfT[(size_t)(c0 + r) * 256 + k0 + ch * 8];
            }
        }
        #pragma unroll
        for (int kk = 0; kk < 2; kk++) {
            int kbyte = kk * 64 + fkb;
            s16x8 af[4], bfr[4];
            #pragma unroll
            for (int m = 0; m < 4; m++) {
                int arow = wm * 64 + m * 16 + fr;
                af[m] = *(const s16x8*)&As[arow * 64 + ((kbyte ^ ((arow & 7) << 4)) >> 1)];
            }
            #pragma unroll
            for (int n = 0; n < 4; n++) {
                int brow = wn * 64 + n * 16 + fr;
                bfr[n] = *(const s16x8*)&Bs[brow * 64 + ((kbyte ^ ((brow & 7) << 4)) >> 1)];
            }
            #pragma unroll
            for (int m = 0; m < 4; m++)
                #pragma unroll
                for (int n = 0; n < 4; n++)
                    acc[m][n] = __builtin_amdgcn_mfma_f32_16x16x32_bf16(af[m], bfr[n], acc[m][n], 0, 0, 0);
        }
    }
    // epilogue: bias + store + per-row (max,sumexp) partials
    float bb[4]; int gcv[4];
    #pragma unroll
    for (int n = 0; n < 4; n++) {
        int gc = c0 + wn * 64 + n * 16 + fr;
        gcv[n] = gc;
        bb[n] = (gc < V_SZ) ? bfb[gc] : 0.0f;
    }
    __syncthreads();                       // all MFMA reads of As done -> reuse as reduce buffer
    float2 (*red)[4] = (float2(*)[4])As;   // [128][4]
    #pragma unroll
    for (int m = 0; m < 4; m++) {
        int rloc = wm * 64 + m * 16 + (lane >> 4) * 4;
        int gr = row0 + rloc;
        #pragma unroll
        for (int r = 0; r < 4; r++) {
            float v[4];
            float vmax = -1e30f;
            #pragma unroll
            for (int n = 0; n < 4; n++) {
                v[n] = (gcv[n] < V_SZ) ? acc[m][n][r] + bb[n] : -1e30f;
                vmax = fmaxf(vmax, v[n]);
            }
            #pragma unroll
            for (int n = 0; n < 4; n++)
                if (gcv[n] < V_SZ)
                    out[(size_t)(gr + r) * V_SZ + gcv[n]] = v[n];
            #pragma unroll
            for (int off = 1; off < 16; off <<= 1)
                vmax = fmaxf(vmax, __shfl_xor(vmax, off));
            float vsum = __expf(v[0] - vmax) + __expf(v[1] - vmax)
                       + __expf(v[2] - vmax) + __expf(v[3] - vmax);
            #pragma unroll
            for (int off = 1; off < 16; off <<= 1)
                vsum += __shfl_xor(vsum, off);
            if ((lane & 15) == 0)
                red[rloc + r][wn] = make_float2(vmax, vsum);
        }
    }
    __syncthreads();
    if (tid < 128) {
        float M = -1e30f, S = 0.0f;
        #pragma unroll
        for (int w = 0; w < 4; w++) {
            float2 p = red[tid][w];
            float M2 = fmaxf(M, p.x);
            S = S * __expf(M - M2) + p.y * __expf(p.x - M2);
            M = M2;
        }
        lsebuf[(size_t)(row0 + tid) * NCB + cb] = make_float2(M, S);
    }
}

// ================= lse finish =================
__global__ __launch_bounds__(256) void gpt_lse(const float2* __restrict__ lsebuf, const float* __restrict__ out,
                                               const int* __restrict__ tgt, float* __restrict__ partial) {
    int wave = threadIdx.x >> 6, lane = threadIdx.x & 63;
    int row = blockIdx.x * 4 + wave;
    float m = -INFINITY, s = 0.0f;
    for (int i = lane; i < NCB; i += 64) {
        float2 p = lsebuf[(size_t)row * NCB + i];
        float M = fmaxf(m, p.x);
        s = s * __expf(m - M) + p.y * __expf(p.x - M);
        m = M;
    }
    #pragma unroll
    for (int off = 1; off < 64; off <<= 1) {
        float m2 = __shfl_xor(m, off);
        float s2 = __shfl_xor(s, off);
        float M = fmaxf(m, m2);
        s = s * __expf(m - M) + s2 * __expf(m2 - M);
        m = M;
    }
    if (lane == 0)
        partial[row] = m + logf(s) - out[(size_t)row * V_SZ + tgt[row]];
}

__global__ void gpt_loss_reduce(const float* __restrict__ partial, float* __restrict__ out) {
    __shared__ float red[256];
    int tid = threadIdx.x;
    float s = 0.0f;
    for (int i = tid; i < 4096; i += 256) s += partial[i];
    red[tid] = s;
    __syncthreads();
    for (int off = 128; off > 0; off >>= 1) {
        if (tid < off) red[tid] += red[tid + off];
        __syncthreads();
    }
    if (tid == 0) out[0] = red[0] * (1.0f / 4096.0f);
}

// ======================= fp32 fallback kernels (small-ws path) =======================
__global__ void gpt_embed(const int* __restrict__ tokens, const float* __restrict__ tok_emb,
                          const float* __restrict__ pos_emb, float* __restrict__ x) {
    int idx = blockIdx.x * 256 + threadIdx.x;
    int bt = idx >> 8, e = idx & 255;
    int t = bt & 511;
    int tok = tokens[bt];
    x[idx] = tok_emb[tok * 256 + e] + pos_emb[t * 256 + e];
}

__global__ void gpt_ln(const float* __restrict__ x, const float* __restrict__ s,
                       const float* __restrict__ b, float* __restrict__ h) {
    __shared__ float red[256];
    int row = blockIdx.x, e = threadIdx.x;
    float v = x[row * 256 + e];
    red[e] = v;
    __syncthreads();
    for (int off = 128; off > 0; off >>= 1) {
        if (e < off) red[e] += red[e + off];
        __syncthreads();
    }
    float mean = red[0] * (1.0f / 256.0f);
    __syncthreads();
    float d = v - mean;
    red[e] = d * d;
    __syncthreads();
    for (int off = 128; off > 0; off >>= 1) {
        if (e < off) red[e] += red[e + off];
        __syncthreads();
    }
    float rstd = rsqrtf(red[0] * (1.0f / 256.0f) + 1e-5f);
    h[row * 256 + e] = d * rstd * s[e] + b[e];
}

__global__ void gpt_qkv(const float* __restrict__ h, const float* __restrict__ Wq,
                        const float* __restrict__ Wk, const float* __restrict__ Wv,
                        float* __restrict__ Q, float* __restrict__ K, float* __restrict__ Vv) {
    __shared__ float hs[8][256];
    int tid = threadIdx.x;
    int row0 = blockIdx.x * 8;
    #pragma unroll
    for (int r = 0; r < 8; r++) hs[r][tid] = h[(row0 + r) * 256 + tid];
    __syncthreads();
    if (tid < 192) {
        int kind = tid >> 6, o = tid & 63, hh = o >> 3, d = o & 7;
        const float* W = kind == 0 ? Wq : (kind == 1 ? Wk : Wv);
        const float* wp = W + hh * 2048 + d;
        float acc[8];
        #pragma unroll
        for (int r = 0; r < 8; r++) acc[r] = 0.0f;
        for (int e = 0; e < 256; e++) {
            float w = wp[e * 8];
            #pragma unroll
            for (int r = 0; r < 8; r++) acc[r] += hs[r][e] * w;
        }
        float* outp = kind == 0 ? Q : (kind == 1 ? K : Vv);
        int b = row0 >> 9;
        #pragma unroll
        for (int r = 0; r < 8; r++) {
            int t = (row0 + r) & 511;
            outp[((b * 8 + hh) * 512 + t) * 8 + d] = acc[r];
        }
    }
}

__global__ void gpt_attn_r(const float* __restrict__ K, const float* __restrict__ Q,
                           float* __restrict__ R) {
    __shared__ __align__(16) float Ks[64][8];
    __shared__ __align__(16) float Qs[64][8];
    int bh = blockIdx.x, tid = threadIdx.x;
    int i = tid >> 3, j = tid & 7;
    const float* Kb = K + bh * 512 * 8;
    const float* Qb = Q + bh * 512 * 8;
    float acc = 0.0f;
    for (int t0 = 0; t0 < 512; t0 += 64) {
        *(float4*)&Ks[tid][0] = *(const float4*)&Kb[(t0 + tid) * 8];
        *(float4*)&Ks[tid][4] = *(const float4*)&Kb[(t0 + tid) * 8 + 4];
        *(float4*)&Qs[tid][0] = *(const float4*)&Qb[(t0 + tid) * 8];
        *(float4*)&Qs[tid][4] = *(const float4*)&Qb[(t0 + tid) * 8 + 4];
        __syncthreads();
        #pragma unroll 16
        for (int t = 0; t < 64; t++) acc += Ks[t][i] * Qs[t][j];
        __syncthreads();
    }
    acc *= (1.0f / 16.0f);
    float val = (j >= i) ? acc : -INFINITY;
    float m = val;
    #pragma unroll
    for (int off = 1; off < 8; off <<= 1) m = fmaxf(m, __shfl_xor(m, off, 8));
    float ex = expf(val - m);
    float sum = ex;
    #pragma unroll
    for (int off = 1; off < 8; off <<= 1) sum += __shfl_xor(sum, off, 8);
    R[bh * 64 + tid] = ex / sum;
}

__global__ void gpt_attn_out(const float* __restrict__ Vv, const float* __restrict__ R,
                             const float* __restrict__ Wo, const float* __restrict__ bo,
                             float* __restrict__ x) {
    __shared__ __align__(16) float as[8][64];
    int tid = threadIdx.x;
    int row0 = blockIdx.x * 8;
    int b = row0 >> 9;
    #pragma unroll
    for (int k = 0; k < 2; k++) {
        int idx = k * 256 + tid;
        int r = idx >> 6, hd = idx & 63;
        int hh = hd >> 3, jj = hd & 7;
        int t = (row0 + r) & 511;
        const float* vp = Vv + ((b * 8 + hh) * 512 + t) * 8;
        const float* rp = R + (b * 8 + hh) * 64 + jj;
        float a = 0.0f;
        #pragma unroll
        for (int i = 0; i < 8; i++) a += vp[i] * rp[i * 8];
        as[r][hd] = a;
    }
    __syncthreads();
    float acc[8];
    float bb = bo[tid];
    #pragma unroll
    for (int r = 0; r < 8; r++) acc[r] = bb;
    for (int hd0 = 0; hd0 < 64; hd0 += 4) {
        float w0 = Wo[(hd0 + 0) * 256 + tid];
        float w1 = Wo[(hd0 + 1) * 256 + tid];
        float w2 = Wo[(hd0 + 2) * 256 + tid];
        float w3 = Wo[(hd0 + 3) * 256 + tid];
        #pragma unroll
        for (int r = 0; r < 8; r++) {
            float4 av = *(const float4*)&as[r][hd0];
            acc[r] += av.x * w0 + av.y * w1 + av.z * w2 + av.w * w3;
        }
    }
    #pragma unroll
    for (int r = 0; r < 8; r++) x[(row0 + r) * 256 + tid] += acc[r];
}

__global__ __launch_bounds__(256) void gpt_mlp(const float* __restrict__ h, const float* __restrict__ W1,
                         const float* __restrict__ b1, const float* __restrict__ W2,
                         const float* __restrict__ b2, float* __restrict__ x) {
    __shared__ __align__(16) float hs[8][256];
    __shared__ __align__(16) float ffs[8][1024];
    int tid = threadIdx.x;
    int row0 = blockIdx.x * 8;
    #pragma unroll
    for (int r = 0; r < 8; r++) hs[r][tid] = h[(row0 + r) * 256 + tid];
    __syncthreads();
    {
        float acc[4][8];
        #pragma unroll
        for (int k = 0; k < 4; k++) {
            float bb = b1[k * 256 + tid];
            #pragma unroll
            for (int r = 0; r < 8; r++) acc[k][r] = bb;
        }
        for (int e0 = 0; e0 < 256; e0 += 4) {
            float w[4][4];
            #pragma unroll
            for (int ee = 0; ee < 4; ee++)
                #pragma unroll
                for (int k = 0; k < 4; k++)
                    w[ee][k] = W1[(e0 + ee) * 1024 + k * 256 + tid];
            #pragma unroll
            for (int r = 0; r < 8; r++) {
                float4 hv = *(const float4*)&hs[r][e0];
                #pragma unroll
                for (int k = 0; k < 4; k++)
                    acc[k][r] += hv.x * w[0][k] + hv.y * w[1][k] + hv.z * w[2][k] + hv.w * w[3][k];
            }
        }
        #pragma unroll
        for (int k = 0; k < 4; k++)
            #pragma unroll
            for (int r = 0; r < 8; r++)
                ffs[r][k * 256 + tid] = fmaxf(acc[k][r], 0.0f);
    }
    __syncthreads();
    {
        float acc[8];
        float bb = b2[tid];
        #pragma unroll
        for (int r = 0; r < 8; r++) acc[r] = bb;
        for (int f0 = 0; f0 < 1024; f0 += 4) {
            float w0 = W2[(f0 + 0) * 256 + tid];
            float w1 = W2[(f0 + 1) * 256 + tid];
            float w2 = W2[(f0 + 2) * 256 + tid];
            float w3 = W2[(f0 + 3) * 256 + tid];
            #pragma unroll
            for (int r = 0; r < 8; r++) {
                float4 fv = *(const float4*)&ffs[r][f0];
                acc[r] += fv.x * w0 + fv.y * w1 + fv.z * w2 + fv.w * w3;
            }
        }
        #pragma unroll
        for (int r = 0; r < 8; r++) x[(row0 + r) * 256 + tid] += acc[r];
    }
}

__global__ __launch_bounds__(256) void gpt_logits(const float* __restrict__ hf, const float* __restrict__ Wf,
                            const float* __restrict__ bf, float* __restrict__ out) {
    __shared__ __align__(16) float hs[32][256];
    int tid = threadIdx.x;
    int row0 = blockIdx.y * 32;
    #pragma unroll
    for (int r = 0; r < 32; r++) hs[r][tid] = hf[(row0 + r) * 256 + tid];
    __syncthreads();
    int c0 = blockIdx.x * 512 + tid;
    int c1 = c0 + 256;
    int c0c = c0 < V_SZ ? c0 : V_SZ - 1;
    int c1c = c1 < V_SZ ? c1 : V_SZ - 1;
    float acc0[32], acc1[32];
    float b0 = bf[c0c], b1 = bf[c1c];
    #pragma unroll
    for (int r = 0; r < 32; r++) { acc0[r] = b0; acc1[r] = b1; }
    const float* p0 = Wf + c0c;
    const float* p1 = Wf + c1c;
    for (int e0 = 0; e0 < 256; e0 += 4) {
        float w00 = p0[(size_t)(e0 + 0) * V_SZ];
        float w01 = p0[(size_t)(e0 + 1) * V_SZ];
        float w02 = p0[(size_t)(e0 + 2) * V_SZ];
        float w03 = p0[(size_t)(e0 + 3) * V_SZ];
        float w10 = p1[(size_t)(e0 + 0) * V_SZ];
        float w11 = p1[(size_t)(e0 + 1) * V_SZ];
        float w12 = p1[(size_t)(e0 + 2) * V_SZ];
        float w13 = p1[(size_t)(e0 + 3) * V_SZ];
        #pragma unroll
        for (int r = 0; r < 32; r++) {
            float4 hv = *(const float4*)&hs[r][e0];
            acc0[r] += hv.x * w00 + hv.y * w01 + hv.z * w02 + hv.w * w03;
            acc1[r] += hv.x * w10 + hv.y * w11 + hv.z * w12 + hv.w * w13;
        }
    }
    if (c0 < V_SZ) {
        #pragma unroll
        for (int r = 0; r < 32; r++) out[(size_t)(row0 + r) * V_SZ + c0] = acc0[r];
    }
    if (c1 < V_SZ) {
        #pragma unroll
        for (int r = 0; r < 32; r++) out[(size_t)(row0 + r) * V_SZ + c1] = acc1[r];
    }
}

__global__ void gpt_loss(const float* __restrict__ logits, const int* __restrict__ tgt,
                         float* __restrict__ partial) {
    __shared__ float ms[256], ss[256];
    int row = blockIdx.x, tid = threadIdx.x;
    const float* lr = logits + (size_t)row * V_SZ;
    float m = -INFINITY, s = 0.0f;
    for (int c = tid; c < V_SZ; c += 256) {
        float v = lr[c];
        float nm = fmaxf(m, v);
        s = s * expf(m - nm) + expf(v - nm);
        m = nm;
    }
    ms[tid] = m; ss[tid] = s;
    __syncthreads();
    for (int off = 128; off > 0; off >>= 1) {
        if (tid < off) {
            float m2 = ms[tid + off], s2 = ss[tid + off];
            float M = fmaxf(ms[tid], m2);
            ss[tid] = ss[tid] * expf(ms[tid] - M) + s2 * expf(m2 - M);
            ms[tid] = M;
        }
        __syncthreads();
    }
    if (tid == 0) {
        float lse = ms[0] + logf(ss[0]);
        partial[row] = lse - lr[tgt[row]];
    }
}

// ======================= launch =======================
extern "C" void kernel_launch(void* const* d_in, const int* in_sizes, int n_in,
                              void* d_out, int out_size, void* d_ws, size_t ws_size,
                              hipStream_t stream) {
    const int*   tokens  = (const int*)d_in[0];
    const int*   ideal   = (const int*)d_in[1];
    const float* tok_emb = (const float*)d_in[2];
    const float* pos_emb = (const float*)d_in[3];
    const float* Wq      = (const float*)d_in[4];
    const float* Wk      = (const float*)d_in[5];
    const float* Wv      = (const float*)d_in[6];
    const float* Wo      = (const float*)d_in[7];
    const float* bo      = (const float*)d_in[8];
    const float* ln1_s   = (const float*)d_in[9];
    const float* ln1_b   = (const float*)d_in[10];
    const float* W1      = (const float*)d_in[11];
    const float* b1      = (const float*)d_in[12];
    const float* W2      = (const float*)d_in[13];
    const float* b2      = (const float*)d_in[14];
    const float* ln2_s   = (const float*)d_in[15];
    const float* ln2_b   = (const float*)d_in[16];
    const float* lnf_s   = (const float*)d_in[17];
    const float* lnf_b   = (const float*)d_in[18];
    const float* Wf      = (const float*)d_in[19];
    const float* bf      = (const float*)d_in[20];
    float* out = (float*)d_out;

    // ---- workspace layout (bf16 path) ----
    size_t off = 0;
    char* wsc = (char*)d_ws;
    ushort* WfT   = (ushort*)(wsc + off); off += (size_t)NPAD * 256 * 2;
    ushort* W1T   = (ushort*)(wsc + off); off += (size_t)16 * 1024 * 256 * 2;
    ushort* W2T   = (ushort*)(wsc + off); off += (size_t)16 * 256 * 1024 * 2;
    ushort* WqkvT = (ushort*)(wsc + off); off += (size_t)16 * 256 * 256 * 2;
    ushort* WoT   = (ushort*)(wsc + off); off += (size_t)16 * 256 * 64 * 2;
    ushort* hb    = (ushort*)(wsc + off); off += (size_t)4096 * 256 * 2;
    ushort* Vb0   = (ushort*)(wsc + off); off += (size_t)4096 * 64 * 2;
    ushort* Vb1   = (ushort*)(wsc + off); off += (size_t)4096 * 64 * 2;
    float*  x     = (float*)(wsc + off);  off += (size_t)4096 * 256 * 4;
    float*  Rp0   = (float*)(wsc + off);  off += (size_t)8 * 32 * 512 * 4;
    float*  Rp1   = (float*)(wsc + off);  off += (size_t)8 * 32 * 512 * 4;
    float*  partial = (float*)(wsc + off); off += (size_t)4096 * 4;
    float2* lsebuf = (float2*)(wsc + off); off += (size_t)4096 * NCB * 8;
    bool big = ws_size >= off;

    if (big) {
        cvt_transpose<<<dim3(16, 4, 16), 256, 0, stream>>>(W1, W1T, 256, 1024, 1024, 262144, 262144);
        cvt_transpose<<<dim3(4, 16, 16), 256, 0, stream>>>(W2, W2T, 1024, 256, 256, 262144, 262144);
        cvt_transpose<<<dim3(4, 1, 16), 256, 0, stream>>>(Wo, WoT, 64, 256, 256, 16384, 16384);
        cvt_transpose<<<dim3(788, 4, 1), 256, 0, stream>>>(Wf, WfT, 256, V_SZ, V_SZ, 0, 0);
        cvt_qkv<<<dim3(16, 3), 256, 0, stream>>>(Wq, Wk, Wv, WqkvT);

        gpt_embed_ln<<<1024, 256, 0, stream>>>(tokens, tok_emb, pos_emb, ln1_s, ln1_b, x, hb);
        gpt_pre<<<256, 512, 0, stream>>>(hb, WqkvT, Vb0, Rp0);

        for (int l = 0; l < 16; l++) {
            const float* nls = (l < 15) ? ln1_s + (l + 1) * 256 : lnf_s;
            const float* nlb = (l < 15) ? ln1_b + (l + 1) * 256 : lnf_b;
            const float* Rin = (l & 1) ? Rp1 : Rp0;
            const ushort* Vin = (l & 1) ? Vb1 : Vb0;
            float* Rout = (l & 1) ? Rp0 : Rp1;
            ushort* Vout = (l & 1) ? Vb0 : Vb1;
            int mode = (l < 15) ? 1 : 0;
            const ushort* Wnext = WqkvT + (size_t)((l < 15) ? (l + 1) : 0) * 65536;
            gpt_layer<<<256, 512, 0, stream>>>(Rin, Vin,
                                               WoT + (size_t)l * 16384, bo + l * 256,
                                               W1T + (size_t)l * 262144, b1 + l * 1024,
                                               W2T + (size_t)l * 262144, b2 + l * 256,
                                               ln2_s + l * 256, ln2_b + l * 256,
                                               nls, nlb, x,
                                               Wnext, Vout, Rout, hb, mode);
        }

        gpt_logits_mfma<<<dim3(32, NCB), 512, 0, stream>>>(hb, WfT, bf, out, lsebuf);
        gpt_lse<<<1024, 256, 0, stream>>>(lsebuf, out, ideal, partial);
        gpt_loss_reduce<<<1, 256, 0, stream>>>(partial, out + (size_t)4096 * V_SZ);
    } else {
        // fp32 fallback
        float* fx  = (float*)d_ws;
        float* fh  = fx + 4096 * 256;
        float* fQ  = fh + 4096 * 256;
        float* fK  = fQ + 4096 * 64;
        float* fV  = fK + 4096 * 64;
        float* fR  = fV + 4096 * 64;
        float* fpart = fR + 64 * 64;
        gpt_embed<<<4096, 256, 0, stream>>>(tokens, tok_emb, pos_emb, fx);
        for (int l = 0; l < 16; l++) {
            gpt_ln<<<4096, 256, 0, stream>>>(fx, ln1_s + l * 256, ln1_b + l * 256, fh);
            gpt_qkv<<<512, 256, 0, stream>>>(fh, Wq + l * 16384, Wk + l * 16384, Wv + l * 16384, fQ, fK, fV);
            gpt_attn_r<<<64, 64, 0, stream>>>(fK, fQ, fR);
            gpt_attn_out<<<512, 256, 0, stream>>>(fV, fR, Wo + l * 16384, bo + l * 256, fx);
            gpt_ln<<<4096, 256, 0, stream>>>(fx, ln2_s + l * 256, ln2_b + l * 256, fh);
            gpt_mlp<<<512, 256, 0, stream>>>(fh, W1 + l * 262144, b1 + l * 1024, W2 + l * 262144, b2 + l * 256, fx);
        }
        gpt_ln<<<4096, 256, 0, stream>>>(fx, lnf_s, lnf_b, fh);
        dim3 lg(99, 128);
        gpt_logits<<<lg, 256, 0, stream>>>(fh, Wf, bf, out);
        gpt_loss<<<4096, 256, 0, stream>>>(out, ideal, fpart);
        gpt_loss_reduce<<<1, 256, 0, stream>>>(fpart, out + (size_t)4096 * V_SZ);
    }
}

// Round 12
// 1004.614 us; speedup vs baseline: 2.0985x; 1.1656x over previous
//
#include <hip/hip_runtime.h>
#include <math.h>

#define V_SZ 50257
#define NPAD 50432   // 197 * 256
#define NCB 197

#define AS1 __attribute__((address_space(1)))
#define AS3 __attribute__((address_space(3)))

typedef short s16x8 __attribute__((ext_vector_type(8)));
typedef ushort u16x4 __attribute__((ext_vector_type(4)));
typedef float f32x4 __attribute__((ext_vector_type(4)));

__device__ __forceinline__ ushort f2bf(float x) {
    union { float f; unsigned u; } v; v.f = x;
    unsigned r = v.u + 0x7FFF + ((v.u >> 16) & 1);   // RNE
    return (ushort)(r >> 16);
}
__device__ __forceinline__ float bf2f(ushort u) {
    union { unsigned u; float f; } v; v.u = ((unsigned)u) << 16; return v.f;
}

// ================= embed + ln1(layer0): wave per row =================
__global__ __launch_bounds__(256) void gpt_embed_ln(const int* __restrict__ tokens,
                                                    const float* __restrict__ tok_emb,
                                                    const float* __restrict__ pos_emb,
                                                    const float* __restrict__ s, const float* __restrict__ b,
                                                    float* __restrict__ x, ushort* __restrict__ hb) {
    int wave = threadIdx.x >> 6, lane = threadIdx.x & 63;
    int row = blockIdx.x * 4 + wave;
    int t = row & 511;
    int tok = tokens[row];
    float4 te = ((const float4*)(tok_emb + tok * 256))[lane];
    float4 pe = ((const float4*)(pos_emb + t * 256))[lane];
    float4 v = make_float4(te.x + pe.x, te.y + pe.y, te.z + pe.z, te.w + pe.w);
    ((float4*)(x + row * 256))[lane] = v;
    float sum = v.x + v.y + v.z + v.w;
    #pragma unroll
    for (int off = 1; off < 64; off <<= 1) sum += __shfl_xor(sum, off);
    float mean = sum * (1.0f / 256.0f);
    float dx = v.x - mean, dy = v.y - mean, dz = v.z - mean, dw = v.w - mean;
    float vs = dx * dx + dy * dy + dz * dz + dw * dw;
    #pragma unroll
    for (int off = 1; off < 64; off <<= 1) vs += __shfl_xor(vs, off);
    float rstd = rsqrtf(vs * (1.0f / 256.0f) + 1e-5f);
    float4 sv = ((const float4*)s)[lane];
    float4 bv = ((const float4*)b)[lane];
    u16x4 o;
    o[0] = f2bf(dx * rstd * sv.x + bv.x);
    o[1] = f2bf(dy * rstd * sv.y + bv.y);
    o[2] = f2bf(dz * rstd * sv.z + bv.z);
    o[3] = f2bf(dw * rstd * sv.w + bv.w);
    *(u16x4*)&hb[row * 256 + lane * 4] = o;
}

// ================= generic transpose+convert: in fp32 [Kd][Nd] -> out bf16 [n][k] =================
__global__ __launch_bounds__(256) void cvt_transpose(const float* __restrict__ in, ushort* __restrict__ out,
                                                     int Kd, int Nd, int n_real,
                                                     int in_stride, int out_stride) {
    __shared__ __align__(16) ushort t[64][80];
    const float* inp = in + (size_t)blockIdx.z * in_stride;
    ushort* outp = out + (size_t)blockIdx.z * out_stride;
    int n0 = blockIdx.x * 64, k0 = blockIdx.y * 64;
    int tid = threadIdx.x;
    #pragma unroll
    for (int p = 0; p < 4; p++) {
        int lk = p * 16 + (tid >> 4);
        int ln = (tid & 15) * 4;
        int k = k0 + lk, n = n0 + ln;
        const float* rowp = inp + (size_t)k * Nd;
        float v0 = 0.f, v1 = 0.f, v2 = 0.f, v3 = 0.f;
        if (n + 0 < n_real) v0 = rowp[n + 0];
        if (n + 1 < n_real) v1 = rowp[n + 1];
        if (n + 2 < n_real) v2 = rowp[n + 2];
        if (n + 3 < n_real) v3 = rowp[n + 3];
        t[ln + 0][lk] = f2bf(v0);
        t[ln + 1][lk] = f2bf(v1);
        t[ln + 2][lk] = f2bf(v2);
        t[ln + 3][lk] = f2bf(v3);
    }
    __syncthreads();
    int ln = tid >> 2, kq = (tid & 3) * 16;
    ushort* op = outp + (size_t)(n0 + ln) * Kd + k0 + kq;
    *(s16x8*)&op[0] = *(const s16x8*)&t[ln][kq];
    *(s16x8*)&op[8] = *(const s16x8*)&t[ln][kq + 8];
}

// ================= Wq/Wk/Wv [L][H][E][D] -> WqkvT [L][256][256] (rows 192..255 zero) =================
__global__ __launch_bounds__(256) void cvt_qkv(const float* __restrict__ Wq, const float* __restrict__ Wk,
                                               const float* __restrict__ Wv, ushort* __restrict__ WqkvT) {
    int l = blockIdx.x, kind = blockIdx.y;
    const float* W = (kind == 0 ? Wq : (kind == 1 ? Wk : Wv)) + l * 16384;
    ushort* out = WqkvT + (size_t)l * 65536 + kind * 64 * 256;
    int tid = threadIdx.x;
    #pragma unroll 4
    for (int it = 0; it < 64; it++) {
        int idx = it * 256 + tid;
        int row = idx >> 8, e = idx & 255;
        int h = row >> 3, d = row & 7;
        out[row * 256 + e] = f2bf(W[h * 2048 + e * 8 + d]);
    }
    if (kind == 0) {
        ushort* zp = WqkvT + (size_t)l * 65536 + 192 * 256;
        #pragma unroll 4
        for (int it = 0; it < 64; it++) zp[it * 256 + tid] = 0;
    }
}

// ================= pre: QKV (16 rows/block) + V out + R partials (layer 0 only) =================
__global__ __launch_bounds__(512, 4) void gpt_pre(const ushort* __restrict__ hb,
                                                  const ushort* __restrict__ WqkvT,
                                                  ushort* __restrict__ Vb,
                                                  float* __restrict__ Rpart) {
    __shared__ __align__(16) ushort As[16 * 64];
    __shared__ __align__(16) ushort Bs[256 * 64];
    __shared__ float kqv[16][193];
    const int tid = threadIdx.x, lane = tid & 63, wn = tid >> 6;
    const int rows0 = blockIdx.x * 16;
    const int fr = lane & 15, fkb = (lane >> 4) * 16;
    const int arow = tid >> 3, ach = tid & 7;

    f32x4 acc[2];
    acc[0] = (f32x4)0.0f; acc[1] = (f32x4)0.0f;

    s16x8 ra, rb[4];
    if (tid < 128) ra = *(const s16x8*)&hb[(size_t)(rows0 + arow) * 256 + ach * 8];
    #pragma unroll
    for (int i = 0; i < 4; i++) {
        int u = tid + i * 512, r = u >> 3, ch = u & 7;
        rb[i] = *(const s16x8*)&WqkvT[(size_t)r * 256 + ch * 8];
    }
    #pragma unroll 1
    for (int kt = 0; kt < 4; kt++) {
        if (kt) __syncthreads();
        if (tid < 128)
            *(s16x8*)&As[arow * 64 + (((ach * 16) ^ ((arow & 7) << 4)) >> 1)] = ra;
        #pragma unroll
        for (int i = 0; i < 4; i++) {
            int u = tid + i * 512, r = u >> 3, ch = u & 7;
            *(s16x8*)&Bs[r * 64 + (((ch * 16) ^ ((r & 7) << 4)) >> 1)] = rb[i];
        }
        __syncthreads();
        if (kt < 3) {
            int k0 = (kt + 1) * 64;
            if (tid < 128) ra = *(const s16x8*)&hb[(size_t)(rows0 + arow) * 256 + k0 + ach * 8];
            #pragma unroll
            for (int i = 0; i < 4; i++) {
                int u = tid + i * 512, r = u >> 3, ch = u & 7;
                rb[i] = *(const s16x8*)&WqkvT[(size_t)r * 256 + k0 + ch * 8];
            }
        }
        #pragma unroll
        for (int kk = 0; kk < 2; kk++) {
            int kbyte = kk * 64 + fkb;
            s16x8 af = *(const s16x8*)&As[fr * 64 + ((kbyte ^ ((fr & 7) << 4)) >> 1)];
            #pragma unroll
            for (int n = 0; n < 2; n++) {
                int brow = wn * 32 + n * 16 + fr;
                s16x8 bfv = *(const s16x8*)&Bs[brow * 64 + ((kbyte ^ ((brow & 7) << 4)) >> 1)];
                acc[n] = __builtin_amdgcn_mfma_f32_16x16x32_bf16(af, bfv, acc[n], 0, 0, 0);
            }
        }
    }
    #pragma unroll
    for (int n = 0; n < 2; n++) {
        int col = wn * 32 + n * 16 + fr;
        if (col < 192) {
            #pragma unroll
            for (int r = 0; r < 4; r++)
                kqv[(lane >> 4) * 4 + r][col] = acc[n][r];
        }
    }
    __syncthreads();
    #pragma unroll
    for (int i = 0; i < 2; i++) {
        int u = tid + i * 512, t = u >> 6, hd = u & 63;
        Vb[(size_t)(rows0 + t) * 64 + hd] = f2bf(kqv[t][128 + hd]);
    }
    {
        int h = tid >> 6, i2 = (tid >> 3) & 7, j = tid & 7;
        float s = 0.0f;
        #pragma unroll
        for (int t = 0; t < 16; t++)
            s += kqv[t][64 + h * 8 + i2] * kqv[t][h * 8 + j];
        int bb = rows0 >> 9, part = (rows0 >> 4) & 31;
        Rpart[(size_t)(bb * 32 + part) * 512 + tid] = s;
    }
}

// ================= fused layer: softmax(R)->ab->proj(+x,+LN)->MLP1->MLP2(+x,+LN)->[QKV next] =================
__global__ __launch_bounds__(512, 4) void gpt_layer(
        const float* __restrict__ Rpart_in, const ushort* __restrict__ Vb_in,
        const ushort* __restrict__ WoT, const float* __restrict__ bo,
        const ushort* __restrict__ W1T, const float* __restrict__ b1,
        const ushort* __restrict__ W2T, const float* __restrict__ b2,
        const float* __restrict__ ls2, const float* __restrict__ lb2,
        const float* __restrict__ nls, const float* __restrict__ nlb,
        float* __restrict__ x,
        const ushort* __restrict__ WqkvT_next,
        ushort* __restrict__ Vb_out, float* __restrict__ Rpart_out,
        ushort* __restrict__ hbout, int mode) {
    __shared__ __align__(16) ushort Bs[256 * 64];     // 32 KB
    __shared__ __align__(16) ushort ffs[16 * 1024];   // 32 KB (aliased as kqv in QKV phase)
    __shared__ __align__(16) ushort h2s[16 * 256];    // 8 KB
    __shared__ __align__(16) ushort abl[16 * 64];     // 2 KB
    __shared__ __align__(16) ushort Vl[16 * 64];      // 2 KB
    __shared__ float Rs[512];                          // 2 KB
    __shared__ float red1[16][8], red2[16][8], mrow[16], rrow[16];

    const int tid = threadIdx.x, lane = tid & 63, wn = tid >> 6;
    const int rows0 = blockIdx.x * 16, b = rows0 >> 9;
    const int fr = lane & 15, fkb = (lane >> 4) * 16, rbase = (lane >> 4) * 4;
    int colv[2]; colv[0] = wn * 32 + fr; colv[1] = wn * 32 + 16 + fr;

    // ---- softmax(R) from 32 partials ----
    {
        const float* rp = Rpart_in + (size_t)b * 32 * 512 + tid;
        float s = 0.0f;
        #pragma unroll
        for (int p = 0; p < 32; p++) s += rp[p * 512];
        s *= (1.0f / 16.0f);
        int ii = (tid >> 3) & 7, j = tid & 7;
        float val = (j >= ii) ? s : -INFINITY;
        float m = val;
        #pragma unroll
        for (int off = 1; off < 8; off <<= 1) m = fmaxf(m, __shfl_xor(m, off, 8));
        float ex = __expf(val - m);
        float su = ex;
        #pragma unroll
        for (int off = 1; off < 8; off <<= 1) su += __shfl_xor(su, off, 8);
        Rs[tid] = ex / su;
    }
    #pragma unroll
    for (int i = 0; i < 2; i++) {
        int u = tid + i * 512, t = u >> 6, hd = u & 63;
        Vl[t * 64 + hd] = Vb_in[(size_t)(rows0 + t) * 64 + hd];
    }
    __syncthreads();
    // ---- ab = V @ R -> abl (bf16, swizzled A) ----
    #pragma unroll
    for (int i = 0; i < 2; i++) {
        int u = tid + i * 512, t = u >> 6, hd = u & 63, h = hd >> 3, j = hd & 7;
        float a = 0.0f;
        #pragma unroll
        for (int q = 0; q < 8; q++)
            a += bf2f(Vl[t * 64 + h * 8 + q]) * Rs[h * 64 + q * 8 + j];
        abl[t * 64 + (((hd * 2) ^ ((t & 7) << 4)) >> 1)] = f2bf(a);
    }
    // ---- proj: 16x256 = abl(16x64) @ WoT(256x64) ----
    s16x8 rbv[4];
    #pragma unroll
    for (int i = 0; i < 4; i++) {
        int u = tid + i * 512, r = u >> 3, ch = u & 7;
        rbv[i] = *(const s16x8*)&WoT[(size_t)r * 64 + ch * 8];
    }
    __syncthreads();
    #pragma unroll
    for (int i = 0; i < 4; i++) {
        int u = tid + i * 512, r = u >> 3, ch = u & 7;
        *(s16x8*)&Bs[r * 64 + (((ch * 16) ^ ((r & 7) << 4)) >> 1)] = rbv[i];
    }
    __syncthreads();
    f32x4 acc[2];
    acc[0] = (f32x4)0.0f; acc[1] = (f32x4)0.0f;
    #pragma unroll
    for (int kk = 0; kk < 2; kk++) {
        int kbyte = kk * 64 + fkb;
        s16x8 af = *(const s16x8*)&abl[fr * 64 + ((kbyte ^ ((fr & 7) << 4)) >> 1)];
        #pragma unroll
        for (int n = 0; n < 2; n++) {
            int brow = wn * 32 + n * 16 + fr;
            s16x8 bfv = *(const s16x8*)&Bs[brow * 64 + ((kbyte ^ ((brow & 7) << 4)) >> 1)];
            acc[n] = __builtin_amdgcn_mfma_f32_16x16x32_bf16(af, bfv, acc[n], 0, 0, 0);
        }
    }
    float xn[2][4];
    #pragma unroll
    for (int n = 0; n < 2; n++) {
        int col = colv[n];
        float bbv = bo[col];
        #pragma unroll
        for (int r = 0; r < 4; r++)
            xn[n][r] = acc[n][r] + bbv + x[(size_t)(rows0 + rbase + r) * 256 + col];
    }
    // ---- LN(ln2) -> h2s ----
    #pragma unroll
    for (int r = 0; r < 4; r++) {
        float s1 = xn[0][r] + xn[1][r];
        float s2 = xn[0][r] * xn[0][r] + xn[1][r] * xn[1][r];
        #pragma unroll
        for (int off = 1; off < 16; off <<= 1) {
            s1 += __shfl_xor(s1, off);
            s2 += __shfl_xor(s2, off);
        }
        if (fr == 0) { red1[rbase + r][wn] = s1; red2[rbase + r][wn] = s2; }
    }
    __syncthreads();
    if (tid < 16) {
        float s1 = 0.f, s2 = 0.f;
        #pragma unroll
        for (int w = 0; w < 8; w++) { s1 += red1[tid][w]; s2 += red2[tid][w]; }
        float mean = s1 * (1.0f / 256.0f);
        float var = s2 * (1.0f / 256.0f) - mean * mean;
        mrow[tid] = mean;
        rrow[tid] = rsqrtf(var + 1e-5f);
    }
    __syncthreads();
    #pragma unroll
    for (int n = 0; n < 2; n++) {
        int col = colv[n];
        float lsv = ls2[col], lbv = lb2[col];
        #pragma unroll
        for (int r = 0; r < 4; r++) {
            int rl = rbase + r;
            float hv = (xn[n][r] - mrow[rl]) * rrow[rl] * lsv + lbv;
            h2s[rl * 256 + (((col * 2) ^ ((rl & 7) << 4)) >> 1)] = f2bf(hv);
        }
    }
    // ---- MLP1: ff = relu(h2 @ W1T + b1), 4 chunks of 256 cols, ff stays in LDS ----
    #pragma unroll 1
    for (int c = 0; c < 4; c++) {
        const ushort* Bg = W1T + (size_t)c * 256 * 256;
        acc[0] = (f32x4)0.0f; acc[1] = (f32x4)0.0f;
        #pragma unroll
        for (int i = 0; i < 4; i++) {
            int u = tid + i * 512, r = u >> 3, ch = u & 7;
            rbv[i] = *(const s16x8*)&Bg[(size_t)r * 256 + ch * 8];
        }
        #pragma unroll 1
        for (int kt = 0; kt < 4; kt++) {
            __syncthreads();
            #pragma unroll
            for (int i = 0; i < 4; i++) {
                int u = tid + i * 512, r = u >> 3, ch = u & 7;
                *(s16x8*)&Bs[r * 64 + (((ch * 16) ^ ((r & 7) << 4)) >> 1)] = rbv[i];
            }
            __syncthreads();
            if (kt < 3) {
                int k0 = (kt + 1) * 64;
                #pragma unroll
                for (int i = 0; i < 4; i++) {
                    int u = tid + i * 512, r = u >> 3, ch = u & 7;
                    rbv[i] = *(const s16x8*)&Bg[(size_t)r * 256 + k0 + ch * 8];
                }
            }
            #pragma unroll
            for (int kk = 0; kk < 2; kk++) {
                int kbyte = kt * 128 + kk * 64 + fkb;
                s16x8 af = *(const s16x8*)&h2s[fr * 256 + ((kbyte ^ ((fr & 7) << 4)) >> 1)];
                int kb2 = kk * 64 + fkb;
                #pragma unroll
                for (int n = 0; n < 2; n++) {
                    int brow = wn * 32 + n * 16 + fr;
                    s16x8 bfv = *(const s16x8*)&Bs[brow * 64 + ((kb2 ^ ((brow & 7) << 4)) >> 1)];
                    acc[n] = __builtin_amdgcn_mfma_f32_16x16x32_bf16(af, bfv, acc[n], 0, 0, 0);
                }
            }
        }
        #pragma unroll
        for (int n = 0; n < 2; n++) {
            int col = c * 256 + colv[n];
            float bb1 = b1[col];
            #pragma unroll
            for (int r = 0; r < 4; r++) {
                int rl = rbase + r;
                ffs[rl * 1024 + (((col * 2) ^ ((rl & 7) << 4)) >> 1)] =
                    f2bf(fmaxf(acc[n][r] + bb1, 0.0f));
            }
        }
    }
    // ---- MLP2: x += ffs @ W2T + b2 (K=1024) ----
    f32x4 a2[2];
    a2[0] = (f32x4)0.0f; a2[1] = (f32x4)0.0f;
    #pragma unroll
    for (int i = 0; i < 4; i++) {
        int u = tid + i * 512, r = u >> 3, ch = u & 7;
        rbv[i] = *(const s16x8*)&W2T[(size_t)r * 1024 + ch * 8];
    }
    #pragma unroll 1
    for (int kt = 0; kt < 16; kt++) {
        __syncthreads();
        #pragma unroll
        for (int i = 0; i < 4; i++) {
            int u = tid + i * 512, r = u >> 3, ch = u & 7;
            *(s16x8*)&Bs[r * 64 + (((ch * 16) ^ ((r & 7) << 4)) >> 1)] = rbv[i];
        }
        __syncthreads();
        if (kt < 15) {
            int k0 = (kt + 1) * 64;
            #pragma unroll
            for (int i = 0; i < 4; i++) {
                int u = tid + i * 512, r = u >> 3, ch = u & 7;
                rbv[i] = *(const s16x8*)&W2T[(size_t)r * 1024 + k0 + ch * 8];
            }
        }
        #pragma unroll
        for (int kk = 0; kk < 2; kk++) {
            int kbyte = kt * 128 + kk * 64 + fkb;
            s16x8 af = *(const s16x8*)&ffs[fr * 1024 + ((kbyte ^ ((fr & 7) << 4)) >> 1)];
            int kb2 = kk * 64 + fkb;
            #pragma unroll
            for (int n = 0; n < 2; n++) {
                int brow = wn * 32 + n * 16 + fr;
                s16x8 bfv = *(const s16x8*)&Bs[brow * 64 + ((kb2 ^ ((brow & 7) << 4)) >> 1)];
                a2[n] = __builtin_amdgcn_mfma_f32_16x16x32_bf16(af, bfv, a2[n], 0, 0, 0);
            }
        }
    }
    #pragma unroll
    for (int n = 0; n < 2; n++) {
        int col = colv[n];
        float bb2 = b2[col];
        #pragma unroll
        for (int r = 0; r < 4; r++) {
            float v = xn[n][r] + a2[n][r] + bb2;
            xn[n][r] = v;
            x[(size_t)(rows0 + rbase + r) * 256 + col] = v;
        }
    }
    // ---- LN(next ln1 / lnf) -> h2s (and global hb if last layer) ----
    __syncthreads();
    #pragma unroll
    for (int r = 0; r < 4; r++) {
        float s1 = xn[0][r] + xn[1][r];
        float s2 = xn[0][r] * xn[0][r] + xn[1][r] * xn[1][r];
        #pragma unroll
        for (int off = 1; off < 16; off <<= 1) {
            s1 += __shfl_xor(s1, off);
            s2 += __shfl_xor(s2, off);
        }
        if (fr == 0) { red1[rbase + r][wn] = s1; red2[rbase + r][wn] = s2; }
    }
    __syncthreads();
    if (tid < 16) {
        float s1 = 0.f, s2 = 0.f;
        #pragma unroll
        for (int w = 0; w < 8; w++) { s1 += red1[tid][w]; s2 += red2[tid][w]; }
        float mean = s1 * (1.0f / 256.0f);
        float var = s2 * (1.0f / 256.0f) - mean * mean;
        mrow[tid] = mean;
        rrow[tid] = rsqrtf(var + 1e-5f);
    }
    __syncthreads();
    #pragma unroll
    for (int n = 0; n < 2; n++) {
        int col = colv[n];
        float lsv = nls[col], lbv = nlb[col];
        #pragma unroll
        for (int r = 0; r < 4; r++) {
            int rl = rbase + r;
            float hv = (xn[n][r] - mrow[rl]) * rrow[rl] * lsv + lbv;
            ushort hu = f2bf(hv);
            h2s[rl * 256 + (((col * 2) ^ ((rl & 7) << 4)) >> 1)] = hu;
            if (mode == 0)
                hbout[(size_t)(rows0 + rl) * 256 + col] = hu;
        }
    }
    if (mode == 0) return;

    // ---- QKV for next layer: kqv = h2 @ WqkvT_next (K=256), A from h2s ----
    float* kqv = (float*)ffs;   // 16 x 193 floats, aliases ffs (dead now)
    acc[0] = (f32x4)0.0f; acc[1] = (f32x4)0.0f;
    #pragma unroll
    for (int i = 0; i < 4; i++) {
        int u = tid + i * 512, r = u >> 3, ch = u & 7;
        rbv[i] = *(const s16x8*)&WqkvT_next[(size_t)r * 256 + ch * 8];
    }
    #pragma unroll 1
    for (int kt = 0; kt < 4; kt++) {
        __syncthreads();
        #pragma unroll
        for (int i = 0; i < 4; i++) {
            int u = tid + i * 512, r = u >> 3, ch = u & 7;
            *(s16x8*)&Bs[r * 64 + (((ch * 16) ^ ((r & 7) << 4)) >> 1)] = rbv[i];
        }
        __syncthreads();
        if (kt < 3) {
            int k0 = (kt + 1) * 64;
            #pragma unroll
            for (int i = 0; i < 4; i++) {
                int u = tid + i * 512, r = u >> 3, ch = u & 7;
                rbv[i] = *(const s16x8*)&WqkvT_next[(size_t)r * 256 + k0 + ch * 8];
            }
        }
        #pragma unroll
        for (int kk = 0; kk < 2; kk++) {
            int kbyte = kt * 128 + kk * 64 + fkb;
            s16x8 af = *(const s16x8*)&h2s[fr * 256 + ((kbyte ^ ((fr & 7) << 4)) >> 1)];
            int kb2 = kk * 64 + fkb;
            #pragma unroll
            for (int n = 0; n < 2; n++) {
                int brow = wn * 32 + n * 16 + fr;
                s16x8 bfv = *(const s16x8*)&Bs[brow * 64 + ((kb2 ^ ((brow & 7) << 4)) >> 1)];
                acc[n] = __builtin_amdgcn_mfma_f32_16x16x32_bf16(af, bfv, acc[n], 0, 0, 0);
            }
        }
    }
    __syncthreads();   // ffs reads (MLP2) long done; safe to write kqv
    #pragma unroll
    for (int n = 0; n < 2; n++) {
        int col = wn * 32 + n * 16 + fr;
        if (col < 192) {
            #pragma unroll
            for (int r = 0; r < 4; r++)
                kqv[(rbase + r) * 193 + col] = acc[n][r];
        }
    }
    __syncthreads();
    #pragma unroll
    for (int i = 0; i < 2; i++) {
        int u = tid + i * 512, t = u >> 6, hd = u & 63;
        Vb_out[(size_t)(rows0 + t) * 64 + hd] = f2bf(kqv[t * 193 + 128 + hd]);
    }
    {
        int h = tid >> 6, i2 = (tid >> 3) & 7, j = tid & 7;
        float s = 0.0f;
        #pragma unroll
        for (int t = 0; t < 16; t++)
            s += kqv[t * 193 + 64 + h * 8 + i2] * kqv[t * 193 + h * 8 + j];
        int part = (rows0 >> 4) & 31;
        Rpart_out[(size_t)(b * 32 + part) * 512 + tid] = s;
    }
}

// ================= logits GEMM: 128x256 tile, 512 thr, global_load_lds staging =================
// LDS stays LINEAR per row; XOR-swizzle applied to the per-lane GLOBAL source chunk
// (m173 pattern) so the MFMA read path is identical to the reg-staged version.
__global__ __launch_bounds__(512, 4) void gpt_logits_mfma(const ushort* __restrict__ hb, const ushort* __restrict__ WfT,
                                                          const float* __restrict__ bfb, float* __restrict__ out,
                                                          float2* __restrict__ lsebuf) {
    __shared__ __align__(16) ushort As[128 * 64];   // 16 KB
    __shared__ __align__(16) ushort Bs[256 * 64];   // 32 KB
    f32x4 acc[4][4];
    // XCD-bijective swizzle: 6304 blocks = 8 * 788
    int flat = blockIdx.y * 32 + blockIdx.x;
    int nf = (flat & 7) * 788 + (flat >> 3);
    int rb = nf & 31, cb = nf >> 5;
    int row0 = rb * 128, c0 = cb * 256;
    const int tid = threadIdx.x, lane = tid & 63, wid = tid >> 6;
    const int wm = wid >> 2, wn = wid & 3;           // 2 x 4 waves, 64x64 each
    const int fr = lane & 15, fkb = (lane >> 4) * 16;

    #pragma unroll
    for (int m = 0; m < 4; m++)
        #pragma unroll
        for (int n = 0; n < 4; n++) acc[m][n] = (f32x4)0.0f;

    // staging geometry: each global_load_lds instr moves 1 KB/wave = 8 rows x 128B
    const int srow = lane >> 3;            // 0..7 row within 8-row group
    const int sch = lane & 7;              // dest 16B chunk within row
    #pragma unroll 1
    for (int kt = 0; kt < 4; kt++) {
        if (kt) __syncthreads();
        {
            int kb = kt * 64;
            // A: 16 KB = 2 instrs/wave; wave wid covers rows [wid*16, wid*16+16)
            #pragma unroll
            for (int i = 0; i < 2; i++) {
                int rloc = wid * 16 + i * 8 + srow;
                int cs = sch ^ (rloc & 7);
                const ushort* gp = &hb[(size_t)(row0 + rloc) * 256 + kb + cs * 8];
                __builtin_amdgcn_global_load_lds((const AS1 void*)gp,
                                                 (AS3 void*)&As[(wid * 16 + i * 8) * 64], 16, 0, 0);
            }
            // B: 32 KB = 4 instrs/wave; wave wid covers rows [wid*32, wid*32+32)
            #pragma unroll
            for (int i = 0; i < 4; i++) {
                int rloc = wid * 32 + i * 8 + srow;
                int cs = sch ^ (rloc & 7);
                const ushort* gp = &WfT[(size_t)(c0 + rloc) * 256 + kb + cs * 8];
                __builtin_amdgcn_global_load_lds((const AS1 void*)gp,
                                                 (AS3 void*)&Bs[(wid * 32 + i * 8) * 64], 16, 0, 0);
            }
        }
        __syncthreads();   // drains vmcnt (global_load_lds) + orders LDS
        #pragma unroll
        for (int kk = 0; kk < 2; kk++) {
            int kbyte = kk * 64 + fkb;
            s16x8 af[4], bfr[4];
            #pragma unroll
            for (int m = 0; m < 4; m++) {
                int arow = wm * 64 + m * 16 + fr;
                af[m] = *(const s16x8*)&As[arow * 64 + ((kbyte ^ ((arow & 7) << 4)) >> 1)];
            }
            #pragma unroll
            for (int n = 0; n < 4; n++) {
                int brow = wn * 64 + n * 16 + fr;
                bfr[n] = *(const s16x8*)&Bs[brow * 64 + ((kbyte ^ ((brow & 7) << 4)) >> 1)];
            }
            #pragma unroll
            for (int m = 0; m < 4; m++)
                #pragma unroll
                for (int n = 0; n < 4; n++)
                    acc[m][n] = __builtin_amdgcn_mfma_f32_16x16x32_bf16(af[m], bfr[n], acc[m][n], 0, 0, 0);
        }
    }
    // epilogue: bias + store + per-row (max,sumexp) partials
    float bb[4]; int gcv[4];
    #pragma unroll
    for (int n = 0; n < 4; n++) {
        int gc = c0 + wn * 64 + n * 16 + fr;
        gcv[n] = gc;
        bb[n] = (gc < V_SZ) ? bfb[gc] : 0.0f;
    }
    __syncthreads();                       // all MFMA reads of As done -> reuse as reduce buffer
    float2 (*red)[4] = (float2(*)[4])As;   // [128][4]
    #pragma unroll
    for (int m = 0; m < 4; m++) {
        int rloc = wm * 64 + m * 16 + (lane >> 4) * 4;
        int gr = row0 + rloc;
        #pragma unroll
        for (int r = 0; r < 4; r++) {
            float v[4];
            float vmax = -1e30f;
            #pragma unroll
            for (int n = 0; n < 4; n++) {
                v[n] = (gcv[n] < V_SZ) ? acc[m][n][r] + bb[n] : -1e30f;
                vmax = fmaxf(vmax, v[n]);
            }
            #pragma unroll
            for (int n = 0; n < 4; n++)
                if (gcv[n] < V_SZ)
                    out[(size_t)(gr + r) * V_SZ + gcv[n]] = v[n];
            #pragma unroll
            for (int off = 1; off < 16; off <<= 1)
                vmax = fmaxf(vmax, __shfl_xor(vmax, off));
            float vsum = __expf(v[0] - vmax) + __expf(v[1] - vmax)
                       + __expf(v[2] - vmax) + __expf(v[3] - vmax);
            #pragma unroll
            for (int off = 1; off < 16; off <<= 1)
                vsum += __shfl_xor(vsum, off);
            if ((lane & 15) == 0)
                red[rloc + r][wn] = make_float2(vmax, vsum);
        }
    }
    __syncthreads();
    if (tid < 128) {
        float M = -1e30f, S = 0.0f;
        #pragma unroll
        for (int w = 0; w < 4; w++) {
            float2 p = red[tid][w];
            float M2 = fmaxf(M, p.x);
            S = S * __expf(M - M2) + p.y * __expf(p.x - M2);
            M = M2;
        }
        lsebuf[(size_t)(row0 + tid) * NCB + cb] = make_float2(M, S);
    }
}

// ================= lse finish =================
__global__ __launch_bounds__(256) void gpt_lse(const float2* __restrict__ lsebuf, const float* __restrict__ out,
                                               const int* __restrict__ tgt, float* __restrict__ partial) {
    int wave = threadIdx.x >> 6, lane = threadIdx.x & 63;
    int row = blockIdx.x * 4 + wave;
    float m = -INFINITY, s = 0.0f;
    for (int i = lane; i < NCB; i += 64) {
        float2 p = lsebuf[(size_t)row * NCB + i];
        float M = fmaxf(m, p.x);
        s = s * __expf(m - M) + p.y * __expf(p.x - M);
        m = M;
    }
    #pragma unroll
    for (int off = 1; off < 64; off <<= 1) {
        float m2 = __shfl_xor(m, off);
        float s2 = __shfl_xor(s, off);
        float M = fmaxf(m, m2);
        s = s * __expf(m - M) + s2 * __expf(m2 - M);
        m = M;
    }
    if (lane == 0)
        partial[row] = m + logf(s) - out[(size_t)row * V_SZ + tgt[row]];
}

__global__ void gpt_loss_reduce(const float* __restrict__ partial, float* __restrict__ out) {
    __shared__ float red[256];
    int tid = threadIdx.x;
    float s = 0.0f;
    for (int i = tid; i < 4096; i += 256) s += partial[i];
    red[tid] = s;
    __syncthreads();
    for (int off = 128; off > 0; off >>= 1) {
        if (tid < off) red[tid] += red[tid + off];
        __syncthreads();
    }
    if (tid == 0) out[0] = red[0] * (1.0f / 4096.0f);
}

// ======================= fp32 fallback kernels (small-ws path) =======================
__global__ void gpt_embed(const int* __restrict__ tokens, const float* __restrict__ tok_emb,
                          const float* __restrict__ pos_emb, float* __restrict__ x) {
    int idx = blockIdx.x * 256 + threadIdx.x;
    int bt = idx >> 8, e = idx & 255;
    int t = bt & 511;
    int tok = tokens[bt];
    x[idx] = tok_emb[tok * 256 + e] + pos_emb[t * 256 + e];
}

__global__ void gpt_ln(const float* __restrict__ x, const float* __restrict__ s,
                       const float* __restrict__ b, float* __restrict__ h) {
    __shared__ float red[256];
    int row = blockIdx.x, e = threadIdx.x;
    float v = x[row * 256 + e];
    red[e] = v;
    __syncthreads();
    for (int off = 128; off > 0; off >>= 1) {
        if (e < off) red[e] += red[e + off];
        __syncthreads();
    }
    float mean = red[0] * (1.0f / 256.0f);
    __syncthreads();
    float d = v - mean;
    red[e] = d * d;
    __syncthreads();
    for (int off = 128; off > 0; off >>= 1) {
        if (e < off) red[e] += red[e + off];
        __syncthreads();
    }
    float rstd = rsqrtf(red[0] * (1.0f / 256.0f) + 1e-5f);
    h[row * 256 + e] = d * rstd * s[e] + b[e];
}

__global__ void gpt_qkv(const float* __restrict__ h, const float* __restrict__ Wq,
                        const float* __restrict__ Wk, const float* __restrict__ Wv,
                        float* __restrict__ Q, float* __restrict__ K, float* __restrict__ Vv) {
    __shared__ float hs[8][256];
    int tid = threadIdx.x;
    int row0 = blockIdx.x * 8;
    #pragma unroll
    for (int r = 0; r < 8; r++) hs[r][tid] = h[(row0 + r) * 256 + tid];
    __syncthreads();
    if (tid < 192) {
        int kind = tid >> 6, o = tid & 63, hh = o >> 3, d = o & 7;
        const float* W = kind == 0 ? Wq : (kind == 1 ? Wk : Wv);
        const float* wp = W + hh * 2048 + d;
        float acc[8];
        #pragma unroll
        for (int r = 0; r < 8; r++) acc[r] = 0.0f;
        for (int e = 0; e < 256; e++) {
            float w = wp[e * 8];
            #pragma unroll
            for (int r = 0; r < 8; r++) acc[r] += hs[r][e] * w;
        }
        float* outp = kind == 0 ? Q : (kind == 1 ? K : Vv);
        int b = row0 >> 9;
        #pragma unroll
        for (int r = 0; r < 8; r++) {
            int t = (row0 + r) & 511;
            outp[((b * 8 + hh) * 512 + t) * 8 + d] = acc[r];
        }
    }
}

__global__ void gpt_attn_r(const float* __restrict__ K, const float* __restrict__ Q,
                           float* __restrict__ R) {
    __shared__ __align__(16) float Ks[64][8];
    __shared__ __align__(16) float Qs[64][8];
    int bh = blockIdx.x, tid = threadIdx.x;
    int i = tid >> 3, j = tid & 7;
    const float* Kb = K + bh * 512 * 8;
    const float* Qb = Q + bh * 512 * 8;
    float acc = 0.0f;
    for (int t0 = 0; t0 < 512; t0 += 64) {
        *(float4*)&Ks[tid][0] = *(const float4*)&Kb[(t0 + tid) * 8];
        *(float4*)&Ks[tid][4] = *(const float4*)&Kb[(t0 + tid) * 8 + 4];
        *(float4*)&Qs[tid][0] = *(const float4*)&Qb[(t0 + tid) * 8];
        *(float4*)&Qs[tid][4] = *(const float4*)&Qb[(t0 + tid) * 8 + 4];
        __syncthreads();
        #pragma unroll 16
        for (int t = 0; t < 64; t++) acc += Ks[t][i] * Qs[t][j];
        __syncthreads();
    }
    acc *= (1.0f / 16.0f);
    float val = (j >= i) ? acc : -INFINITY;
    float m = val;
    #pragma unroll
    for (int off = 1; off < 8; off <<= 1) m = fmaxf(m, __shfl_xor(m, off, 8));
    float ex = expf(val - m);
    float sum = ex;
    #pragma unroll
    for (int off = 1; off < 8; off <<= 1) sum += __shfl_xor(sum, off, 8);
    R[bh * 64 + tid] = ex / sum;
}

__global__ void gpt_attn_out(const float* __restrict__ Vv, const float* __restrict__ R,
                             const float* __restrict__ Wo, const float* __restrict__ bo,
                             float* __restrict__ x) {
    __shared__ __align__(16) float as[8][64];
    int tid = threadIdx.x;
    int row0 = blockIdx.x * 8;
    int b = row0 >> 9;
    #pragma unroll
    for (int k = 0; k < 2; k++) {
        int idx = k * 256 + tid;
        int r = idx >> 6, hd = idx & 63;
        int hh = hd >> 3, jj = hd & 7;
        int t = (row0 + r) & 511;
        const float* vp = Vv + ((b * 8 + hh) * 512 + t) * 8;
        const float* rp = R + (b * 8 + hh) * 64 + jj;
        float a = 0.0f;
        #pragma unroll
        for (int i = 0; i < 8; i++) a += vp[i] * rp[i * 8];
        as[r][hd] = a;
    }
    __syncthreads();
    float acc[8];
    float bb = bo[tid];
    #pragma unroll
    for (int r = 0; r < 8; r++) acc[r] = bb;
    for (int hd0 = 0; hd0 < 64; hd0 += 4) {
        float w0 = Wo[(hd0 + 0) * 256 + tid];
        float w1 = Wo[(hd0 + 1) * 256 + tid];
        float w2 = Wo[(hd0 + 2) * 256 + tid];
        float w3 = Wo[(hd0 + 3) * 256 + tid];
        #pragma unroll
        for (int r = 0; r < 8; r++) {
            float4 av = *(const float4*)&as[r][hd0];
            acc[r] += av.x * w0 + av.y * w1 + av.z * w2 + av.w * w3;
        }
    }
    #pragma unroll
    for (int r = 0; r < 8; r++) x[(row0 + r) * 256 + tid] += acc[r];
}

__global__ __launch_bounds__(256) void gpt_mlp(const float* __restrict__ h, const float* __restrict__ W1,
                         const float* __restrict__ b1, const float* __restrict__ W2,
                         const float* __restrict__ b2, float* __restrict__ x) {
    __shared__ __align__(16) float hs[8][256];
    __shared__ __align__(16) float ffs[8][1024];
    int tid = threadIdx.x;
    int row0 = blockIdx.x * 8;
    #pragma unroll
    for (int r = 0; r < 8; r++) hs[r][tid] = h[(row0 + r) * 256 + tid];
    __syncthreads();
    {
        float acc[4][8];
        #pragma unroll
        for (int k = 0; k < 4; k++) {
            float bb = b1[k * 256 + tid];
            #pragma unroll
            for (int r = 0; r < 8; r++) acc[k][r] = bb;
        }
        for (int e0 = 0; e0 < 256; e0 += 4) {
            float w[4][4];
            #pragma unroll
            for (int ee = 0; ee < 4; ee++)
                #pragma unroll
                for (int k = 0; k < 4; k++)
                    w[ee][k] = W1[(e0 + ee) * 1024 + k * 256 + tid];
            #pragma unroll
            for (int r = 0; r < 8; r++) {
                float4 hv = *(const float4*)&hs[r][e0];
                #pragma unroll
                for (int k = 0; k < 4; k++)
                    acc[k][r] += hv.x * w[0][k] + hv.y * w[1][k] + hv.z * w[2][k] + hv.w * w[3][k];
            }
        }
        #pragma unroll
        for (int k = 0; k < 4; k++)
            #pragma unroll
            for (int r = 0; r < 8; r++)
                ffs[r][k * 256 + tid] = fmaxf(acc[k][r], 0.0f);
    }
    __syncthreads();
    {
        float acc[8];
        float bb = b2[tid];
        #pragma unroll
        for (int r = 0; r < 8; r++) acc[r] = bb;
        for (int f0 = 0; f0 < 1024; f0 += 4) {
            float w0 = W2[(f0 + 0) * 256 + tid];
            float w1 = W2[(f0 + 1) * 256 + tid];
            float w2 = W2[(f0 + 2) * 256 + tid];
            float w3 = W2[(f0 + 3) * 256 + tid];
            #pragma unroll
            for (int r = 0; r < 8; r++) {
                float4 fv = *(const float4*)&ffs[r][f0];
                acc[r] += fv.x * w0 + fv.y * w1 + fv.z * w2 + fv.w * w3;
            }
        }
        #pragma unroll
        for (int r = 0; r < 8; r++) x[(row0 + r) * 256 + tid] += acc[r];
    }
}

__global__ __launch_bounds__(256) void gpt_logits(const float* __restrict__ hf, const float* __restrict__ Wf,
                            const float* __restrict__ bf, float* __restrict__ out) {
    __shared__ __align__(16) float hs[32][256];
    int tid = threadIdx.x;
    int row0 = blockIdx.y * 32;
    #pragma unroll
    for (int r = 0; r < 32; r++) hs[r][tid] = hf[(row0 + r) * 256 + tid];
    __syncthreads();
    int c0 = blockIdx.x * 512 + tid;
    int c1 = c0 + 256;
    int c0c = c0 < V_SZ ? c0 : V_SZ - 1;
    int c1c = c1 < V_SZ ? c1 : V_SZ - 1;
    float acc0[32], acc1[32];
    float b0 = bf[c0c], b1 = bf[c1c];
    #pragma unroll
    for (int r = 0; r < 32; r++) { acc0[r] = b0; acc1[r] = b1; }
    const float* p0 = Wf + c0c;
    const float* p1 = Wf + c1c;
    for (int e0 = 0; e0 < 256; e0 += 4) {
        float w00 = p0[(size_t)(e0 + 0) * V_SZ];
        float w01 = p0[(size_t)(e0 + 1) * V_SZ];
        float w02 = p0[(size_t)(e0 + 2) * V_SZ];
        float w03 = p0[(size_t)(e0 + 3) * V_SZ];
        float w10 = p1[(size_t)(e0 + 0) * V_SZ];
        float w11 = p1[(size_t)(e0 + 1) * V_SZ];
        float w12 = p1[(size_t)(e0 + 2) * V_SZ];
        float w13 = p1[(size_t)(e0 + 3) * V_SZ];
        #pragma unroll
        for (int r = 0; r < 32; r++) {
            float4 hv = *(const float4*)&hs[r][e0];
            acc0[r] += hv.x * w00 + hv.y * w01 + hv.z * w02 + hv.w * w03;
            acc1[r] += hv.x * w10 + hv.y * w11 + hv.z * w12 + hv.w * w13;
        }
    }
    if (c0 < V_SZ) {
        #pragma unroll
        for (int r = 0; r < 32; r++) out[(size_t)(row0 + r) * V_SZ + c0] = acc0[r];
    }
    if (c1 < V_SZ) {
        #pragma unroll
        for (int r = 0; r < 32; r++) out[(size_t)(row0 + r) * V_SZ + c1] = acc1[r];
    }
}

__global__ void gpt_loss(const float* __restrict__ logits, const int* __restrict__ tgt,
                         float* __restrict__ partial) {
    __shared__ float ms[256], ss[256];
    int row = blockIdx.x, tid = threadIdx.x;
    const float* lr = logits + (size_t)row * V_SZ;
    float m = -INFINITY, s = 0.0f;
    for (int c = tid; c < V_SZ; c += 256) {
        float v = lr[c];
        float nm = fmaxf(m, v);
        s = s * expf(m - nm) + expf(v - nm);
        m = nm;
    }
    ms[tid] = m; ss[tid] = s;
    __syncthreads();
    for (int off = 128; off > 0; off >>= 1) {
        if (tid < off) {
            float m2 = ms[tid + off], s2 = ss[tid + off];
            float M = fmaxf(ms[tid], m2);
            ss[tid] = ss[tid] * expf(ms[tid] - M) + s2 * expf(m2 - M);
            ms[tid] = M;
        }
        __syncthreads();
    }
    if (tid == 0) {
        float lse = ms[0] + logf(ss[0]);
        partial[row] = lse - lr[tgt[row]];
    }
}

// ======================= launch =======================
extern "C" void kernel_launch(void* const* d_in, const int* in_sizes, int n_in,
                              void* d_out, int out_size, void* d_ws, size_t ws_size,
                              hipStream_t stream) {
    const int*   tokens  = (const int*)d_in[0];
    const int*   ideal   = (const int*)d_in[1];
    const float* tok_emb = (const float*)d_in[2];
    const float* pos_emb = (const float*)d_in[3];
    const float* Wq      = (const float*)d_in[4];
    const float* Wk      = (const float*)d_in[5];
    const float* Wv      = (const float*)d_in[6];
    const float* Wo      = (const float*)d_in[7];
    const float* bo      = (const float*)d_in[8];
    const float* ln1_s   = (const float*)d_in[9];
    const float* ln1_b   = (const float*)d_in[10];
    const float* W1      = (const float*)d_in[11];
    const float* b1      = (const float*)d_in[12];
    const float* W2      = (const float*)d_in[13];
    const float* b2      = (const float*)d_in[14];
    const float* ln2_s   = (const float*)d_in[15];
    const float* ln2_b   = (const float*)d_in[16];
    const float* lnf_s   = (const float*)d_in[17];
    const float* lnf_b   = (const float*)d_in[18];
    const float* Wf      = (const float*)d_in[19];
    const float* bf      = (const float*)d_in[20];
    float* out = (float*)d_out;

    // ---- workspace layout (bf16 path) ----
    size_t off = 0;
    char* wsc = (char*)d_ws;
    ushort* WfT   = (ushort*)(wsc + off); off += (size_t)NPAD * 256 * 2;
    ushort* W1T   = (ushort*)(wsc + off); off += (size_t)16 * 1024 * 256 * 2;
    ushort* W2T   = (ushort*)(wsc + off); off += (size_t)16 * 256 * 1024 * 2;
    ushort* WqkvT = (ushort*)(wsc + off); off += (size_t)16 * 256 * 256 * 2;
    ushort* WoT   = (ushort*)(wsc + off); off += (size_t)16 * 256 * 64 * 2;
    ushort* hb    = (ushort*)(wsc + off); off += (size_t)4096 * 256 * 2;
    ushort* Vb0   = (ushort*)(wsc + off); off += (size_t)4096 * 64 * 2;
    ushort* Vb1   = (ushort*)(wsc + off); off += (size_t)4096 * 64 * 2;
    float*  x     = (float*)(wsc + off);  off += (size_t)4096 * 256 * 4;
    float*  Rp0   = (float*)(wsc + off);  off += (size_t)8 * 32 * 512 * 4;
    float*  Rp1   = (float*)(wsc + off);  off += (size_t)8 * 32 * 512 * 4;
    float*  partial = (float*)(wsc + off); off += (size_t)4096 * 4;
    float2* lsebuf = (float2*)(wsc + off); off += (size_t)4096 * NCB * 8;
    bool big = ws_size >= off;

    if (big) {
        cvt_transpose<<<dim3(16, 4, 16), 256, 0, stream>>>(W1, W1T, 256, 1024, 1024, 262144, 262144);
        cvt_transpose<<<dim3(4, 16, 16), 256, 0, stream>>>(W2, W2T, 1024, 256, 256, 262144, 262144);
        cvt_transpose<<<dim3(4, 1, 16), 256, 0, stream>>>(Wo, WoT, 64, 256, 256, 16384, 16384);
        cvt_transpose<<<dim3(788, 4, 1), 256, 0, stream>>>(Wf, WfT, 256, V_SZ, V_SZ, 0, 0);
        cvt_qkv<<<dim3(16, 3), 256, 0, stream>>>(Wq, Wk, Wv, WqkvT);

        gpt_embed_ln<<<1024, 256, 0, stream>>>(tokens, tok_emb, pos_emb, ln1_s, ln1_b, x, hb);
        gpt_pre<<<256, 512, 0, stream>>>(hb, WqkvT, Vb0, Rp0);

        for (int l = 0; l < 16; l++) {
            const float* nls = (l < 15) ? ln1_s + (l + 1) * 256 : lnf_s;
            const float* nlb = (l < 15) ? ln1_b + (l + 1) * 256 : lnf_b;
            const float* Rin = (l & 1) ? Rp1 : Rp0;
            const ushort* Vin = (l & 1) ? Vb1 : Vb0;
            float* Rout = (l & 1) ? Rp0 : Rp1;
            ushort* Vout = (l & 1) ? Vb0 : Vb1;
            int mode = (l < 15) ? 1 : 0;
            const ushort* Wnext = WqkvT + (size_t)((l < 15) ? (l + 1) : 0) * 65536;
            gpt_layer<<<256, 512, 0, stream>>>(Rin, Vin,
                                               WoT + (size_t)l * 16384, bo + l * 256,
                                               W1T + (size_t)l * 262144, b1 + l * 1024,
                                               W2T + (size_t)l * 262144, b2 + l * 256,
                                               ln2_s + l * 256, ln2_b + l * 256,
                                               nls, nlb, x,
                                               Wnext, Vout, Rout, hb, mode);
        }

        gpt_logits_mfma<<<dim3(32, NCB), 512, 0, stream>>>(hb, WfT, bf, out, lsebuf);
        gpt_lse<<<1024, 256, 0, stream>>>(lsebuf, out, ideal, partial);
        gpt_loss_reduce<<<1, 256, 0, stream>>>(partial, out + (size_t)4096 * V_SZ);
    } else {
        // fp32 fallback
        float* fx  = (float*)d_ws;
        float* fh  = fx + 4096 * 256;
        float* fQ  = fh + 4096 * 256;
        float* fK  = fQ + 4096 * 64;
        float* fV  = fK + 4096 * 64;
        float* fR  = fV + 4096 * 64;
        float* fpart = fR + 64 * 64;
        gpt_embed<<<4096, 256, 0, stream>>>(tokens, tok_emb, pos_emb, fx);
        for (int l = 0; l < 16; l++) {
            gpt_ln<<<4096, 256, 0, stream>>>(fx, ln1_s + l * 256, ln1_b + l * 256, fh);
            gpt_qkv<<<512, 256, 0, stream>>>(fh, Wq + l * 16384, Wk + l * 16384, Wv + l * 16384, fQ, fK, fV);
            gpt_attn_r<<<64, 64, 0, stream>>>(fK, fQ, fR);
            gpt_attn_out<<<512, 256, 0, stream>>>(fV, fR, Wo + l * 16384, bo + l * 256, fx);
            gpt_ln<<<4096, 256, 0, stream>>>(fx, ln2_s + l * 256, ln2_b + l * 256, fh);
            gpt_mlp<<<512, 256, 0, stream>>>(fh, W1 + l * 262144, b1 + l * 1024, W2 + l * 262144, b2 + l * 256, fx);
        }
        gpt_ln<<<4096, 256, 0, stream>>>(fx, lnf_s, lnf_b, fh);
        dim3 lg(99, 128);
        gpt_logits<<<lg, 256, 0, stream>>>(fh, Wf, bf, out);
        gpt_loss<<<4096, 256, 0, stream>>>(out, ideal, fpart);
        gpt_loss_reduce<<<1, 256, 0, stream>>>(fpart, out + (size_t)4096 * V_SZ);
    }
}

// Round 13
// 917.227 us; speedup vs baseline: 2.2984x; 1.0953x over previous
//
#include <hip/hip_runtime.h>
#include <math.h>

#define V_SZ 50257
#define NPAD 50432   // 197 * 256
#define NCB 197

#define AS1 __attribute__((address_space(1)))
#define AS3 __attribute__((address_space(3)))

typedef short s16x8 __attribute__((ext_vector_type(8)));
typedef ushort u16x4 __attribute__((ext_vector_type(4)));
typedef float f32x4 __attribute__((ext_vector_type(4)));

__device__ __forceinline__ ushort f2bf(float x) {
    union { float f; unsigned u; } v; v.f = x;
    unsigned r = v.u + 0x7FFF + ((v.u >> 16) & 1);   // RNE
    return (ushort)(r >> 16);
}
__device__ __forceinline__ float bf2f(ushort u) {
    union { unsigned u; float f; } v; v.u = ((unsigned)u) << 16; return v.f;
}

// ================= embed + ln1(layer0): wave per row =================
__global__ __launch_bounds__(256) void gpt_embed_ln(const int* __restrict__ tokens,
                                                    const float* __restrict__ tok_emb,
                                                    const float* __restrict__ pos_emb,
                                                    const float* __restrict__ s, const float* __restrict__ b,
                                                    float* __restrict__ x, ushort* __restrict__ hb) {
    int wave = threadIdx.x >> 6, lane = threadIdx.x & 63;
    int row = blockIdx.x * 4 + wave;
    int t = row & 511;
    int tok = tokens[row];
    float4 te = ((const float4*)(tok_emb + tok * 256))[lane];
    float4 pe = ((const float4*)(pos_emb + t * 256))[lane];
    float4 v = make_float4(te.x + pe.x, te.y + pe.y, te.z + pe.z, te.w + pe.w);
    ((float4*)(x + row * 256))[lane] = v;
    float sum = v.x + v.y + v.z + v.w;
    #pragma unroll
    for (int off = 1; off < 64; off <<= 1) sum += __shfl_xor(sum, off);
    float mean = sum * (1.0f / 256.0f);
    float dx = v.x - mean, dy = v.y - mean, dz = v.z - mean, dw = v.w - mean;
    float vs = dx * dx + dy * dy + dz * dz + dw * dw;
    #pragma unroll
    for (int off = 1; off < 64; off <<= 1) vs += __shfl_xor(vs, off);
    float rstd = rsqrtf(vs * (1.0f / 256.0f) + 1e-5f);
    float4 sv = ((const float4*)s)[lane];
    float4 bv = ((const float4*)b)[lane];
    u16x4 o;
    o[0] = f2bf(dx * rstd * sv.x + bv.x);
    o[1] = f2bf(dy * rstd * sv.y + bv.y);
    o[2] = f2bf(dz * rstd * sv.z + bv.z);
    o[3] = f2bf(dw * rstd * sv.w + bv.w);
    *(u16x4*)&hb[row * 256 + lane * 4] = o;
}

// ================= generic transpose+convert: in fp32 [Kd][Nd] -> out bf16 [n][k] =================
__global__ __launch_bounds__(256) void cvt_transpose(const float* __restrict__ in, ushort* __restrict__ out,
                                                     int Kd, int Nd, int n_real,
                                                     int in_stride, int out_stride) {
    __shared__ __align__(16) ushort t[64][80];
    const float* inp = in + (size_t)blockIdx.z * in_stride;
    ushort* outp = out + (size_t)blockIdx.z * out_stride;
    int n0 = blockIdx.x * 64, k0 = blockIdx.y * 64;
    int tid = threadIdx.x;
    #pragma unroll
    for (int p = 0; p < 4; p++) {
        int lk = p * 16 + (tid >> 4);
        int ln = (tid & 15) * 4;
        int k = k0 + lk, n = n0 + ln;
        const float* rowp = inp + (size_t)k * Nd;
        float v0 = 0.f, v1 = 0.f, v2 = 0.f, v3 = 0.f;
        if (n + 0 < n_real) v0 = rowp[n + 0];
        if (n + 1 < n_real) v1 = rowp[n + 1];
        if (n + 2 < n_real) v2 = rowp[n + 2];
        if (n + 3 < n_real) v3 = rowp[n + 3];
        t[ln + 0][lk] = f2bf(v0);
        t[ln + 1][lk] = f2bf(v1);
        t[ln + 2][lk] = f2bf(v2);
        t[ln + 3][lk] = f2bf(v3);
    }
    __syncthreads();
    int ln = tid >> 2, kq = (tid & 3) * 16;
    ushort* op = outp + (size_t)(n0 + ln) * Kd + k0 + kq;
    *(s16x8*)&op[0] = *(const s16x8*)&t[ln][kq];
    *(s16x8*)&op[8] = *(const s16x8*)&t[ln][kq + 8];
}

// ================= Wq/Wk/Wv [L][H][E][D] -> WqkvT [L][256][256] (rows 192..255 zero) =================
__global__ __launch_bounds__(256) void cvt_qkv(const float* __restrict__ Wq, const float* __restrict__ Wk,
                                               const float* __restrict__ Wv, ushort* __restrict__ WqkvT) {
    int l = blockIdx.x, kind = blockIdx.y;
    const float* W = (kind == 0 ? Wq : (kind == 1 ? Wk : Wv)) + l * 16384;
    ushort* out = WqkvT + (size_t)l * 65536 + kind * 64 * 256;
    int tid = threadIdx.x;
    #pragma unroll 4
    for (int it = 0; it < 64; it++) {
        int idx = it * 256 + tid;
        int row = idx >> 8, e = idx & 255;
        int h = row >> 3, d = row & 7;
        out[row * 256 + e] = f2bf(W[h * 2048 + e * 8 + d]);
    }
    if (kind == 0) {
        ushort* zp = WqkvT + (size_t)l * 65536 + 192 * 256;
        #pragma unroll 4
        for (int it = 0; it < 64; it++) zp[it * 256 + tid] = 0;
    }
}

// ================= pre: QKV (16 rows/block) + V out + R partials (layer 0 only) =================
__global__ __launch_bounds__(512, 4) void gpt_pre(const ushort* __restrict__ hb,
                                                  const ushort* __restrict__ WqkvT,
                                                  ushort* __restrict__ Vb,
                                                  float* __restrict__ Rpart) {
    __shared__ __align__(16) ushort As[16 * 64];
    __shared__ __align__(16) ushort Bs[256 * 64];
    __shared__ float kqv[16][193];
    const int tid = threadIdx.x, lane = tid & 63, wn = tid >> 6;
    const int rows0 = blockIdx.x * 16;
    const int fr = lane & 15, fkb = (lane >> 4) * 16;
    const int arow = tid >> 3, ach = tid & 7;

    f32x4 acc[2];
    acc[0] = (f32x4)0.0f; acc[1] = (f32x4)0.0f;

    s16x8 ra, rb[4];
    if (tid < 128) ra = *(const s16x8*)&hb[(size_t)(rows0 + arow) * 256 + ach * 8];
    #pragma unroll
    for (int i = 0; i < 4; i++) {
        int u = tid + i * 512, r = u >> 3, ch = u & 7;
        rb[i] = *(const s16x8*)&WqkvT[(size_t)r * 256 + ch * 8];
    }
    #pragma unroll 1
    for (int kt = 0; kt < 4; kt++) {
        if (kt) __syncthreads();
        if (tid < 128)
            *(s16x8*)&As[arow * 64 + (((ach * 16) ^ ((arow & 7) << 4)) >> 1)] = ra;
        #pragma unroll
        for (int i = 0; i < 4; i++) {
            int u = tid + i * 512, r = u >> 3, ch = u & 7;
            *(s16x8*)&Bs[r * 64 + (((ch * 16) ^ ((r & 7) << 4)) >> 1)] = rb[i];
        }
        __syncthreads();
        if (kt < 3) {
            int k0 = (kt + 1) * 64;
            if (tid < 128) ra = *(const s16x8*)&hb[(size_t)(rows0 + arow) * 256 + k0 + ach * 8];
            #pragma unroll
            for (int i = 0; i < 4; i++) {
                int u = tid + i * 512, r = u >> 3, ch = u & 7;
                rb[i] = *(const s16x8*)&WqkvT[(size_t)r * 256 + k0 + ch * 8];
            }
        }
        #pragma unroll
        for (int kk = 0; kk < 2; kk++) {
            int kbyte = kk * 64 + fkb;
            s16x8 af = *(const s16x8*)&As[fr * 64 + ((kbyte ^ ((fr & 7) << 4)) >> 1)];
            #pragma unroll
            for (int n = 0; n < 2; n++) {
                int brow = wn * 32 + n * 16 + fr;
                s16x8 bfv = *(const s16x8*)&Bs[brow * 64 + ((kbyte ^ ((brow & 7) << 4)) >> 1)];
                acc[n] = __builtin_amdgcn_mfma_f32_16x16x32_bf16(af, bfv, acc[n], 0, 0, 0);
            }
        }
    }
    #pragma unroll
    for (int n = 0; n < 2; n++) {
        int col = wn * 32 + n * 16 + fr;
        if (col < 192) {
            #pragma unroll
            for (int r = 0; r < 4; r++)
                kqv[(lane >> 4) * 4 + r][col] = acc[n][r];
        }
    }
    __syncthreads();
    #pragma unroll
    for (int i = 0; i < 2; i++) {
        int u = tid + i * 512, t = u >> 6, hd = u & 63;
        Vb[(size_t)(rows0 + t) * 64 + hd] = f2bf(kqv[t][128 + hd]);
    }
    {
        int h = tid >> 6, i2 = (tid >> 3) & 7, j = tid & 7;
        float s = 0.0f;
        #pragma unroll
        for (int t = 0; t < 16; t++)
            s += kqv[t][64 + h * 8 + i2] * kqv[t][h * 8 + j];
        int bb = rows0 >> 9, part = (rows0 >> 4) & 31;
        Rpart[(size_t)(bb * 32 + part) * 512 + tid] = s;
    }
}

// ================= fused layer: per-wave B staging -> zero barriers in K-loops =================
// Key fact: wave wn's MFMA B-fragments only touch Bs rows [wn*32, wn*32+32).
// Staging those rows from the SAME wave makes ds_write->ds_read same-wave
// (ordered by compiler lgkmcnt), eliminating all per-K-step __syncthreads.
__global__ __launch_bounds__(512, 4) void gpt_layer(
        const float* __restrict__ Rpart_in, const ushort* __restrict__ Vb_in,
        const ushort* __restrict__ WoT, const float* __restrict__ bo,
        const ushort* __restrict__ W1T, const float* __restrict__ b1,
        const ushort* __restrict__ W2T, const float* __restrict__ b2,
        const float* __restrict__ ls2, const float* __restrict__ lb2,
        const float* __restrict__ nls, const float* __restrict__ nlb,
        float* __restrict__ x,
        const ushort* __restrict__ WqkvT_next,
        ushort* __restrict__ Vb_out, float* __restrict__ Rpart_out,
        ushort* __restrict__ hbout, int mode) {
    __shared__ __align__(16) ushort Bs[256 * 64];     // 32 KB (per-wave 32-row stripes)
    __shared__ __align__(16) ushort ffs[16 * 1024];   // 32 KB (aliased as kqv in QKV phase)
    __shared__ __align__(16) ushort h2s[16 * 256];    // 8 KB
    __shared__ __align__(16) ushort abl[16 * 64];     // 2 KB
    __shared__ __align__(16) ushort Vl[16 * 64];      // 2 KB
    __shared__ float Rs[512];                          // 2 KB
    __shared__ float red1[16][8], red2[16][8], mrow[16], rrow[16];

    const int tid = threadIdx.x, lane = tid & 63, wn = tid >> 6;
    const int rows0 = blockIdx.x * 16, b = rows0 >> 9;
    const int fr = lane & 15, fkb = (lane >> 4) * 16, rbase = (lane >> 4) * 4;
    int colv[2]; colv[0] = wn * 32 + fr; colv[1] = wn * 32 + 16 + fr;
    // per-wave staging units: lane covers 4 of the 256 (row,chunk) units in its stripe
    int srow_[4], sch_[4];
    #pragma unroll
    for (int i = 0; i < 4; i++) {
        int u = lane + i * 64;
        srow_[i] = wn * 32 + (u >> 3);
        sch_[i] = u & 7;
    }

    // ---- softmax(R) from 32 partials ----
    {
        const float* rp = Rpart_in + (size_t)b * 32 * 512 + tid;
        float s = 0.0f;
        #pragma unroll
        for (int p = 0; p < 32; p++) s += rp[p * 512];
        s *= (1.0f / 16.0f);
        int ii = (tid >> 3) & 7, j = tid & 7;
        float val = (j >= ii) ? s : -INFINITY;
        float m = val;
        #pragma unroll
        for (int off = 1; off < 8; off <<= 1) m = fmaxf(m, __shfl_xor(m, off, 8));
        float ex = __expf(val - m);
        float su = ex;
        #pragma unroll
        for (int off = 1; off < 8; off <<= 1) su += __shfl_xor(su, off, 8);
        Rs[tid] = ex / su;
    }
    #pragma unroll
    for (int i = 0; i < 2; i++) {
        int u = tid + i * 512, t = u >> 6, hd = u & 63;
        Vl[t * 64 + hd] = Vb_in[(size_t)(rows0 + t) * 64 + hd];
    }
    __syncthreads();
    // ---- ab = V @ R -> abl (bf16, swizzled A) ----
    #pragma unroll
    for (int i = 0; i < 2; i++) {
        int u = tid + i * 512, t = u >> 6, hd = u & 63, h = hd >> 3, j = hd & 7;
        float a = 0.0f;
        #pragma unroll
        for (int q = 0; q < 8; q++)
            a += bf2f(Vl[t * 64 + h * 8 + q]) * Rs[h * 64 + q * 8 + j];
        abl[t * 64 + (((hd * 2) ^ ((t & 7) << 4)) >> 1)] = f2bf(a);
    }
    // ---- proj: 16x256 = abl(16x64) @ WoT(256x64); B per-wave staged ----
    s16x8 rbv[4];
    #pragma unroll
    for (int i = 0; i < 4; i++)
        rbv[i] = *(const s16x8*)&WoT[(size_t)srow_[i] * 64 + sch_[i] * 8];
    __syncthreads();   // abl ready for cross-wave reads
    #pragma unroll
    for (int i = 0; i < 4; i++)
        *(s16x8*)&Bs[srow_[i] * 64 + (((sch_[i] * 16) ^ ((srow_[i] & 7) << 4)) >> 1)] = rbv[i];
    f32x4 acc[2];
    acc[0] = (f32x4)0.0f; acc[1] = (f32x4)0.0f;
    #pragma unroll
    for (int kk = 0; kk < 2; kk++) {
        int kbyte = kk * 64 + fkb;
        s16x8 af = *(const s16x8*)&abl[fr * 64 + ((kbyte ^ ((fr & 7) << 4)) >> 1)];
        #pragma unroll
        for (int n = 0; n < 2; n++) {
            int brow = wn * 32 + n * 16 + fr;
            s16x8 bfv = *(const s16x8*)&Bs[brow * 64 + ((kbyte ^ ((brow & 7) << 4)) >> 1)];
            acc[n] = __builtin_amdgcn_mfma_f32_16x16x32_bf16(af, bfv, acc[n], 0, 0, 0);
        }
    }
    float xn[2][4];
    #pragma unroll
    for (int n = 0; n < 2; n++) {
        int col = colv[n];
        float bbv = bo[col];
        #pragma unroll
        for (int r = 0; r < 4; r++)
            xn[n][r] = acc[n][r] + bbv + x[(size_t)(rows0 + rbase + r) * 256 + col];
    }
    // ---- LN(ln2) -> h2s ----
    #pragma unroll
    for (int r = 0; r < 4; r++) {
        float s1 = xn[0][r] + xn[1][r];
        float s2 = xn[0][r] * xn[0][r] + xn[1][r] * xn[1][r];
        #pragma unroll
        for (int off = 1; off < 16; off <<= 1) {
            s1 += __shfl_xor(s1, off);
            s2 += __shfl_xor(s2, off);
        }
        if (fr == 0) { red1[rbase + r][wn] = s1; red2[rbase + r][wn] = s2; }
    }
    __syncthreads();
    if (tid < 16) {
        float s1 = 0.f, s2 = 0.f;
        #pragma unroll
        for (int w = 0; w < 8; w++) { s1 += red1[tid][w]; s2 += red2[tid][w]; }
        float mean = s1 * (1.0f / 256.0f);
        float var = s2 * (1.0f / 256.0f) - mean * mean;
        mrow[tid] = mean;
        rrow[tid] = rsqrtf(var + 1e-5f);
    }
    __syncthreads();
    #pragma unroll
    for (int n = 0; n < 2; n++) {
        int col = colv[n];
        float lsv = ls2[col], lbv = lb2[col];
        #pragma unroll
        for (int r = 0; r < 4; r++) {
            int rl = rbase + r;
            float hv = (xn[n][r] - mrow[rl]) * rrow[rl] * lsv + lbv;
            h2s[rl * 256 + (((col * 2) ^ ((rl & 7) << 4)) >> 1)] = f2bf(hv);
        }
    }
    __syncthreads();   // h2s ready for cross-wave reads
    // ---- MLP1: ff = relu(h2 @ W1T + b1), 4 col-chunks; zero barriers inside ----
    #pragma unroll 1
    for (int c = 0; c < 4; c++) {
        const ushort* Bg = W1T + (size_t)c * 256 * 256;
        acc[0] = (f32x4)0.0f; acc[1] = (f32x4)0.0f;
        #pragma unroll
        for (int i = 0; i < 4; i++)
            rbv[i] = *(const s16x8*)&Bg[(size_t)srow_[i] * 256 + sch_[i] * 8];
        #pragma unroll 1
        for (int kt = 0; kt < 4; kt++) {
            #pragma unroll
            for (int i = 0; i < 4; i++)
                *(s16x8*)&Bs[srow_[i] * 64 + (((sch_[i] * 16) ^ ((srow_[i] & 7) << 4)) >> 1)] = rbv[i];
            if (kt < 3) {
                int k0 = (kt + 1) * 64;
                #pragma unroll
                for (int i = 0; i < 4; i++)
                    rbv[i] = *(const s16x8*)&Bg[(size_t)srow_[i] * 256 + k0 + sch_[i] * 8];
            }
            #pragma unroll
            for (int kk = 0; kk < 2; kk++) {
                int kbyte = kt * 128 + kk * 64 + fkb;
                s16x8 af = *(const s16x8*)&h2s[fr * 256 + ((kbyte ^ ((fr & 7) << 4)) >> 1)];
                int kb2 = kk * 64 + fkb;
                #pragma unroll
                for (int n = 0; n < 2; n++) {
                    int brow = wn * 32 + n * 16 + fr;
                    s16x8 bfv = *(const s16x8*)&Bs[brow * 64 + ((kb2 ^ ((brow & 7) << 4)) >> 1)];
                    acc[n] = __builtin_amdgcn_mfma_f32_16x16x32_bf16(af, bfv, acc[n], 0, 0, 0);
                }
            }
        }
        #pragma unroll
        for (int n = 0; n < 2; n++) {
            int col = c * 256 + colv[n];
            float bb1 = b1[col];
            #pragma unroll
            for (int r = 0; r < 4; r++) {
                int rl = rbase + r;
                ffs[rl * 1024 + (((col * 2) ^ ((rl & 7) << 4)) >> 1)] =
                    f2bf(fmaxf(acc[n][r] + bb1, 0.0f));
            }
        }
    }
    __syncthreads();   // ffs complete before cross-wave MLP2 reads
    // ---- MLP2: x += ffs @ W2T + b2 (K=1024); zero barriers inside ----
    f32x4 a2[2];
    a2[0] = (f32x4)0.0f; a2[1] = (f32x4)0.0f;
    #pragma unroll
    for (int i = 0; i < 4; i++)
        rbv[i] = *(const s16x8*)&W2T[(size_t)srow_[i] * 1024 + sch_[i] * 8];
    #pragma unroll 2
    for (int kt = 0; kt < 16; kt++) {
        #pragma unroll
        for (int i = 0; i < 4; i++)
            *(s16x8*)&Bs[srow_[i] * 64 + (((sch_[i] * 16) ^ ((srow_[i] & 7) << 4)) >> 1)] = rbv[i];
        if (kt < 15) {
            int k0 = (kt + 1) * 64;
            #pragma unroll
            for (int i = 0; i < 4; i++)
                rbv[i] = *(const s16x8*)&W2T[(size_t)srow_[i] * 1024 + k0 + sch_[i] * 8];
        }
        #pragma unroll
        for (int kk = 0; kk < 2; kk++) {
            int kbyte = kt * 128 + kk * 64 + fkb;
            s16x8 af = *(const s16x8*)&ffs[fr * 1024 + ((kbyte ^ ((fr & 7) << 4)) >> 1)];
            int kb2 = kk * 64 + fkb;
            #pragma unroll
            for (int n = 0; n < 2; n++) {
                int brow = wn * 32 + n * 16 + fr;
                s16x8 bfv = *(const s16x8*)&Bs[brow * 64 + ((kb2 ^ ((brow & 7) << 4)) >> 1)];
                a2[n] = __builtin_amdgcn_mfma_f32_16x16x32_bf16(af, bfv, a2[n], 0, 0, 0);
            }
        }
    }
    #pragma unroll
    for (int n = 0; n < 2; n++) {
        int col = colv[n];
        float bb2 = b2[col];
        #pragma unroll
        for (int r = 0; r < 4; r++) {
            float v = xn[n][r] + a2[n][r] + bb2;
            xn[n][r] = v;
            x[(size_t)(rows0 + rbase + r) * 256 + col] = v;
        }
    }
    // ---- LN(next ln1 / lnf) -> h2s (and global hb if last layer) ----
    __syncthreads();
    #pragma unroll
    for (int r = 0; r < 4; r++) {
        float s1 = xn[0][r] + xn[1][r];
        float s2 = xn[0][r] * xn[0][r] + xn[1][r] * xn[1][r];
        #pragma unroll
        for (int off = 1; off < 16; off <<= 1) {
            s1 += __shfl_xor(s1, off);
            s2 += __shfl_xor(s2, off);
        }
        if (fr == 0) { red1[rbase + r][wn] = s1; red2[rbase + r][wn] = s2; }
    }
    __syncthreads();
    if (tid < 16) {
        float s1 = 0.f, s2 = 0.f;
        #pragma unroll
        for (int w = 0; w < 8; w++) { s1 += red1[tid][w]; s2 += red2[tid][w]; }
        float mean = s1 * (1.0f / 256.0f);
        float var = s2 * (1.0f / 256.0f) - mean * mean;
        mrow[tid] = mean;
        rrow[tid] = rsqrtf(var + 1e-5f);
    }
    __syncthreads();
    #pragma unroll
    for (int n = 0; n < 2; n++) {
        int col = colv[n];
        float lsv = nls[col], lbv = nlb[col];
        #pragma unroll
        for (int r = 0; r < 4; r++) {
            int rl = rbase + r;
            float hv = (xn[n][r] - mrow[rl]) * rrow[rl] * lsv + lbv;
            ushort hu = f2bf(hv);
            h2s[rl * 256 + (((col * 2) ^ ((rl & 7) << 4)) >> 1)] = hu;
            if (mode == 0)
                hbout[(size_t)(rows0 + rl) * 256 + col] = hu;
        }
    }
    if (mode == 0) return;
    __syncthreads();   // h2s ready for QKV cross-wave reads

    // ---- QKV for next layer: kqv = h2 @ WqkvT_next (K=256); zero barriers inside ----
    float* kqv = (float*)ffs;   // 16 x 193 floats, aliases ffs (dead: all waves past MLP2 via LN barriers)
    acc[0] = (f32x4)0.0f; acc[1] = (f32x4)0.0f;
    #pragma unroll
    for (int i = 0; i < 4; i++)
        rbv[i] = *(const s16x8*)&WqkvT_next[(size_t)srow_[i] * 256 + sch_[i] * 8];
    #pragma unroll 1
    for (int kt = 0; kt < 4; kt++) {
        #pragma unroll
        for (int i = 0; i < 4; i++)
            *(s16x8*)&Bs[srow_[i] * 64 + (((sch_[i] * 16) ^ ((srow_[i] & 7) << 4)) >> 1)] = rbv[i];
        if (kt < 3) {
            int k0 = (kt + 1) * 64;
            #pragma unroll
            for (int i = 0; i < 4; i++)
                rbv[i] = *(const s16x8*)&WqkvT_next[(size_t)srow_[i] * 256 + k0 + sch_[i] * 8];
        }
        #pragma unroll
        for (int kk = 0; kk < 2; kk++) {
            int kbyte = kt * 128 + kk * 64 + fkb;
            s16x8 af = *(const s16x8*)&h2s[fr * 256 + ((kbyte ^ ((fr & 7) << 4)) >> 1)];
            int kb2 = kk * 64 + fkb;
            #pragma unroll
            for (int n = 0; n < 2; n++) {
                int brow = wn * 32 + n * 16 + fr;
                s16x8 bfv = *(const s16x8*)&Bs[brow * 64 + ((kb2 ^ ((brow & 7) << 4)) >> 1)];
                acc[n] = __builtin_amdgcn_mfma_f32_16x16x32_bf16(af, bfv, acc[n], 0, 0, 0);
            }
        }
    }
    __syncthreads();   // safe point before kqv (ffs-alias) writes
    #pragma unroll
    for (int n = 0; n < 2; n++) {
        int col = wn * 32 + n * 16 + fr;
        if (col < 192) {
            #pragma unroll
            for (int r = 0; r < 4; r++)
                kqv[(rbase + r) * 193 + col] = acc[n][r];
        }
    }
    __syncthreads();
    #pragma unroll
    for (int i = 0; i < 2; i++) {
        int u = tid + i * 512, t = u >> 6, hd = u & 63;
        Vb_out[(size_t)(rows0 + t) * 64 + hd] = f2bf(kqv[t * 193 + 128 + hd]);
    }
    {
        int h = tid >> 6, i2 = (tid >> 3) & 7, j = tid & 7;
        float s = 0.0f;
        #pragma unroll
        for (int t = 0; t < 16; t++)
            s += kqv[t * 193 + 64 + h * 8 + i2] * kqv[t * 193 + h * 8 + j];
        int part = (rows0 >> 4) & 31;
        Rpart_out[(size_t)(b * 32 + part) * 512 + tid] = s;
    }
}

// ================= logits GEMM: 128x256 tile, 512 thr, global_load_lds staging =================
__global__ __launch_bounds__(512, 4) void gpt_logits_mfma(const ushort* __restrict__ hb, const ushort* __restrict__ WfT,
                                                          const float* __restrict__ bfb, float* __restrict__ out,
                                                          float2* __restrict__ lsebuf) {
    __shared__ __align__(16) ushort As[128 * 64];   // 16 KB
    __shared__ __align__(16) ushort Bs[256 * 64];   // 32 KB
    f32x4 acc[4][4];
    // XCD-bijective swizzle: 6304 blocks = 8 * 788
    int flat = blockIdx.y * 32 + blockIdx.x;
    int nf = (flat & 7) * 788 + (flat >> 3);
    int rb = nf & 31, cb = nf >> 5;
    int row0 = rb * 128, c0 = cb * 256;
    const int tid = threadIdx.x, lane = tid & 63, wid = tid >> 6;
    const int wm = wid >> 2, wn = wid & 3;           // 2 x 4 waves, 64x64 each
    const int fr = lane & 15, fkb = (lane >> 4) * 16;

    #pragma unroll
    for (int m = 0; m < 4; m++)
        #pragma unroll
        for (int n = 0; n < 4; n++) acc[m][n] = (f32x4)0.0f;

    const int srow = lane >> 3;            // 0..7 row within 8-row group
    const int sch = lane & 7;              // dest 16B chunk within row
    #pragma unroll 1
    for (int kt = 0; kt < 4; kt++) {
        if (kt) __syncthreads();
        {
            int kb = kt * 64;
            #pragma unroll
            for (int i = 0; i < 2; i++) {
                int rloc = wid * 16 + i * 8 + srow;
                int cs = sch ^ (rloc & 7);
                const ushort* gp = &hb[(size_t)(row0 + rloc) * 256 + kb + cs * 8];
                __builtin_amdgcn_global_load_lds((const AS1 void*)gp,
                                                 (AS3 void*)&As[(wid * 16 + i * 8) * 64], 16, 0, 0);
            }
            #pragma unroll
            for (int i = 0; i < 4; i++) {
                int rloc = wid * 32 + i * 8 + srow;
                int cs = sch ^ (rloc & 7);
                const ushort* gp = &WfT[(size_t)(c0 + rloc) * 256 + kb + cs * 8];
                __builtin_amdgcn_global_load_lds((const AS1 void*)gp,
                                                 (AS3 void*)&Bs[(wid * 32 + i * 8) * 64], 16, 0, 0);
            }
        }
        __syncthreads();
        #pragma unroll
        for (int kk = 0; kk < 2; kk++) {
            int kbyte = kk * 64 + fkb;
            s16x8 af[4], bfr[4];
            #pragma unroll
            for (int m = 0; m < 4; m++) {
                int arow = wm * 64 + m * 16 + fr;
                af[m] = *(const s16x8*)&As[arow * 64 + ((kbyte ^ ((arow & 7) << 4)) >> 1)];
            }
            #pragma unroll
            for (int n = 0; n < 4; n++) {
                int brow = wn * 64 + n * 16 + fr;
                bfr[n] = *(const s16x8*)&Bs[brow * 64 + ((kbyte ^ ((brow & 7) << 4)) >> 1)];
            }
            #pragma unroll
            for (int m = 0; m < 4; m++)
                #pragma unroll
                for (int n = 0; n < 4; n++)
                    acc[m][n] = __builtin_amdgcn_mfma_f32_16x16x32_bf16(af[m], bfr[n], acc[m][n], 0, 0, 0);
        }
    }
    float bb[4]; int gcv[4];
    #pragma unroll
    for (int n = 0; n < 4; n++) {
        int gc = c0 + wn * 64 + n * 16 + fr;
        gcv[n] = gc;
        bb[n] = (gc < V_SZ) ? bfb[gc] : 0.0f;
    }
    __syncthreads();
    float2 (*red)[4] = (float2(*)[4])As;
    #pragma unroll
    for (int m = 0; m < 4; m++) {
        int rloc = wm * 64 + m * 16 + (lane >> 4) * 4;
        int gr = row0 + rloc;
        #pragma unroll
        for (int r = 0; r < 4; r++) {
            float v[4];
            float vmax = -1e30f;
            #pragma unroll
            for (int n = 0; n < 4; n++) {
                v[n] = (gcv[n] < V_SZ) ? acc[m][n][r] + bb[n] : -1e30f;
                vmax = fmaxf(vmax, v[n]);
            }
            #pragma unroll
            for (int n = 0; n < 4; n++)
                if (gcv[n] < V_SZ)
                    out[(size_t)(gr + r) * V_SZ + gcv[n]] = v[n];
            #pragma unroll
            for (int off = 1; off < 16; off <<= 1)
                vmax = fmaxf(vmax, __shfl_xor(vmax, off));
            float vsum = __expf(v[0] - vmax) + __expf(v[1] - vmax)
                       + __expf(v[2] - vmax) + __expf(v[3] - vmax);
            #pragma unroll
            for (int off = 1; off < 16; off <<= 1)
                vsum += __shfl_xor(vsum, off);
            if ((lane & 15) == 0)
                red[rloc + r][wn] = make_float2(vmax, vsum);
        }
    }
    __syncthreads();
    if (tid < 128) {
        float M = -1e30f, S = 0.0f;
        #pragma unroll
        for (int w = 0; w < 4; w++) {
            float2 p = red[tid][w];
            float M2 = fmaxf(M, p.x);
            S = S * __expf(M - M2) + p.y * __expf(p.x - M2);
            M = M2;
        }
        lsebuf[(size_t)(row0 + tid) * NCB + cb] = make_float2(M, S);
    }
}

// ================= lse finish =================
__global__ __launch_bounds__(256) void gpt_lse(const float2* __restrict__ lsebuf, const float* __restrict__ out,
                                               const int* __restrict__ tgt, float* __restrict__ partial) {
    int wave = threadIdx.x >> 6, lane = threadIdx.x & 63;
    int row = blockIdx.x * 4 + wave;
    float m = -INFINITY, s = 0.0f;
    for (int i = lane; i < NCB; i += 64) {
        float2 p = lsebuf[(size_t)row * NCB + i];
        float M = fmaxf(m, p.x);
        s = s * __expf(m - M) + p.y * __expf(p.x - M);
        m = M;
    }
    #pragma unroll
    for (int off = 1; off < 64; off <<= 1) {
        float m2 = __shfl_xor(m, off);
        float s2 = __shfl_xor(s, off);
        float M = fmaxf(m, m2);
        s = s * __expf(m - M) + s2 * __expf(m2 - M);
        m = M;
    }
    if (lane == 0)
        partial[row] = m + logf(s) - out[(size_t)row * V_SZ + tgt[row]];
}

__global__ void gpt_loss_reduce(const float* __restrict__ partial, float* __restrict__ out) {
    __shared__ float red[256];
    int tid = threadIdx.x;
    float s = 0.0f;
    for (int i = tid; i < 4096; i += 256) s += partial[i];
    red[tid] = s;
    __syncthreads();
    for (int off = 128; off > 0; off >>= 1) {
        if (tid < off) red[tid] += red[tid + off];
        __syncthreads();
    }
    if (tid == 0) out[0] = red[0] * (1.0f / 4096.0f);
}

// ======================= fp32 fallback kernels (small-ws path) =======================
__global__ void gpt_embed(const int* __restrict__ tokens, const float* __restrict__ tok_emb,
                          const float* __restrict__ pos_emb, float* __restrict__ x) {
    int idx = blockIdx.x * 256 + threadIdx.x;
    int bt = idx >> 8, e = idx & 255;
    int t = bt & 511;
    int tok = tokens[bt];
    x[idx] = tok_emb[tok * 256 + e] + pos_emb[t * 256 + e];
}

__global__ void gpt_ln(const float* __restrict__ x, const float* __restrict__ s,
                       const float* __restrict__ b, float* __restrict__ h) {
    __shared__ float red[256];
    int row = blockIdx.x, e = threadIdx.x;
    float v = x[row * 256 + e];
    red[e] = v;
    __syncthreads();
    for (int off = 128; off > 0; off >>= 1) {
        if (e < off) red[e] += red[e + off];
        __syncthreads();
    }
    float mean = red[0] * (1.0f / 256.0f);
    __syncthreads();
    float d = v - mean;
    red[e] = d * d;
    __syncthreads();
    for (int off = 128; off > 0; off >>= 1) {
        if (e < off) red[e] += red[e + off];
        __syncthreads();
    }
    float rstd = rsqrtf(red[0] * (1.0f / 256.0f) + 1e-5f);
    h[row * 256 + e] = d * rstd * s[e] + b[e];
}

__global__ void gpt_qkv(const float* __restrict__ h, const float* __restrict__ Wq,
                        const float* __restrict__ Wk, const float* __restrict__ Wv,
                        float* __restrict__ Q, float* __restrict__ K, float* __restrict__ Vv) {
    __shared__ float hs[8][256];
    int tid = threadIdx.x;
    int row0 = blockIdx.x * 8;
    #pragma unroll
    for (int r = 0; r < 8; r++) hs[r][tid] = h[(row0 + r) * 256 + tid];
    __syncthreads();
    if (tid < 192) {
        int kind = tid >> 6, o = tid & 63, hh = o >> 3, d = o & 7;
        const float* W = kind == 0 ? Wq : (kind == 1 ? Wk : Wv);
        const float* wp = W + hh * 2048 + d;
        float acc[8];
        #pragma unroll
        for (int r = 0; r < 8; r++) acc[r] = 0.0f;
        for (int e = 0; e < 256; e++) {
            float w = wp[e * 8];
            #pragma unroll
            for (int r = 0; r < 8; r++) acc[r] += hs[r][e] * w;
        }
        float* outp = kind == 0 ? Q : (kind == 1 ? K : Vv);
        int b = row0 >> 9;
        #pragma unroll
        for (int r = 0; r < 8; r++) {
            int t = (row0 + r) & 511;
            outp[((b * 8 + hh) * 512 + t) * 8 + d] = acc[r];
        }
    }
}

__global__ void gpt_attn_r(const float* __restrict__ K, const float* __restrict__ Q,
                           float* __restrict__ R) {
    __shared__ __align__(16) float Ks[64][8];
    __shared__ __align__(16) float Qs[64][8];
    int bh = blockIdx.x, tid = threadIdx.x;
    int i = tid >> 3, j = tid & 7;
    const float* Kb = K + bh * 512 * 8;
    const float* Qb = Q + bh * 512 * 8;
    float acc = 0.0f;
    for (int t0 = 0; t0 < 512; t0 += 64) {
        *(float4*)&Ks[tid][0] = *(const float4*)&Kb[(t0 + tid) * 8];
        *(float4*)&Ks[tid][4] = *(const float4*)&Kb[(t0 + tid) * 8 + 4];
        *(float4*)&Qs[tid][0] = *(const float4*)&Qb[(t0 + tid) * 8];
        *(float4*)&Qs[tid][4] = *(const float4*)&Qb[(t0 + tid) * 8 + 4];
        __syncthreads();
        #pragma unroll 16
        for (int t = 0; t < 64; t++) acc += Ks[t][i] * Qs[t][j];
        __syncthreads();
    }
    acc *= (1.0f / 16.0f);
    float val = (j >= i) ? acc : -INFINITY;
    float m = val;
    #pragma unroll
    for (int off = 1; off < 8; off <<= 1) m = fmaxf(m, __shfl_xor(m, off, 8));
    float ex = expf(val - m);
    float sum = ex;
    #pragma unroll
    for (int off = 1; off < 8; off <<= 1) sum += __shfl_xor(sum, off, 8);
    R[bh * 64 + tid] = ex / sum;
}

__global__ void gpt_attn_out(const float* __restrict__ Vv, const float* __restrict__ R,
                             const float* __restrict__ Wo, const float* __restrict__ bo,
                             float* __restrict__ x) {
    __shared__ __align__(16) float as[8][64];
    int tid = threadIdx.x;
    int row0 = blockIdx.x * 8;
    int b = row0 >> 9;
    #pragma unroll
    for (int k = 0; k < 2; k++) {
        int idx = k * 256 + tid;
        int r = idx >> 6, hd = idx & 63;
        int hh = hd >> 3, jj = hd & 7;
        int t = (row0 + r) & 511;
        const float* vp = Vv + ((b * 8 + hh) * 512 + t) * 8;
        const float* rp = R + (b * 8 + hh) * 64 + jj;
        float a = 0.0f;
        #pragma unroll
        for (int i = 0; i < 8; i++) a += vp[i] * rp[i * 8];
        as[r][hd] = a;
    }
    __syncthreads();
    float acc[8];
    float bb = bo[tid];
    #pragma unroll
    for (int r = 0; r < 8; r++) acc[r] = bb;
    for (int hd0 = 0; hd0 < 64; hd0 += 4) {
        float w0 = Wo[(hd0 + 0) * 256 + tid];
        float w1 = Wo[(hd0 + 1) * 256 + tid];
        float w2 = Wo[(hd0 + 2) * 256 + tid];
        float w3 = Wo[(hd0 + 3) * 256 + tid];
        #pragma unroll
        for (int r = 0; r < 8; r++) {
            float4 av = *(const float4*)&as[r][hd0];
            acc[r] += av.x * w0 + av.y * w1 + av.z * w2 + av.w * w3;
        }
    }
    #pragma unroll
    for (int r = 0; r < 8; r++) x[(row0 + r) * 256 + tid] += acc[r];
}

__global__ __launch_bounds__(256) void gpt_mlp(const float* __restrict__ h, const float* __restrict__ W1,
                         const float* __restrict__ b1, const float* __restrict__ W2,
                         const float* __restrict__ b2, float* __restrict__ x) {
    __shared__ __align__(16) float hs[8][256];
    __shared__ __align__(16) float ffs[8][1024];
    int tid = threadIdx.x;
    int row0 = blockIdx.x * 8;
    #pragma unroll
    for (int r = 0; r < 8; r++) hs[r][tid] = h[(row0 + r) * 256 + tid];
    __syncthreads();
    {
        float acc[4][8];
        #pragma unroll
        for (int k = 0; k < 4; k++) {
            float bb = b1[k * 256 + tid];
            #pragma unroll
            for (int r = 0; r < 8; r++) acc[k][r] = bb;
        }
        for (int e0 = 0; e0 < 256; e0 += 4) {
            float w[4][4];
            #pragma unroll
            for (int ee = 0; ee < 4; ee++)
                #pragma unroll
                for (int k = 0; k < 4; k++)
                    w[ee][k] = W1[(e0 + ee) * 1024 + k * 256 + tid];
            #pragma unroll
            for (int r = 0; r < 8; r++) {
                float4 hv = *(const float4*)&hs[r][e0];
                #pragma unroll
                for (int k = 0; k < 4; k++)
                    acc[k][r] += hv.x * w[0][k] + hv.y * w[1][k] + hv.z * w[2][k] + hv.w * w[3][k];
            }
        }
        #pragma unroll
        for (int k = 0; k < 4; k++)
            #pragma unroll
            for (int r = 0; r < 8; r++)
                ffs[r][k * 256 + tid] = fmaxf(acc[k][r], 0.0f);
    }
    __syncthreads();
    {
        float acc[8];
        float bb = b2[tid];
        #pragma unroll
        for (int r = 0; r < 8; r++) acc[r] = bb;
        for (int f0 = 0; f0 < 1024; f0 += 4) {
            float w0 = W2[(f0 + 0) * 256 + tid];
            float w1 = W2[(f0 + 1) * 256 + tid];
            float w2 = W2[(f0 + 2) * 256 + tid];
            float w3 = W2[(f0 + 3) * 256 + tid];
            #pragma unroll
            for (int r = 0; r < 8; r++) {
                float4 fv = *(const float4*)&ffs[r][f0];
                acc[r] += fv.x * w0 + fv.y * w1 + fv.z * w2 + fv.w * w3;
            }
        }
        #pragma unroll
        for (int r = 0; r < 8; r++) x[(row0 + r) * 256 + tid] += acc[r];
    }
}

__global__ __launch_bounds__(256) void gpt_logits(const float* __restrict__ hf, const float* __restrict__ Wf,
                            const float* __restrict__ bf, float* __restrict__ out) {
    __shared__ __align__(16) float hs[32][256];
    int tid = threadIdx.x;
    int row0 = blockIdx.y * 32;
    #pragma unroll
    for (int r = 0; r < 32; r++) hs[r][tid] = hf[(row0 + r) * 256 + tid];
    __syncthreads();
    int c0 = blockIdx.x * 512 + tid;
    int c1 = c0 + 256;
    int c0c = c0 < V_SZ ? c0 : V_SZ - 1;
    int c1c = c1 < V_SZ ? c1 : V_SZ - 1;
    float acc0[32], acc1[32];
    float b0 = bf[c0c], b1 = bf[c1c];
    #pragma unroll
    for (int r = 0; r < 32; r++) { acc0[r] = b0; acc1[r] = b1; }
    const float* p0 = Wf + c0c;
    const float* p1 = Wf + c1c;
    for (int e0 = 0; e0 < 256; e0 += 4) {
        float w00 = p0[(size_t)(e0 + 0) * V_SZ];
        float w01 = p0[(size_t)(e0 + 1) * V_SZ];
        float w02 = p0[(size_t)(e0 + 2) * V_SZ];
        float w03 = p0[(size_t)(e0 + 3) * V_SZ];
        float w10 = p1[(size_t)(e0 + 0) * V_SZ];
        float w11 = p1[(size_t)(e0 + 1) * V_SZ];
        float w12 = p1[(size_t)(e0 + 2) * V_SZ];
        float w13 = p1[(size_t)(e0 + 3) * V_SZ];
        #pragma unroll
        for (int r = 0; r < 32; r++) {
            float4 hv = *(const float4*)&hs[r][e0];
            acc0[r] += hv.x * w00 + hv.y * w01 + hv.z * w02 + hv.w * w03;
            acc1[r] += hv.x * w10 + hv.y * w11 + hv.z * w12 + hv.w * w13;
        }
    }
    if (c0 < V_SZ) {
        #pragma unroll
        for (int r = 0; r < 32; r++) out[(size_t)(row0 + r) * V_SZ + c0] = acc0[r];
    }
    if (c1 < V_SZ) {
        #pragma unroll
        for (int r = 0; r < 32; r++) out[(size_t)(row0 + r) * V_SZ + c1] = acc1[r];
    }
}

__global__ void gpt_loss(const float* __restrict__ logits, const int* __restrict__ tgt,
                         float* __restrict__ partial) {
    __shared__ float ms[256], ss[256];
    int row = blockIdx.x, tid = threadIdx.x;
    const float* lr = logits + (size_t)row * V_SZ;
    float m = -INFINITY, s = 0.0f;
    for (int c = tid; c < V_SZ; c += 256) {
        float v = lr[c];
        float nm = fmaxf(m, v);
        s = s * expf(m - nm) + expf(v - nm);
        m = nm;
    }
    ms[tid] = m; ss[tid] = s;
    __syncthreads();
    for (int off = 128; off > 0; off >>= 1) {
        if (tid < off) {
            float m2 = ms[tid + off], s2 = ss[tid + off];
            float M = fmaxf(ms[tid], m2);
            ss[tid] = ss[tid] * expf(ms[tid] - M) + s2 * expf(m2 - M);
            ms[tid] = M;
        }
        __syncthreads();
    }
    if (tid == 0) {
        float lse = ms[0] + logf(ss[0]);
        partial[row] = lse - lr[tgt[row]];
    }
}

// ======================= launch =======================
extern "C" void kernel_launch(void* const* d_in, const int* in_sizes, int n_in,
                              void* d_out, int out_size, void* d_ws, size_t ws_size,
                              hipStream_t stream) {
    const int*   tokens  = (const int*)d_in[0];
    const int*   ideal   = (const int*)d_in[1];
    const float* tok_emb = (const float*)d_in[2];
    const float* pos_emb = (const float*)d_in[3];
    const float* Wq      = (const float*)d_in[4];
    const float* Wk      = (const float*)d_in[5];
    const float* Wv      = (const float*)d_in[6];
    const float* Wo      = (const float*)d_in[7];
    const float* bo      = (const float*)d_in[8];
    const float* ln1_s   = (const float*)d_in[9];
    const float* ln1_b   = (const float*)d_in[10];
    const float* W1      = (const float*)d_in[11];
    const float* b1      = (const float*)d_in[12];
    const float* W2      = (const float*)d_in[13];
    const float* b2      = (const float*)d_in[14];
    const float* ln2_s   = (const float*)d_in[15];
    const float* ln2_b   = (const float*)d_in[16];
    const float* lnf_s   = (const float*)d_in[17];
    const float* lnf_b   = (const float*)d_in[18];
    const float* Wf      = (const float*)d_in[19];
    const float* bf      = (const float*)d_in[20];
    float* out = (float*)d_out;

    // ---- workspace layout (bf16 path) ----
    size_t off = 0;
    char* wsc = (char*)d_ws;
    ushort* WfT   = (ushort*)(wsc + off); off += (size_t)NPAD * 256 * 2;
    ushort* W1T   = (ushort*)(wsc + off); off += (size_t)16 * 1024 * 256 * 2;
    ushort* W2T   = (ushort*)(wsc + off); off += (size_t)16 * 256 * 1024 * 2;
    ushort* WqkvT = (ushort*)(wsc + off); off += (size_t)16 * 256 * 256 * 2;
    ushort* WoT   = (ushort*)(wsc + off); off += (size_t)16 * 256 * 64 * 2;
    ushort* hb    = (ushort*)(wsc + off); off += (size_t)4096 * 256 * 2;
    ushort* Vb0   = (ushort*)(wsc + off); off += (size_t)4096 * 64 * 2;
    ushort* Vb1   = (ushort*)(wsc + off); off += (size_t)4096 * 64 * 2;
    float*  x     = (float*)(wsc + off);  off += (size_t)4096 * 256 * 4;
    float*  Rp0   = (float*)(wsc + off);  off += (size_t)8 * 32 * 512 * 4;
    float*  Rp1   = (float*)(wsc + off);  off += (size_t)8 * 32 * 512 * 4;
    float*  partial = (float*)(wsc + off); off += (size_t)4096 * 4;
    float2* lsebuf = (float2*)(wsc + off); off += (size_t)4096 * NCB * 8;
    bool big = ws_size >= off;

    if (big) {
        cvt_transpose<<<dim3(16, 4, 16), 256, 0, stream>>>(W1, W1T, 256, 1024, 1024, 262144, 262144);
        cvt_transpose<<<dim3(4, 16, 16), 256, 0, stream>>>(W2, W2T, 1024, 256, 256, 262144, 262144);
        cvt_transpose<<<dim3(4, 1, 16), 256, 0, stream>>>(Wo, WoT, 64, 256, 256, 16384, 16384);
        cvt_transpose<<<dim3(788, 4, 1), 256, 0, stream>>>(Wf, WfT, 256, V_SZ, V_SZ, 0, 0);
        cvt_qkv<<<dim3(16, 3), 256, 0, stream>>>(Wq, Wk, Wv, WqkvT);

        gpt_embed_ln<<<1024, 256, 0, stream>>>(tokens, tok_emb, pos_emb, ln1_s, ln1_b, x, hb);
        gpt_pre<<<256, 512, 0, stream>>>(hb, WqkvT, Vb0, Rp0);

        for (int l = 0; l < 16; l++) {
            const float* nls = (l < 15) ? ln1_s + (l + 1) * 256 : lnf_s;
            const float* nlb = (l < 15) ? ln1_b + (l + 1) * 256 : lnf_b;
            const float* Rin = (l & 1) ? Rp1 : Rp0;
            const ushort* Vin = (l & 1) ? Vb1 : Vb0;
            float* Rout = (l & 1) ? Rp0 : Rp1;
            ushort* Vout = (l & 1) ? Vb0 : Vb1;
            int mode = (l < 15) ? 1 : 0;
            const ushort* Wnext = WqkvT + (size_t)((l < 15) ? (l + 1) : 0) * 65536;
            gpt_layer<<<256, 512, 0, stream>>>(Rin, Vin,
                                               WoT + (size_t)l * 16384, bo + l * 256,
                                               W1T + (size_t)l * 262144, b1 + l * 1024,
                                               W2T + (size_t)l * 262144, b2 + l * 256,
                                               ln2_s + l * 256, ln2_b + l * 256,
                                               nls, nlb, x,
                                               Wnext, Vout, Rout, hb, mode);
        }

        gpt_logits_mfma<<<dim3(32, NCB), 512, 0, stream>>>(hb, WfT, bf, out, lsebuf);
        gpt_lse<<<1024, 256, 0, stream>>>(lsebuf, out, ideal, partial);
        gpt_loss_reduce<<<1, 256, 0, stream>>>(partial, out + (size_t)4096 * V_SZ);
    } else {
        // fp32 fallback
        float* fx  = (float*)d_ws;
        float* fh  = fx + 4096 * 256;
        float* fQ  = fh + 4096 * 256;
        float* fK  = fQ + 4096 * 64;
        float* fV  = fK + 4096 * 64;
        float* fR  = fV + 4096 * 64;
        float* fpart = fR + 64 * 64;
        gpt_embed<<<4096, 256, 0, stream>>>(tokens, tok_emb, pos_emb, fx);
        for (int l = 0; l < 16; l++) {
            gpt_ln<<<4096, 256, 0, stream>>>(fx, ln1_s + l * 256, ln1_b + l * 256, fh);
            gpt_qkv<<<512, 256, 0, stream>>>(fh, Wq + l * 16384, Wk + l * 16384, Wv + l * 16384, fQ, fK, fV);
            gpt_attn_r<<<64, 64, 0, stream>>>(fK, fQ, fR);
            gpt_attn_out<<<512, 256, 0, stream>>>(fV, fR, Wo + l * 16384, bo + l * 256, fx);
            gpt_ln<<<4096, 256, 0, stream>>>(fx, ln2_s + l * 256, ln2_b + l * 256, fh);
            gpt_mlp<<<512, 256, 0, stream>>>(fh, W1 + l * 262144, b1 + l * 1024, W2 + l * 262144, b2 + l * 256, fx);
        }
        gpt_ln<<<4096, 256, 0, stream>>>(fx, lnf_s, lnf_b, fh);
        dim3 lg(99, 128);
        gpt_logits<<<lg, 256, 0, stream>>>(fh, Wf, bf, out);
        gpt_loss<<<4096, 256, 0, stream>>>(out, ideal, fpart);
        gpt_loss_reduce<<<1, 256, 0, stream>>>(fpart, out + (size_t)4096 * V_SZ);
    }
}

// Round 14
// 906.953 us; speedup vs baseline: 2.3244x; 1.0113x over previous
//
#include <hip/hip_runtime.h>
#include <math.h>

#define V_SZ 50257
#define NPAD 50432   // 197 * 256
#define NCB 197

#define AS1 __attribute__((address_space(1)))
#define AS3 __attribute__((address_space(3)))

typedef short s16x8 __attribute__((ext_vector_type(8)));
typedef ushort u16x4 __attribute__((ext_vector_type(4)));
typedef float f32x4 __attribute__((ext_vector_type(4)));

__device__ __forceinline__ ushort f2bf(float x) {
    union { float f; unsigned u; } v; v.f = x;
    unsigned r = v.u + 0x7FFF + ((v.u >> 16) & 1);   // RNE
    return (ushort)(r >> 16);
}
__device__ __forceinline__ float bf2f(ushort u) {
    union { unsigned u; float f; } v; v.u = ((unsigned)u) << 16; return v.f;
}

// ================= embed + ln1(layer0): wave per row =================
__global__ __launch_bounds__(256) void gpt_embed_ln(const int* __restrict__ tokens,
                                                    const float* __restrict__ tok_emb,
                                                    const float* __restrict__ pos_emb,
                                                    const float* __restrict__ s, const float* __restrict__ b,
                                                    float* __restrict__ x, ushort* __restrict__ hb) {
    int wave = threadIdx.x >> 6, lane = threadIdx.x & 63;
    int row = blockIdx.x * 4 + wave;
    int t = row & 511;
    int tok = tokens[row];
    float4 te = ((const float4*)(tok_emb + tok * 256))[lane];
    float4 pe = ((const float4*)(pos_emb + t * 256))[lane];
    float4 v = make_float4(te.x + pe.x, te.y + pe.y, te.z + pe.z, te.w + pe.w);
    ((float4*)(x + row * 256))[lane] = v;
    float sum = v.x + v.y + v.z + v.w;
    #pragma unroll
    for (int off = 1; off < 64; off <<= 1) sum += __shfl_xor(sum, off);
    float mean = sum * (1.0f / 256.0f);
    float dx = v.x - mean, dy = v.y - mean, dz = v.z - mean, dw = v.w - mean;
    float vs = dx * dx + dy * dy + dz * dz + dw * dw;
    #pragma unroll
    for (int off = 1; off < 64; off <<= 1) vs += __shfl_xor(vs, off);
    float rstd = rsqrtf(vs * (1.0f / 256.0f) + 1e-5f);
    float4 sv = ((const float4*)s)[lane];
    float4 bv = ((const float4*)b)[lane];
    u16x4 o;
    o[0] = f2bf(dx * rstd * sv.x + bv.x);
    o[1] = f2bf(dy * rstd * sv.y + bv.y);
    o[2] = f2bf(dz * rstd * sv.z + bv.z);
    o[3] = f2bf(dw * rstd * sv.w + bv.w);
    *(u16x4*)&hb[row * 256 + lane * 4] = o;
}

// ================= generic transpose+convert: in fp32 [Kd][Nd] -> out bf16 [n][k] =================
__global__ __launch_bounds__(256) void cvt_transpose(const float* __restrict__ in, ushort* __restrict__ out,
                                                     int Kd, int Nd, int n_real,
                                                     int in_stride, int out_stride) {
    __shared__ __align__(16) ushort t[64][80];
    const float* inp = in + (size_t)blockIdx.z * in_stride;
    ushort* outp = out + (size_t)blockIdx.z * out_stride;
    int n0 = blockIdx.x * 64, k0 = blockIdx.y * 64;
    int tid = threadIdx.x;
    #pragma unroll
    for (int p = 0; p < 4; p++) {
        int lk = p * 16 + (tid >> 4);
        int ln = (tid & 15) * 4;
        int k = k0 + lk, n = n0 + ln;
        const float* rowp = inp + (size_t)k * Nd;
        float v0 = 0.f, v1 = 0.f, v2 = 0.f, v3 = 0.f;
        if (n + 0 < n_real) v0 = rowp[n + 0];
        if (n + 1 < n_real) v1 = rowp[n + 1];
        if (n + 2 < n_real) v2 = rowp[n + 2];
        if (n + 3 < n_real) v3 = rowp[n + 3];
        t[ln + 0][lk] = f2bf(v0);
        t[ln + 1][lk] = f2bf(v1);
        t[ln + 2][lk] = f2bf(v2);
        t[ln + 3][lk] = f2bf(v3);
    }
    __syncthreads();
    int ln = tid >> 2, kq = (tid & 3) * 16;
    ushort* op = outp + (size_t)(n0 + ln) * Kd + k0 + kq;
    *(s16x8*)&op[0] = *(const s16x8*)&t[ln][kq];
    *(s16x8*)&op[8] = *(const s16x8*)&t[ln][kq + 8];
}

// ================= Wq/Wk/Wv [L][H][E][D] -> WqkvT [L][256][256] (rows 192..255 zero) =================
__global__ __launch_bounds__(256) void cvt_qkv(const float* __restrict__ Wq, const float* __restrict__ Wk,
                                               const float* __restrict__ Wv, ushort* __restrict__ WqkvT) {
    int l = blockIdx.x, kind = blockIdx.y;
    const float* W = (kind == 0 ? Wq : (kind == 1 ? Wk : Wv)) + l * 16384;
    ushort* out = WqkvT + (size_t)l * 65536 + kind * 64 * 256;
    int tid = threadIdx.x;
    #pragma unroll 4
    for (int it = 0; it < 64; it++) {
        int idx = it * 256 + tid;
        int row = idx >> 8, e = idx & 255;
        int h = row >> 3, d = row & 7;
        out[row * 256 + e] = f2bf(W[h * 2048 + e * 8 + d]);
    }
    if (kind == 0) {
        ushort* zp = WqkvT + (size_t)l * 65536 + 192 * 256;
        #pragma unroll 4
        for (int it = 0; it < 64; it++) zp[it * 256 + tid] = 0;
    }
}

// ================= pre: QKV (16 rows/block) + V out + R partials (layer 0 only) =================
__global__ __launch_bounds__(512, 4) void gpt_pre(const ushort* __restrict__ hb,
                                                  const ushort* __restrict__ WqkvT,
                                                  ushort* __restrict__ Vb,
                                                  float* __restrict__ Rpart) {
    __shared__ __align__(16) ushort As[16 * 64];
    __shared__ __align__(16) ushort Bs[256 * 64];
    __shared__ float kqv[16][193];
    const int tid = threadIdx.x, lane = tid & 63, wn = tid >> 6;
    const int rows0 = blockIdx.x * 16;
    const int fr = lane & 15, fkb = (lane >> 4) * 16;
    const int arow = tid >> 3, ach = tid & 7;

    f32x4 acc[2];
    acc[0] = (f32x4)0.0f; acc[1] = (f32x4)0.0f;

    s16x8 ra, rb[4];
    if (tid < 128) ra = *(const s16x8*)&hb[(size_t)(rows0 + arow) * 256 + ach * 8];
    #pragma unroll
    for (int i = 0; i < 4; i++) {
        int u = tid + i * 512, r = u >> 3, ch = u & 7;
        rb[i] = *(const s16x8*)&WqkvT[(size_t)r * 256 + ch * 8];
    }
    #pragma unroll 1
    for (int kt = 0; kt < 4; kt++) {
        if (kt) __syncthreads();
        if (tid < 128)
            *(s16x8*)&As[arow * 64 + (((ach * 16) ^ ((arow & 7) << 4)) >> 1)] = ra;
        #pragma unroll
        for (int i = 0; i < 4; i++) {
            int u = tid + i * 512, r = u >> 3, ch = u & 7;
            *(s16x8*)&Bs[r * 64 + (((ch * 16) ^ ((r & 7) << 4)) >> 1)] = rb[i];
        }
        __syncthreads();
        if (kt < 3) {
            int k0 = (kt + 1) * 64;
            if (tid < 128) ra = *(const s16x8*)&hb[(size_t)(rows0 + arow) * 256 + k0 + ach * 8];
            #pragma unroll
            for (int i = 0; i < 4; i++) {
                int u = tid + i * 512, r = u >> 3, ch = u & 7;
                rb[i] = *(const s16x8*)&WqkvT[(size_t)r * 256 + k0 + ch * 8];
            }
        }
        #pragma unroll
        for (int kk = 0; kk < 2; kk++) {
            int kbyte = kk * 64 + fkb;
            s16x8 af = *(const s16x8*)&As[fr * 64 + ((kbyte ^ ((fr & 7) << 4)) >> 1)];
            #pragma unroll
            for (int n = 0; n < 2; n++) {
                int brow = wn * 32 + n * 16 + fr;
                s16x8 bfv = *(const s16x8*)&Bs[brow * 64 + ((kbyte ^ ((brow & 7) << 4)) >> 1)];
                acc[n] = __builtin_amdgcn_mfma_f32_16x16x32_bf16(af, bfv, acc[n], 0, 0, 0);
            }
        }
    }
    #pragma unroll
    for (int n = 0; n < 2; n++) {
        int col = wn * 32 + n * 16 + fr;
        if (col < 192) {
            #pragma unroll
            for (int r = 0; r < 4; r++)
                kqv[(lane >> 4) * 4 + r][col] = acc[n][r];
        }
    }
    __syncthreads();
    #pragma unroll
    for (int i = 0; i < 2; i++) {
        int u = tid + i * 512, t = u >> 6, hd = u & 63;
        Vb[(size_t)(rows0 + t) * 64 + hd] = f2bf(kqv[t][128 + hd]);
    }
    {
        int h = tid >> 6, i2 = (tid >> 3) & 7, j = tid & 7;
        float s = 0.0f;
        #pragma unroll
        for (int t = 0; t < 16; t++)
            s += kqv[t][64 + h * 8 + i2] * kqv[t][h * 8 + j];
        int bb = rows0 >> 9, part = (rows0 >> 4) & 31;
        Rpart[(size_t)(bb * 32 + part) * 512 + tid] = s;
    }
}

// ================= fused layer: per-wave B staging, x prefetch, setprio on MFMA =================
__global__ __launch_bounds__(512, 4) void gpt_layer(
        const float* __restrict__ Rpart_in, const ushort* __restrict__ Vb_in,
        const ushort* __restrict__ WoT, const float* __restrict__ bo,
        const ushort* __restrict__ W1T, const float* __restrict__ b1,
        const ushort* __restrict__ W2T, const float* __restrict__ b2,
        const float* __restrict__ ls2, const float* __restrict__ lb2,
        const float* __restrict__ nls, const float* __restrict__ nlb,
        float* __restrict__ x,
        const ushort* __restrict__ WqkvT_next,
        ushort* __restrict__ Vb_out, float* __restrict__ Rpart_out,
        ushort* __restrict__ hbout, int mode) {
    __shared__ __align__(16) ushort Bs[256 * 64];     // 32 KB (per-wave 32-row stripes)
    __shared__ __align__(16) ushort ffs[16 * 1024];   // 32 KB (aliased as kqv in QKV phase)
    __shared__ __align__(16) ushort h2s[16 * 256];    // 8 KB
    __shared__ __align__(16) ushort abl[16 * 64];     // 2 KB
    __shared__ __align__(16) ushort Vl[16 * 64];      // 2 KB
    __shared__ float Rs[512];                          // 2 KB
    __shared__ float red1[16][8], red2[16][8], mrow[16], rrow[16];

    const int tid = threadIdx.x, lane = tid & 63, wn = tid >> 6;
    const int rows0 = blockIdx.x * 16, b = rows0 >> 9;
    const int fr = lane & 15, fkb = (lane >> 4) * 16, rbase = (lane >> 4) * 4;
    int colv[2]; colv[0] = wn * 32 + fr; colv[1] = wn * 32 + 16 + fr;
    // per-wave staging units: lane covers 4 of the 256 (row,chunk) units in its stripe
    int srow_[4], sch_[4];
    #pragma unroll
    for (int i = 0; i < 4; i++) {
        int u = lane + i * 64;
        srow_[i] = wn * 32 + (u >> 3);
        sch_[i] = u & 7;
    }

    // ---- prefetch residual x (consumed at proj epilogue) ----
    float xr[2][4];
    #pragma unroll
    for (int n = 0; n < 2; n++)
        #pragma unroll
        for (int r = 0; r < 4; r++)
            xr[n][r] = x[(size_t)(rows0 + rbase + r) * 256 + colv[n]];

    // ---- softmax(R) from 32 partials ----
    {
        const float* rp = Rpart_in + (size_t)b * 32 * 512 + tid;
        float s = 0.0f;
        #pragma unroll
        for (int p = 0; p < 32; p++) s += rp[p * 512];
        s *= (1.0f / 16.0f);
        int ii = (tid >> 3) & 7, j = tid & 7;
        float val = (j >= ii) ? s : -INFINITY;
        float m = val;
        #pragma unroll
        for (int off = 1; off < 8; off <<= 1) m = fmaxf(m, __shfl_xor(m, off, 8));
        float ex = __expf(val - m);
        float su = ex;
        #pragma unroll
        for (int off = 1; off < 8; off <<= 1) su += __shfl_xor(su, off, 8);
        Rs[tid] = ex / su;
    }
    #pragma unroll
    for (int i = 0; i < 2; i++) {
        int u = tid + i * 512, t = u >> 6, hd = u & 63;
        Vl[t * 64 + hd] = Vb_in[(size_t)(rows0 + t) * 64 + hd];
    }
    __syncthreads();
    // ---- ab = V @ R -> abl (bf16, swizzled A) ----
    #pragma unroll
    for (int i = 0; i < 2; i++) {
        int u = tid + i * 512, t = u >> 6, hd = u & 63, h = hd >> 3, j = hd & 7;
        float a = 0.0f;
        #pragma unroll
        for (int q = 0; q < 8; q++)
            a += bf2f(Vl[t * 64 + h * 8 + q]) * Rs[h * 64 + q * 8 + j];
        abl[t * 64 + (((hd * 2) ^ ((t & 7) << 4)) >> 1)] = f2bf(a);
    }
    // ---- proj: 16x256 = abl(16x64) @ WoT(256x64); B per-wave staged ----
    s16x8 rbv[4];
    #pragma unroll
    for (int i = 0; i < 4; i++)
        rbv[i] = *(const s16x8*)&WoT[(size_t)srow_[i] * 64 + sch_[i] * 8];
    __syncthreads();   // abl ready for cross-wave reads
    #pragma unroll
    for (int i = 0; i < 4; i++)
        *(s16x8*)&Bs[srow_[i] * 64 + (((sch_[i] * 16) ^ ((srow_[i] & 7) << 4)) >> 1)] = rbv[i];
    f32x4 acc[2];
    acc[0] = (f32x4)0.0f; acc[1] = (f32x4)0.0f;
    __builtin_amdgcn_s_setprio(1);
    #pragma unroll
    for (int kk = 0; kk < 2; kk++) {
        int kbyte = kk * 64 + fkb;
        s16x8 af = *(const s16x8*)&abl[fr * 64 + ((kbyte ^ ((fr & 7) << 4)) >> 1)];
        #pragma unroll
        for (int n = 0; n < 2; n++) {
            int brow = wn * 32 + n * 16 + fr;
            s16x8 bfv = *(const s16x8*)&Bs[brow * 64 + ((kbyte ^ ((brow & 7) << 4)) >> 1)];
            acc[n] = __builtin_amdgcn_mfma_f32_16x16x32_bf16(af, bfv, acc[n], 0, 0, 0);
        }
    }
    __builtin_amdgcn_s_setprio(0);
    float xn[2][4];
    #pragma unroll
    for (int n = 0; n < 2; n++) {
        int col = colv[n];
        float bbv = bo[col];
        #pragma unroll
        for (int r = 0; r < 4; r++)
            xn[n][r] = acc[n][r] + bbv + xr[n][r];
    }
    // ---- LN(ln2) -> h2s ----
    #pragma unroll
    for (int r = 0; r < 4; r++) {
        float s1 = xn[0][r] + xn[1][r];
        float s2 = xn[0][r] * xn[0][r] + xn[1][r] * xn[1][r];
        #pragma unroll
        for (int off = 1; off < 16; off <<= 1) {
            s1 += __shfl_xor(s1, off);
            s2 += __shfl_xor(s2, off);
        }
        if (fr == 0) { red1[rbase + r][wn] = s1; red2[rbase + r][wn] = s2; }
    }
    __syncthreads();
    if (tid < 16) {
        float s1 = 0.f, s2 = 0.f;
        #pragma unroll
        for (int w = 0; w < 8; w++) { s1 += red1[tid][w]; s2 += red2[tid][w]; }
        float mean = s1 * (1.0f / 256.0f);
        float var = s2 * (1.0f / 256.0f) - mean * mean;
        mrow[tid] = mean;
        rrow[tid] = rsqrtf(var + 1e-5f);
    }
    __syncthreads();
    #pragma unroll
    for (int n = 0; n < 2; n++) {
        int col = colv[n];
        float lsv = ls2[col], lbv = lb2[col];
        #pragma unroll
        for (int r = 0; r < 4; r++) {
            int rl = rbase + r;
            float hv = (xn[n][r] - mrow[rl]) * rrow[rl] * lsv + lbv;
            h2s[rl * 256 + (((col * 2) ^ ((rl & 7) << 4)) >> 1)] = f2bf(hv);
        }
    }
    __syncthreads();   // h2s ready for cross-wave reads
    // ---- MLP1: ff = relu(h2 @ W1T + b1), 4 col-chunks; zero barriers inside ----
    #pragma unroll 1
    for (int c = 0; c < 4; c++) {
        const ushort* Bg = W1T + (size_t)c * 256 * 256;
        acc[0] = (f32x4)0.0f; acc[1] = (f32x4)0.0f;
        #pragma unroll
        for (int i = 0; i < 4; i++)
            rbv[i] = *(const s16x8*)&Bg[(size_t)srow_[i] * 256 + sch_[i] * 8];
        #pragma unroll 1
        for (int kt = 0; kt < 4; kt++) {
            #pragma unroll
            for (int i = 0; i < 4; i++)
                *(s16x8*)&Bs[srow_[i] * 64 + (((sch_[i] * 16) ^ ((srow_[i] & 7) << 4)) >> 1)] = rbv[i];
            if (kt < 3) {
                int k0 = (kt + 1) * 64;
                #pragma unroll
                for (int i = 0; i < 4; i++)
                    rbv[i] = *(const s16x8*)&Bg[(size_t)srow_[i] * 256 + k0 + sch_[i] * 8];
            }
            __builtin_amdgcn_s_setprio(1);
            #pragma unroll
            for (int kk = 0; kk < 2; kk++) {
                int kbyte = kt * 128 + kk * 64 + fkb;
                s16x8 af = *(const s16x8*)&h2s[fr * 256 + ((kbyte ^ ((fr & 7) << 4)) >> 1)];
                int kb2 = kk * 64 + fkb;
                #pragma unroll
                for (int n = 0; n < 2; n++) {
                    int brow = wn * 32 + n * 16 + fr;
                    s16x8 bfv = *(const s16x8*)&Bs[brow * 64 + ((kb2 ^ ((brow & 7) << 4)) >> 1)];
                    acc[n] = __builtin_amdgcn_mfma_f32_16x16x32_bf16(af, bfv, acc[n], 0, 0, 0);
                }
            }
            __builtin_amdgcn_s_setprio(0);
        }
        #pragma unroll
        for (int n = 0; n < 2; n++) {
            int col = c * 256 + colv[n];
            float bb1 = b1[col];
            #pragma unroll
            for (int r = 0; r < 4; r++) {
                int rl = rbase + r;
                ffs[rl * 1024 + (((col * 2) ^ ((rl & 7) << 4)) >> 1)] =
                    f2bf(fmaxf(acc[n][r] + bb1, 0.0f));
            }
        }
    }
    __syncthreads();   // ffs complete before cross-wave MLP2 reads
    // ---- MLP2: x += ffs @ W2T + b2 (K=1024); zero barriers inside ----
    f32x4 a2[2];
    a2[0] = (f32x4)0.0f; a2[1] = (f32x4)0.0f;
    #pragma unroll
    for (int i = 0; i < 4; i++)
        rbv[i] = *(const s16x8*)&W2T[(size_t)srow_[i] * 1024 + sch_[i] * 8];
    #pragma unroll 2
    for (int kt = 0; kt < 16; kt++) {
        #pragma unroll
        for (int i = 0; i < 4; i++)
            *(s16x8*)&Bs[srow_[i] * 64 + (((sch_[i] * 16) ^ ((srow_[i] & 7) << 4)) >> 1)] = rbv[i];
        if (kt < 15) {
            int k0 = (kt + 1) * 64;
            #pragma unroll
            for (int i = 0; i < 4; i++)
                rbv[i] = *(const s16x8*)&W2T[(size_t)srow_[i] * 1024 + k0 + sch_[i] * 8];
        }
        __builtin_amdgcn_s_setprio(1);
        #pragma unroll
        for (int kk = 0; kk < 2; kk++) {
            int kbyte = kt * 128 + kk * 64 + fkb;
            s16x8 af = *(const s16x8*)&ffs[fr * 1024 + ((kbyte ^ ((fr & 7) << 4)) >> 1)];
            int kb2 = kk * 64 + fkb;
            #pragma unroll
            for (int n = 0; n < 2; n++) {
                int brow = wn * 32 + n * 16 + fr;
                s16x8 bfv = *(const s16x8*)&Bs[brow * 64 + ((kb2 ^ ((brow & 7) << 4)) >> 1)];
                a2[n] = __builtin_amdgcn_mfma_f32_16x16x32_bf16(af, bfv, a2[n], 0, 0, 0);
            }
        }
        __builtin_amdgcn_s_setprio(0);
    }
    #pragma unroll
    for (int n = 0; n < 2; n++) {
        int col = colv[n];
        float bb2 = b2[col];
        #pragma unroll
        for (int r = 0; r < 4; r++) {
            float v = xn[n][r] + a2[n][r] + bb2;
            xn[n][r] = v;
            x[(size_t)(rows0 + rbase + r) * 256 + col] = v;
        }
    }
    // ---- LN(next ln1 / lnf) -> h2s (and global hb if last layer) ----
    __syncthreads();
    #pragma unroll
    for (int r = 0; r < 4; r++) {
        float s1 = xn[0][r] + xn[1][r];
        float s2 = xn[0][r] * xn[0][r] + xn[1][r] * xn[1][r];
        #pragma unroll
        for (int off = 1; off < 16; off <<= 1) {
            s1 += __shfl_xor(s1, off);
            s2 += __shfl_xor(s2, off);
        }
        if (fr == 0) { red1[rbase + r][wn] = s1; red2[rbase + r][wn] = s2; }
    }
    __syncthreads();
    if (tid < 16) {
        float s1 = 0.f, s2 = 0.f;
        #pragma unroll
        for (int w = 0; w < 8; w++) { s1 += red1[tid][w]; s2 += red2[tid][w]; }
        float mean = s1 * (1.0f / 256.0f);
        float var = s2 * (1.0f / 256.0f) - mean * mean;
        mrow[tid] = mean;
        rrow[tid] = rsqrtf(var + 1e-5f);
    }
    __syncthreads();
    #pragma unroll
    for (int n = 0; n < 2; n++) {
        int col = colv[n];
        float lsv = nls[col], lbv = nlb[col];
        #pragma unroll
        for (int r = 0; r < 4; r++) {
            int rl = rbase + r;
            float hv = (xn[n][r] - mrow[rl]) * rrow[rl] * lsv + lbv;
            ushort hu = f2bf(hv);
            h2s[rl * 256 + (((col * 2) ^ ((rl & 7) << 4)) >> 1)] = hu;
            if (mode == 0)
                hbout[(size_t)(rows0 + rl) * 256 + col] = hu;
        }
    }
    if (mode == 0) return;
    __syncthreads();   // h2s ready for QKV cross-wave reads

    // ---- QKV for next layer: kqv = h2 @ WqkvT_next (K=256); zero barriers inside ----
    float* kqv = (float*)ffs;   // 16 x 193 floats, aliases ffs (dead: all waves past MLP2 via LN barriers)
    acc[0] = (f32x4)0.0f; acc[1] = (f32x4)0.0f;
    #pragma unroll
    for (int i = 0; i < 4; i++)
        rbv[i] = *(const s16x8*)&WqkvT_next[(size_t)srow_[i] * 256 + sch_[i] * 8];
    #pragma unroll 1
    for (int kt = 0; kt < 4; kt++) {
        #pragma unroll
        for (int i = 0; i < 4; i++)
            *(s16x8*)&Bs[srow_[i] * 64 + (((sch_[i] * 16) ^ ((srow_[i] & 7) << 4)) >> 1)] = rbv[i];
        if (kt < 3) {
            int k0 = (kt + 1) * 64;
            #pragma unroll
            for (int i = 0; i < 4; i++)
                rbv[i] = *(const s16x8*)&WqkvT_next[(size_t)srow_[i] * 256 + k0 + sch_[i] * 8];
        }
        __builtin_amdgcn_s_setprio(1);
        #pragma unroll
        for (int kk = 0; kk < 2; kk++) {
            int kbyte = kt * 128 + kk * 64 + fkb;
            s16x8 af = *(const s16x8*)&h2s[fr * 256 + ((kbyte ^ ((fr & 7) << 4)) >> 1)];
            int kb2 = kk * 64 + fkb;
            #pragma unroll
            for (int n = 0; n < 2; n++) {
                int brow = wn * 32 + n * 16 + fr;
                s16x8 bfv = *(const s16x8*)&Bs[brow * 64 + ((kb2 ^ ((brow & 7) << 4)) >> 1)];
                acc[n] = __builtin_amdgcn_mfma_f32_16x16x32_bf16(af, bfv, acc[n], 0, 0, 0);
            }
        }
        __builtin_amdgcn_s_setprio(0);
    }
    __syncthreads();   // safe point before kqv (ffs-alias) writes
    #pragma unroll
    for (int n = 0; n < 2; n++) {
        int col = wn * 32 + n * 16 + fr;
        if (col < 192) {
            #pragma unroll
            for (int r = 0; r < 4; r++)
                kqv[(rbase + r) * 193 + col] = acc[n][r];
        }
    }
    __syncthreads();
    #pragma unroll
    for (int i = 0; i < 2; i++) {
        int u = tid + i * 512, t = u >> 6, hd = u & 63;
        Vb_out[(size_t)(rows0 + t) * 64 + hd] = f2bf(kqv[t * 193 + 128 + hd]);
    }
    {
        int h = tid >> 6, i2 = (tid >> 3) & 7, j = tid & 7;
        float s = 0.0f;
        #pragma unroll
        for (int t = 0; t < 16; t++)
            s += kqv[t * 193 + 64 + h * 8 + i2] * kqv[t * 193 + h * 8 + j];
        int part = (rows0 >> 4) & 31;
        Rpart_out[(size_t)(b * 32 + part) * 512 + tid] = s;
    }
}

// ================= logits GEMM: 128x256 tile, 512 thr, global_load_lds staging =================
__global__ __launch_bounds__(512, 4) void gpt_logits_mfma(const ushort* __restrict__ hb, const ushort* __restrict__ WfT,
                                                          const float* __restrict__ bfb, float* __restrict__ out,
                                                          float2* __restrict__ lsebuf) {
    __shared__ __align__(16) ushort As[128 * 64];   // 16 KB
    __shared__ __align__(16) ushort Bs[256 * 64];   // 32 KB
    f32x4 acc[4][4];
    // XCD-bijective swizzle: 6304 blocks = 8 * 788
    int flat = blockIdx.y * 32 + blockIdx.x;
    int nf = (flat & 7) * 788 + (flat >> 3);
    int rb = nf & 31, cb = nf >> 5;
    int row0 = rb * 128, c0 = cb * 256;
    const int tid = threadIdx.x, lane = tid & 63, wid = tid >> 6;
    const int wm = wid >> 2, wn = wid & 3;           // 2 x 4 waves, 64x64 each
    const int fr = lane & 15, fkb = (lane >> 4) * 16;

    #pragma unroll
    for (int m = 0; m < 4; m++)
        #pragma unroll
        for (int n = 0; n < 4; n++) acc[m][n] = (f32x4)0.0f;

    // prefetch bias (consumed only in epilogue)
    float bb[4]; int gcv[4];
    #pragma unroll
    for (int n = 0; n < 4; n++) {
        int gc = c0 + wn * 64 + n * 16 + fr;
        gcv[n] = gc;
        bb[n] = (gc < V_SZ) ? bfb[gc] : 0.0f;
    }

    const int srow = lane >> 3;            // 0..7 row within 8-row group
    const int sch = lane & 7;              // dest 16B chunk within row
    #pragma unroll 1
    for (int kt = 0; kt < 4; kt++) {
        if (kt) __syncthreads();
        {
            int kb = kt * 64;
            #pragma unroll
            for (int i = 0; i < 2; i++) {
                int rloc = wid * 16 + i * 8 + srow;
                int cs = sch ^ (rloc & 7);
                const ushort* gp = &hb[(size_t)(row0 + rloc) * 256 + kb + cs * 8];
                __builtin_amdgcn_global_load_lds((const AS1 void*)gp,
                                                 (AS3 void*)&As[(wid * 16 + i * 8) * 64], 16, 0, 0);
            }
            #pragma unroll
            for (int i = 0; i < 4; i++) {
                int rloc = wid * 32 + i * 8 + srow;
                int cs = sch ^ (rloc & 7);
                const ushort* gp = &WfT[(size_t)(c0 + rloc) * 256 + kb + cs * 8];
                __builtin_amdgcn_global_load_lds((const AS1 void*)gp,
                                                 (AS3 void*)&Bs[(wid * 32 + i * 8) * 64], 16, 0, 0);
            }
        }
        __syncthreads();
        #pragma unroll
        for (int kk = 0; kk < 2; kk++) {
            int kbyte = kk * 64 + fkb;
            s16x8 af[4], bfr[4];
            #pragma unroll
            for (int m = 0; m < 4; m++) {
                int arow = wm * 64 + m * 16 + fr;
                af[m] = *(const s16x8*)&As[arow * 64 + ((kbyte ^ ((arow & 7) << 4)) >> 1)];
            }
            #pragma unroll
            for (int n = 0; n < 4; n++) {
                int brow = wn * 64 + n * 16 + fr;
                bfr[n] = *(const s16x8*)&Bs[brow * 64 + ((kbyte ^ ((brow & 7) << 4)) >> 1)];
            }
            #pragma unroll
            for (int m = 0; m < 4; m++)
                #pragma unroll
                for (int n = 0; n < 4; n++)
                    acc[m][n] = __builtin_amdgcn_mfma_f32_16x16x32_bf16(af[m], bfr[n], acc[m][n], 0, 0, 0);
        }
    }
    __syncthreads();
    float2 (*red)[4] = (float2(*)[4])As;
    #pragma unroll
    for (int m = 0; m < 4; m++) {
        int rloc = wm * 64 + m * 16 + (lane >> 4) * 4;
        int gr = row0 + rloc;
        #pragma unroll
        for (int r = 0; r < 4; r++) {
            float v[4];
            float vmax = -1e30f;
            #pragma unroll
            for (int n = 0; n < 4; n++) {
                v[n] = (gcv[n] < V_SZ) ? acc[m][n][r] + bb[n] : -1e30f;
                vmax = fmaxf(vmax, v[n]);
            }
            #pragma unroll
            for (int n = 0; n < 4; n++)
                if (gcv[n] < V_SZ)
                    out[(size_t)(gr + r) * V_SZ + gcv[n]] = v[n];
            #pragma unroll
            for (int off = 1; off < 16; off <<= 1)
                vmax = fmaxf(vmax, __shfl_xor(vmax, off));
            float vsum = __expf(v[0] - vmax) + __expf(v[1] - vmax)
                       + __expf(v[2] - vmax) + __expf(v[3] - vmax);
            #pragma unroll
            for (int off = 1; off < 16; off <<= 1)
                vsum += __shfl_xor(vsum, off);
            if ((lane & 15) == 0)
                red[rloc + r][wn] = make_float2(vmax, vsum);
        }
    }
    __syncthreads();
    if (tid < 128) {
        float M = -1e30f, S = 0.0f;
        #pragma unroll
        for (int w = 0; w < 4; w++) {
            float2 p = red[tid][w];
            float M2 = fmaxf(M, p.x);
            S = S * __expf(M - M2) + p.y * __expf(p.x - M2);
            M = M2;
        }
        lsebuf[(size_t)(row0 + tid) * NCB + cb] = make_float2(M, S);
    }
}

// ================= lse finish =================
__global__ __launch_bounds__(256) void gpt_lse(const float2* __restrict__ lsebuf, const float* __restrict__ out,
                                               const int* __restrict__ tgt, float* __restrict__ partial) {
    int wave = threadIdx.x >> 6, lane = threadIdx.x & 63;
    int row = blockIdx.x * 4 + wave;
    float m = -INFINITY, s = 0.0f;
    for (int i = lane; i < NCB; i += 64) {
        float2 p = lsebuf[(size_t)row * NCB + i];
        float M = fmaxf(m, p.x);
        s = s * __expf(m - M) + p.y * __expf(p.x - M);
        m = M;
    }
    #pragma unroll
    for (int off = 1; off < 64; off <<= 1) {
        float m2 = __shfl_xor(m, off);
        float s2 = __shfl_xor(s, off);
        float M = fmaxf(m, m2);
        s = s * __expf(m - M) + s2 * __expf(m2 - M);
        m = M;
    }
    if (lane == 0)
        partial[row] = m + logf(s) - out[(size_t)row * V_SZ + tgt[row]];
}

__global__ void gpt_loss_reduce(const float* __restrict__ partial, float* __restrict__ out) {
    __shared__ float red[256];
    int tid = threadIdx.x;
    float s = 0.0f;
    for (int i = tid; i < 4096; i += 256) s += partial[i];
    red[tid] = s;
    __syncthreads();
    for (int off = 128; off > 0; off >>= 1) {
        if (tid < off) red[tid] += red[tid + off];
        __syncthreads();
    }
    if (tid == 0) out[0] = red[0] * (1.0f / 4096.0f);
}

// ======================= fp32 fallback kernels (small-ws path) =======================
__global__ void gpt_embed(const int* __restrict__ tokens, const float* __restrict__ tok_emb,
                          const float* __restrict__ pos_emb, float* __restrict__ x) {
    int idx = blockIdx.x * 256 + threadIdx.x;
    int bt = idx >> 8, e = idx & 255;
    int t = bt & 511;
    int tok = tokens[bt];
    x[idx] = tok_emb[tok * 256 + e] + pos_emb[t * 256 + e];
}

__global__ void gpt_ln(const float* __restrict__ x, const float* __restrict__ s,
                       const float* __restrict__ b, float* __restrict__ h) {
    __shared__ float red[256];
    int row = blockIdx.x, e = threadIdx.x;
    float v = x[row * 256 + e];
    red[e] = v;
    __syncthreads();
    for (int off = 128; off > 0; off >>= 1) {
        if (e < off) red[e] += red[e + off];
        __syncthreads();
    }
    float mean = red[0] * (1.0f / 256.0f);
    __syncthreads();
    float d = v - mean;
    red[e] = d * d;
    __syncthreads();
    for (int off = 128; off > 0; off >>= 1) {
        if (e < off) red[e] += red[e + off];
        __syncthreads();
    }
    float rstd = rsqrtf(red[0] * (1.0f / 256.0f) + 1e-5f);
    h[row * 256 + e] = d * rstd * s[e] + b[e];
}

__global__ void gpt_qkv(const float* __restrict__ h, const float* __restrict__ Wq,
                        const float* __restrict__ Wk, const float* __restrict__ Wv,
                        float* __restrict__ Q, float* __restrict__ K, float* __restrict__ Vv) {
    __shared__ float hs[8][256];
    int tid = threadIdx.x;
    int row0 = blockIdx.x * 8;
    #pragma unroll
    for (int r = 0; r < 8; r++) hs[r][tid] = h[(row0 + r) * 256 + tid];
    __syncthreads();
    if (tid < 192) {
        int kind = tid >> 6, o = tid & 63, hh = o >> 3, d = o & 7;
        const float* W = kind == 0 ? Wq : (kind == 1 ? Wk : Wv);
        const float* wp = W + hh * 2048 + d;
        float acc[8];
        #pragma unroll
        for (int r = 0; r < 8; r++) acc[r] = 0.0f;
        for (int e = 0; e < 256; e++) {
            float w = wp[e * 8];
            #pragma unroll
            for (int r = 0; r < 8; r++) acc[r] += hs[r][e] * w;
        }
        float* outp = kind == 0 ? Q : (kind == 1 ? K : Vv);
        int b = row0 >> 9;
        #pragma unroll
        for (int r = 0; r < 8; r++) {
            int t = (row0 + r) & 511;
            outp[((b * 8 + hh) * 512 + t) * 8 + d] = acc[r];
        }
    }
}

__global__ void gpt_attn_r(const float* __restrict__ K, const float* __restrict__ Q,
                           float* __restrict__ R) {
    __shared__ __align__(16) float Ks[64][8];
    __shared__ __align__(16) float Qs[64][8];
    int bh = blockIdx.x, tid = threadIdx.x;
    int i = tid >> 3, j = tid & 7;
    const float* Kb = K + bh * 512 * 8;
    const float* Qb = Q + bh * 512 * 8;
    float acc = 0.0f;
    for (int t0 = 0; t0 < 512; t0 += 64) {
        *(float4*)&Ks[tid][0] = *(const float4*)&Kb[(t0 + tid) * 8];
        *(float4*)&Ks[tid][4] = *(const float4*)&Kb[(t0 + tid) * 8 + 4];
        *(float4*)&Qs[tid][0] = *(const float4*)&Qb[(t0 + tid) * 8];
        *(float4*)&Qs[tid][4] = *(const float4*)&Qb[(t0 + tid) * 8 + 4];
        __syncthreads();
        #pragma unroll 16
        for (int t = 0; t < 64; t++) acc += Ks[t][i] * Qs[t][j];
        __syncthreads();
    }
    acc *= (1.0f / 16.0f);
    float val = (j >= i) ? acc : -INFINITY;
    float m = val;
    #pragma unroll
    for (int off = 1; off < 8; off <<= 1) m = fmaxf(m, __shfl_xor(m, off, 8));
    float ex = expf(val - m);
    float sum = ex;
    #pragma unroll
    for (int off = 1; off < 8; off <<= 1) sum += __shfl_xor(sum, off, 8);
    R[bh * 64 + tid] = ex / sum;
}

__global__ void gpt_attn_out(const float* __restrict__ Vv, const float* __restrict__ R,
                             const float* __restrict__ Wo, const float* __restrict__ bo,
                             float* __restrict__ x) {
    __shared__ __align__(16) float as[8][64];
    int tid = threadIdx.x;
    int row0 = blockIdx.x * 8;
    int b = row0 >> 9;
    #pragma unroll
    for (int k = 0; k < 2; k++) {
        int idx = k * 256 + tid;
        int r = idx >> 6, hd = idx & 63;
        int hh = hd >> 3, jj = hd & 7;
        int t = (row0 + r) & 511;
        const float* vp = Vv + ((b * 8 + hh) * 512 + t) * 8;
        const float* rp = R + (b * 8 + hh) * 64 + jj;
        float a = 0.0f;
        #pragma unroll
        for (int i = 0; i < 8; i++) a += vp[i] * rp[i * 8];
        as[r][hd] = a;
    }
    __syncthreads();
    float acc[8];
    float bb = bo[tid];
    #pragma unroll
    for (int r = 0; r < 8; r++) acc[r] = bb;
    for (int hd0 = 0; hd0 < 64; hd0 += 4) {
        float w0 = Wo[(hd0 + 0) * 256 + tid];
        float w1 = Wo[(hd0 + 1) * 256 + tid];
        float w2 = Wo[(hd0 + 2) * 256 + tid];
        float w3 = Wo[(hd0 + 3) * 256 + tid];
        #pragma unroll
        for (int r = 0; r < 8; r++) {
            float4 av = *(const float4*)&as[r][hd0];
            acc[r] += av.x * w0 + av.y * w1 + av.z * w2 + av.w * w3;
        }
    }
    #pragma unroll
    for (int r = 0; r < 8; r++) x[(row0 + r) * 256 + tid] += acc[r];
}

__global__ __launch_bounds__(256) void gpt_mlp(const float* __restrict__ h, const float* __restrict__ W1,
                         const float* __restrict__ b1, const float* __restrict__ W2,
                         const float* __restrict__ b2, float* __restrict__ x) {
    __shared__ __align__(16) float hs[8][256];
    __shared__ __align__(16) float ffs[8][1024];
    int tid = threadIdx.x;
    int row0 = blockIdx.x * 8;
    #pragma unroll
    for (int r = 0; r < 8; r++) hs[r][tid] = h[(row0 + r) * 256 + tid];
    __syncthreads();
    {
        float acc[4][8];
        #pragma unroll
        for (int k = 0; k < 4; k++) {
            float bb = b1[k * 256 + tid];
            #pragma unroll
            for (int r = 0; r < 8; r++) acc[k][r] = bb;
        }
        for (int e0 = 0; e0 < 256; e0 += 4) {
            float w[4][4];
            #pragma unroll
            for (int ee = 0; ee < 4; ee++)
                #pragma unroll
                for (int k = 0; k < 4; k++)
                    w[ee][k] = W1[(e0 + ee) * 1024 + k * 256 + tid];
            #pragma unroll
            for (int r = 0; r < 8; r++) {
                float4 hv = *(const float4*)&hs[r][e0];
                #pragma unroll
                for (int k = 0; k < 4; k++)
                    acc[k][r] += hv.x * w[0][k] + hv.y * w[1][k] + hv.z * w[2][k] + hv.w * w[3][k];
            }
        }
        #pragma unroll
        for (int k = 0; k < 4; k++)
            #pragma unroll
            for (int r = 0; r < 8; r++)
                ffs[r][k * 256 + tid] = fmaxf(acc[k][r], 0.0f);
    }
    __syncthreads();
    {
        float acc[8];
        float bb = b2[tid];
        #pragma unroll
        for (int r = 0; r < 8; r++) acc[r] = bb;
        for (int f0 = 0; f0 < 1024; f0 += 4) {
            float w0 = W2[(f0 + 0) * 256 + tid];
            float w1 = W2[(f0 + 1) * 256 + tid];
            float w2 = W2[(f0 + 2) * 256 + tid];
            float w3 = W2[(f0 + 3) * 256 + tid];
            #pragma unroll
            for (int r = 0; r < 8; r++) {
                float4 fv = *(const float4*)&ffs[r][f0];
                acc[r] += fv.x * w0 + fv.y * w1 + fv.z * w2 + fv.w * w3;
            }
        }
        #pragma unroll
        for (int r = 0; r < 8; r++) x[(row0 + r) * 256 + tid] += acc[r];
    }
}

__global__ __launch_bounds__(256) void gpt_logits(const float* __restrict__ hf, const float* __restrict__ Wf,
                            const float* __restrict__ bf, float* __restrict__ out) {
    __shared__ __align__(16) float hs[32][256];
    int tid = threadIdx.x;
    int row0 = blockIdx.y * 32;
    #pragma unroll
    for (int r = 0; r < 32; r++) hs[r][tid] = hf[(row0 + r) * 256 + tid];
    __syncthreads();
    int c0 = blockIdx.x * 512 + tid;
    int c1 = c0 + 256;
    int c0c = c0 < V_SZ ? c0 : V_SZ - 1;
    int c1c = c1 < V_SZ ? c1 : V_SZ - 1;
    float acc0[32], acc1[32];
    float b0 = bf[c0c], b1 = bf[c1c];
    #pragma unroll
    for (int r = 0; r < 32; r++) { acc0[r] = b0; acc1[r] = b1; }
    const float* p0 = Wf + c0c;
    const float* p1 = Wf + c1c;
    for (int e0 = 0; e0 < 256; e0 += 4) {
        float w00 = p0[(size_t)(e0 + 0) * V_SZ];
        float w01 = p0[(size_t)(e0 + 1) * V_SZ];
        float w02 = p0[(size_t)(e0 + 2) * V_SZ];
        float w03 = p0[(size_t)(e0 + 3) * V_SZ];
        float w10 = p1[(size_t)(e0 + 0) * V_SZ];
        float w11 = p1[(size_t)(e0 + 1) * V_SZ];
        float w12 = p1[(size_t)(e0 + 2) * V_SZ];
        float w13 = p1[(size_t)(e0 + 3) * V_SZ];
        #pragma unroll
        for (int r = 0; r < 32; r++) {
            float4 hv = *(const float4*)&hs[r][e0];
            acc0[r] += hv.x * w00 + hv.y * w01 + hv.z * w02 + hv.w * w03;
            acc1[r] += hv.x * w10 + hv.y * w11 + hv.z * w12 + hv.w * w13;
        }
    }
    if (c0 < V_SZ) {
        #pragma unroll
        for (int r = 0; r < 32; r++) out[(size_t)(row0 + r) * V_SZ + c0] = acc0[r];
    }
    if (c1 < V_SZ) {
        #pragma unroll
        for (int r = 0; r < 32; r++) out[(size_t)(row0 + r) * V_SZ + c1] = acc1[r];
    }
}

__global__ void gpt_loss(const float* __restrict__ logits, const int* __restrict__ tgt,
                         float* __restrict__ partial) {
    __shared__ float ms[256], ss[256];
    int row = blockIdx.x, tid = threadIdx.x;
    const float* lr = logits + (size_t)row * V_SZ;
    float m = -INFINITY, s = 0.0f;
    for (int c = tid; c < V_SZ; c += 256) {
        float v = lr[c];
        float nm = fmaxf(m, v);
        s = s * expf(m - nm) + expf(v - nm);
        m = nm;
    }
    ms[tid] = m; ss[tid] = s;
    __syncthreads();
    for (int off = 128; off > 0; off >>= 1) {
        if (tid < off) {
            float m2 = ms[tid + off], s2 = ss[tid + off];
            float M = fmaxf(ms[tid], m2);
            ss[tid] = ss[tid] * expf(ms[tid] - M) + s2 * expf(m2 - M);
            ms[tid] = M;
        }
        __syncthreads();
    }
    if (tid == 0) {
        float lse = ms[0] + logf(ss[0]);
        partial[row] = lse - lr[tgt[row]];
    }
}

// ======================= launch =======================
extern "C" void kernel_launch(void* const* d_in, const int* in_sizes, int n_in,
                              void* d_out, int out_size, void* d_ws, size_t ws_size,
                              hipStream_t stream) {
    const int*   tokens  = (const int*)d_in[0];
    const int*   ideal   = (const int*)d_in[1];
    const float* tok_emb = (const float*)d_in[2];
    const float* pos_emb = (const float*)d_in[3];
    const float* Wq      = (const float*)d_in[4];
    const float* Wk      = (const float*)d_in[5];
    const float* Wv      = (const float*)d_in[6];
    const float* Wo      = (const float*)d_in[7];
    const float* bo      = (const float*)d_in[8];
    const float* ln1_s   = (const float*)d_in[9];
    const float* ln1_b   = (const float*)d_in[10];
    const float* W1      = (const float*)d_in[11];
    const float* b1      = (const float*)d_in[12];
    const float* W2      = (const float*)d_in[13];
    const float* b2      = (const float*)d_in[14];
    const float* ln2_s   = (const float*)d_in[15];
    const float* ln2_b   = (const float*)d_in[16];
    const float* lnf_s   = (const float*)d_in[17];
    const float* lnf_b   = (const float*)d_in[18];
    const float* Wf      = (const float*)d_in[19];
    const float* bf      = (const float*)d_in[20];
    float* out = (float*)d_out;

    // ---- workspace layout (bf16 path) ----
    size_t off = 0;
    char* wsc = (char*)d_ws;
    ushort* WfT   = (ushort*)(wsc + off); off += (size_t)NPAD * 256 * 2;
    ushort* W1T   = (ushort*)(wsc + off); off += (size_t)16 * 1024 * 256 * 2;
    ushort* W2T   = (ushort*)(wsc + off); off += (size_t)16 * 256 * 1024 * 2;
    ushort* WqkvT = (ushort*)(wsc + off); off += (size_t)16 * 256 * 256 * 2;
    ushort* WoT   = (ushort*)(wsc + off); off += (size_t)16 * 256 * 64 * 2;
    ushort* hb    = (ushort*)(wsc + off); off += (size_t)4096 * 256 * 2;
    ushort* Vb0   = (ushort*)(wsc + off); off += (size_t)4096 * 64 * 2;
    ushort* Vb1   = (ushort*)(wsc + off); off += (size_t)4096 * 64 * 2;
    float*  x     = (float*)(wsc + off);  off += (size_t)4096 * 256 * 4;
    float*  Rp0   = (float*)(wsc + off);  off += (size_t)8 * 32 * 512 * 4;
    float*  Rp1   = (float*)(wsc + off);  off += (size_t)8 * 32 * 512 * 4;
    float*  partial = (float*)(wsc + off); off += (size_t)4096 * 4;
    float2* lsebuf = (float2*)(wsc + off); off += (size_t)4096 * NCB * 8;
    bool big = ws_size >= off;

    if (big) {
        cvt_transpose<<<dim3(16, 4, 16), 256, 0, stream>>>(W1, W1T, 256, 1024, 1024, 262144, 262144);
        cvt_transpose<<<dim3(4, 16, 16), 256, 0, stream>>>(W2, W2T, 1024, 256, 256, 262144, 262144);
        cvt_transpose<<<dim3(4, 1, 16), 256, 0, stream>>>(Wo, WoT, 64, 256, 256, 16384, 16384);
        cvt_transpose<<<dim3(788, 4, 1), 256, 0, stream>>>(Wf, WfT, 256, V_SZ, V_SZ, 0, 0);
        cvt_qkv<<<dim3(16, 3), 256, 0, stream>>>(Wq, Wk, Wv, WqkvT);

        gpt_embed_ln<<<1024, 256, 0, stream>>>(tokens, tok_emb, pos_emb, ln1_s, ln1_b, x, hb);
        gpt_pre<<<256, 512, 0, stream>>>(hb, WqkvT, Vb0, Rp0);

        for (int l = 0; l < 16; l++) {
            const float* nls = (l < 15) ? ln1_s + (l + 1) * 256 : lnf_s;
            const float* nlb = (l < 15) ? ln1_b + (l + 1) * 256 : lnf_b;
            const float* Rin = (l & 1) ? Rp1 : Rp0;
            const ushort* Vin = (l & 1) ? Vb1 : Vb0;
            float* Rout = (l & 1) ? Rp0 : Rp1;
            ushort* Vout = (l & 1) ? Vb0 : Vb1;
            int mode = (l < 15) ? 1 : 0;
            const ushort* Wnext = WqkvT + (size_t)((l < 15) ? (l + 1) : 0) * 65536;
            gpt_layer<<<256, 512, 0, stream>>>(Rin, Vin,
                                               WoT + (size_t)l * 16384, bo + l * 256,
                                               W1T + (size_t)l * 262144, b1 + l * 1024,
                                               W2T + (size_t)l * 262144, b2 + l * 256,
                                               ln2_s + l * 256, ln2_b + l * 256,
                                               nls, nlb, x,
                                               Wnext, Vout, Rout, hb, mode);
        }

        gpt_logits_mfma<<<dim3(32, NCB), 512, 0, stream>>>(hb, WfT, bf, out, lsebuf);
        gpt_lse<<<1024, 256, 0, stream>>>(lsebuf, out, ideal, partial);
        gpt_loss_reduce<<<1, 256, 0, stream>>>(partial, out + (size_t)4096 * V_SZ);
    } else {
        // fp32 fallback
        float* fx  = (float*)d_ws;
        float* fh  = fx + 4096 * 256;
        float* fQ  = fh + 4096 * 256;
        float* fK  = fQ + 4096 * 64;
        float* fV  = fK + 4096 * 64;
        float* fR  = fV + 4096 * 64;
        float* fpart = fR + 64 * 64;
        gpt_embed<<<4096, 256, 0, stream>>>(tokens, tok_emb, pos_emb, fx);
        for (int l = 0; l < 16; l++) {
            gpt_ln<<<4096, 256, 0, stream>>>(fx, ln1_s + l * 256, ln1_b + l * 256, fh);
            gpt_qkv<<<512, 256, 0, stream>>>(fh, Wq + l * 16384, Wk + l * 16384, Wv + l * 16384, fQ, fK, fV);
            gpt_attn_r<<<64, 64, 0, stream>>>(fK, fQ, fR);
            gpt_attn_out<<<512, 256, 0, stream>>>(fV, fR, Wo + l * 16384, bo + l * 256, fx);
            gpt_ln<<<4096, 256, 0, stream>>>(fx, ln2_s + l * 256, ln2_b + l * 256, fh);
            gpt_mlp<<<512, 256, 0, stream>>>(fh, W1 + l * 262144, b1 + l * 1024, W2 + l * 262144, b2 + l * 256, fx);
        }
        gpt_ln<<<4096, 256, 0, stream>>>(fx, lnf_s, lnf_b, fh);
        dim3 lg(99, 128);
        gpt_logits<<<lg, 256, 0, stream>>>(fh, Wf, bf, out);
        gpt_loss<<<4096, 256, 0, stream>>>(out, ideal, fpart);
        gpt_loss_reduce<<<1, 256, 0, stream>>>(fpart, out + (size_t)4096 * V_SZ);
    }
}